// Round 12
// baseline (1230.830 us; speedup 1.0000x reference)
//
#include <hip/hip_runtime.h>
#include <hip/hip_bf16.h>

// Problem constants
constexpr int Bc = 16, Sc = 512, Hc = 256, Vc = 8000, NHc = 4, HDc = 64;
constexpr int FFc = 512, Mc = 64;
constexpr int ROWS = Bc * Sc;      // 8192
constexpr int CH = 4 * Hc;         // 1024
constexpr int NT2 = CH / 32;       // 32 K-tiles (BK=32) for the head GEMM

typedef __attribute__((ext_vector_type(4))) float f32x4v;
typedef __attribute__((ext_vector_type(8))) short short8v;
typedef __attribute__((ext_vector_type(4))) short short4v;
typedef __hip_bfloat16 bf16;

// ---- 3-way bf16 split: x = h + m + l + O(2^-27 |x|) ----
__device__ inline void split3(float x, bf16& h, bf16& m, bf16& l) {
    h = __float2bfloat16(x);
    const float r = x - __bfloat162float(h);   // exact
    m = __float2bfloat16(r);
    const float r2 = r - __bfloat162float(m);  // exact
    l = __float2bfloat16(r2);
}

// ---------------- consolidated weight prep (one launch) ----------------
__device__ __forceinline__ void split_range(const float* __restrict__ in,
                                            bf16* __restrict__ h, bf16* __restrict__ m,
                                            bf16* __restrict__ l, int blk, int t) {
    const size_t i = ((size_t)blk * 256 + t) * 4;
    const float4 v = *(const float4*)&in[i];
    split3(v.x, h[i + 0], m[i + 0], l[i + 0]);
    split3(v.y, h[i + 1], m[i + 1], l[i + 1]);
    split3(v.z, h[i + 2], m[i + 2], l[i + 2]);
    split3(v.w, h[i + 3], m[i + 3], l[i + 3]);
}

__global__ __launch_bounds__(256) void k_prep(
    const float* __restrict__ qkv_w, const float* __restrict__ out_w,
    const float* __restrict__ ff1_w, const float* __restrict__ ff2_w,
    const float* __restrict__ log_w, const float* __restrict__ mat_w,
    const float* __restrict__ conv_w, const float* __restrict__ head_w,
    const float* __restrict__ log_b, const float* __restrict__ mat_b,
    bf16* qkvwh, bf16* qkvwm, bf16* qkvwl,
    bf16* outwh, bf16* outwm, bf16* outwl,
    bf16* ff1wh, bf16* ff1wm, bf16* ff1wl,
    bf16* ff2wh, bf16* ff2wm, bf16* ff2wl,
    bf16* lmwh, bf16* lmwm, bf16* lmwl,
    bf16* w2h, bf16* w2m, bf16* w2l,
    bf16* hwb, float* lmb) {
    const int blk = blockIdx.x;
    const int t = threadIdx.x;
    if (blk < 384) {
        split_range(qkv_w, qkvwh, qkvwm, qkvwl, blk, t);
    } else if (blk < 512) {
        split_range(out_w, outwh, outwm, outwl, blk - 384, t);
    } else if (blk < 768) {
        split_range(ff1_w, ff1wh, ff1wm, ff1wl, blk - 512, t);
    } else if (blk < 1024) {
        split_range(ff2_w, ff2wh, ff2wm, ff2wl, blk - 768, t);
    } else if (blk < 1088) {
        split_range(log_w, lmwh, lmwm, lmwl, blk - 1024, t);
    } else if (blk < 1152) {
        split_range(mat_w, lmwh + 65536, lmwm + 65536, lmwl + 65536, blk - 1088, t);
    } else if (blk < 1920) {
        const int idx = (blk - 1152) * 256 + t;       // conv re-layout + split
        const int o = idx / 768, rem = idx % 768;
        const int k = rem >> 8, i = rem & 255;
        split3(conv_w[(size_t)o * 768 + i * 3 + k], w2h[idx], w2m[idx], w2l[idx]);
    } else if (blk < 9920) {
        const size_t i = ((size_t)(blk - 1920) * 256 + t) * 4;   // head_w -> bf16, vector store
        const float4 v = *(const float4*)&head_w[i];
        bf16 b0 = __float2bfloat16(v.x), b1 = __float2bfloat16(v.y);
        bf16 b2 = __float2bfloat16(v.z), b3 = __float2bfloat16(v.w);
        short4v sv;
        sv[0] = *(const short*)&b0; sv[1] = *(const short*)&b1;
        sv[2] = *(const short*)&b2; sv[3] = *(const short*)&b3;
        *(short4v*)(hwb + i) = sv;
    } else {
        lmb[t] = log_b[t];
        lmb[256 + t] = mat_b[t];
    }
}

// ---------------- embed + pos (+ split planes) ----------------
__global__ __launch_bounds__(256) void k_embed(const int* __restrict__ ids,
                                               const float* __restrict__ emb,
                                               const float* __restrict__ pos,
                                               float* __restrict__ x,
                                               bf16* __restrict__ xh, bf16* __restrict__ xm,
                                               bf16* __restrict__ xl) {
    const int r = blockIdx.x;
    const int h = threadIdx.x;
    const int s = r & (Sc - 1);
    const int id = ids[r];
    const float v = emb[(size_t)id * Hc + h] + pos[(size_t)s * Hc + h];
    const size_t o = (size_t)r * Hc + h;
    x[o] = v;
    split3(v, xh[o], xm[o], xl[o]);
}

// ======== batched bf16x3 MFMA GEMM: C = A[M,K] @ B[N,K]^T ========
// EPI: 0 = +bias, 1 = gelu(x+bias), 3 = none
// OUTS: 0 = fp32 C, 1 = split3 planes, 3 = bf16 write into C (cast) at ldc stride
template <int EPI, int OUTS, int BN>
__global__ __launch_bounds__(256) void k_bg3(
    const bf16* __restrict__ Ah, const bf16* __restrict__ Am, const bf16* __restrict__ Al,
    const bf16* __restrict__ Bh, const bf16* __restrict__ Bm, const bf16* __restrict__ Bl,
    const float* __restrict__ bias, float* __restrict__ C,
    bf16* __restrict__ Oh, bf16* __restrict__ Om, bf16* __restrict__ Ol,
    int K, int lda, int ldb, int ldc,
    long zA2, long zA1, long zB2, long zB1, long zC2, long zC1) {
    constexpr int NF = BN / 32;
    __shared__ bf16 As[3][128 * 32];
    __shared__ bf16 Bs[3][BN * 32];
    const int z = blockIdx.z, z2 = z >> 2, z1 = z & 3;
    const size_t aoff = (size_t)z2 * zA2 + (size_t)z1 * zA1;
    const size_t boff = (size_t)z2 * zB2 + (size_t)z1 * zB1;
    const size_t coff = (size_t)z2 * zC2 + (size_t)z1 * zC1;
    const int t = threadIdx.x;
    const int tm = blockIdx.x * 128, tn = blockIdx.y * BN;
    const int w = t >> 6, l = t & 63;
    const int wr = w >> 1, wc = w & 1;
    const bf16* Ap[3] = {Ah, Am, Al};
    const bf16* Bp[3] = {Bh, Bm, Bl};
    f32x4v acc[4][NF];
    const f32x4v zero = {0.f, 0.f, 0.f, 0.f};
#pragma unroll
    for (int i = 0; i < 4; ++i)
#pragma unroll
        for (int j = 0; j < NF; ++j) acc[i][j] = zero;

    for (int kt = 0; kt < K; kt += 32) {
#pragma unroll
        for (int p = 0; p < 3; ++p) {
#pragma unroll
            for (int j = 0; j < 2; ++j) {
                const int c = j * 256 + t;
                const int row = c >> 2, kc = c & 3;
                const int skc = kc ^ ((row >> 1) & 3);
                const bf16* ga = Ap[p] + aoff + (size_t)(tm + row) * lda + kt + skc * 8;
                __builtin_amdgcn_global_load_lds((const __attribute__((address_space(1))) void*)ga,
                                                 (__attribute__((address_space(3))) void*)(&As[p][0] + c * 8),
                                                 16, 0, 0);
            }
            if (BN == 128) {
#pragma unroll
                for (int j = 0; j < 2; ++j) {
                    const int c = j * 256 + t;
                    const int row = c >> 2, kc = c & 3;
                    const int skc = kc ^ ((row >> 1) & 3);
                    const bf16* gb = Bp[p] + boff + (size_t)(tn + row) * ldb + kt + skc * 8;
                    __builtin_amdgcn_global_load_lds((const __attribute__((address_space(1))) void*)gb,
                                                     (__attribute__((address_space(3))) void*)(&Bs[p][0] + c * 8),
                                                     16, 0, 0);
                }
            } else {
                const int c = t;
                const int row = c >> 2, kc = c & 3;
                const int skc = kc ^ ((row >> 1) & 3);
                const bf16* gb = Bp[p] + boff + (size_t)(tn + row) * ldb + kt + skc * 8;
                __builtin_amdgcn_global_load_lds((const __attribute__((address_space(1))) void*)gb,
                                                 (__attribute__((address_space(3))) void*)(&Bs[p][0] + c * 8),
                                                 16, 0, 0);
            }
        }
        __syncthreads();
        const int lr = l & 15, lkc = l >> 4;
        short8v af[3][4], bfr[3][NF];
#pragma unroll
        for (int p = 0; p < 3; ++p)
#pragma unroll
            for (int m = 0; m < 4; ++m) {
                const int row = wr * 64 + m * 16 + lr;
                const int sc = lkc ^ ((row >> 1) & 3);
                af[p][m] = *(const short8v*)(&As[p][0] + row * 32 + sc * 8);
            }
#pragma unroll
        for (int p = 0; p < 3; ++p)
#pragma unroll
            for (int n = 0; n < NF; ++n) {
                const int row = wc * (BN / 2) + n * 16 + lr;
                const int sc = lkc ^ ((row >> 1) & 3);
                bfr[p][n] = *(const short8v*)(&Bs[p][0] + row * 32 + sc * 8);
            }
        // 6 term passes: hh, hm, mh, hl, lh, mm
#pragma unroll
        for (int m = 0; m < 4; ++m)
#pragma unroll
            for (int n = 0; n < NF; ++n)
                acc[m][n] = __builtin_amdgcn_mfma_f32_16x16x32_bf16(af[0][m], bfr[0][n], acc[m][n], 0, 0, 0);
#pragma unroll
        for (int m = 0; m < 4; ++m)
#pragma unroll
            for (int n = 0; n < NF; ++n)
                acc[m][n] = __builtin_amdgcn_mfma_f32_16x16x32_bf16(af[0][m], bfr[1][n], acc[m][n], 0, 0, 0);
#pragma unroll
        for (int m = 0; m < 4; ++m)
#pragma unroll
            for (int n = 0; n < NF; ++n)
                acc[m][n] = __builtin_amdgcn_mfma_f32_16x16x32_bf16(af[1][m], bfr[0][n], acc[m][n], 0, 0, 0);
#pragma unroll
        for (int m = 0; m < 4; ++m)
#pragma unroll
            for (int n = 0; n < NF; ++n)
                acc[m][n] = __builtin_amdgcn_mfma_f32_16x16x32_bf16(af[0][m], bfr[2][n], acc[m][n], 0, 0, 0);
#pragma unroll
        for (int m = 0; m < 4; ++m)
#pragma unroll
            for (int n = 0; n < NF; ++n)
                acc[m][n] = __builtin_amdgcn_mfma_f32_16x16x32_bf16(af[2][m], bfr[0][n], acc[m][n], 0, 0, 0);
#pragma unroll
        for (int m = 0; m < 4; ++m)
#pragma unroll
            for (int n = 0; n < NF; ++n)
                acc[m][n] = __builtin_amdgcn_mfma_f32_16x16x32_bf16(af[1][m], bfr[1][n], acc[m][n], 0, 0, 0);
        __syncthreads();
    }
    const int lr = l & 15, lq = (l >> 4) * 4;
#pragma unroll
    for (int n = 0; n < NF; ++n) {
        const int col = tn + wc * (BN / 2) + n * 16 + lr;
        const float bv = (EPI == 0 || EPI == 1) ? bias[col] : 0.0f;
#pragma unroll
        for (int m = 0; m < 4; ++m) {
            const int rbase = tm + wr * 64 + m * 16 + lq;
#pragma unroll
            for (int j = 0; j < 4; ++j) {
                float v = acc[m][n][j];
                if (EPI == 0) v += bv;
                if (EPI == 1) { v += bv; v = 0.5f * v * (1.0f + erff(v / 1.41421356237309515f)); }
                const size_t o = coff + (size_t)(rbase + j) * ldc + col;
                if (OUTS == 0) C[o] = v;
                else if (OUTS == 3) ((bf16*)C)[o] = __float2bfloat16(v);
                else split3(v, Oh[o], Om[o], Ol[o]);
            }
        }
    }
}

// ---------------- V-transpose: VT[z][d][s] from qkv planes ----------------
__global__ __launch_bounds__(256) void k_vt(const bf16* __restrict__ qh,
                                            const bf16* __restrict__ qm,
                                            const bf16* __restrict__ ql,
                                            bf16* __restrict__ vh, bf16* __restrict__ vm,
                                            bf16* __restrict__ vl) {
    __shared__ bf16 tile[64][72];
    const int sblk = blockIdx.x;           // 0..7
    const int z = blockIdx.y;              // 0..63
    const int b = z >> 2, h = z & 3;
    const int t = threadIdx.x;
    const int sr = t >> 2, c16 = (t & 3) * 16;
    const bf16* qp[3] = {qh, qm, ql};
    bf16* vp[3] = {vh, vm, vl};
    for (int p = 0; p < 3; ++p) {
        const bf16* src = qp[p] + (size_t)(b * Sc + sblk * 64 + sr) * 768 + 512 + h * 64 + c16;
        *(short8v*)&tile[sr][c16] = *(const short8v*)src;
        *(short8v*)&tile[sr][c16 + 8] = *(const short8v*)(src + 8);
        __syncthreads();
        bf16 out[16];
#pragma unroll
        for (int i = 0; i < 16; ++i) out[i] = tile[c16 + i][sr];
        bf16* dst = vp[p] + (size_t)(z * 64 + sr) * Sc + sblk * 64 + c16;
        *(short8v*)dst = *(short8v*)&out[0];
        *(short8v*)(dst + 8) = *(short8v*)&out[8];
        __syncthreads();
    }
}

// ======== fused attention (R8 version): pipelined LDS staging, issue-early ========
#define S_PASS(QA, KB)                                                                     \
    _Pragma("unroll") for (int m = 0; m < 2; ++m) _Pragma("unroll") for (int ks = 0; ks < 2; ++ks) \
        sa[m] = __builtin_amdgcn_mfma_f32_16x16x32_bf16(QA[m][ks], KB[ks], sa[m], 0, 0, 0);
#define PV_PASS(PA, VB)                                                                    \
    _Pragma("unroll") for (int m = 0; m < 2; ++m) _Pragma("unroll") for (int ks = 0; ks < 2; ++ks) \
        oa[m] = __builtin_amdgcn_mfma_f32_16x16x32_bf16(PA[m][ks], VB[ks], oa[m], 0, 0, 0);

__global__ __launch_bounds__(512) void k_attn(
    const bf16* __restrict__ qph, const bf16* __restrict__ qpm, const bf16* __restrict__ qpl,
    const bf16* __restrict__ vth, const bf16* __restrict__ vtm, const bf16* __restrict__ vtl,
    bf16* __restrict__ oh, bf16* __restrict__ om, bf16* __restrict__ ol) {
    extern __shared__ char smem[];
    float* S = (float*)smem;                        // 64 x 512 fp32, swizzled
    bf16* KV0 = (bf16*)(smem + 131072);             // 3 planes of [64][64]
    bf16* KV1 = KV0 + 4096;
    bf16* KV2 = KV1 + 4096;
    const int qc = blockIdx.x, z = blockIdx.y;
    const int b = z >> 2, hh = z & 3;
    const int t = threadIdx.x;
    const int w = t >> 6, lane = t & 63;
    const int lr = lane & 15, lkc = lane >> 4;      // lkc 0..3
    const int qg = w >> 2, kg = w & 3;
    const int r8 = t >> 3, c8 = t & 7;              // staging map
    const f32x4v zero = {0.f, 0.f, 0.f, 0.f};

    // Q A-frags in registers (one-time gather)
    short8v qf0[2][2], qf1[2][2], qf2[2][2];
#pragma unroll
    for (int m = 0; m < 2; ++m)
#pragma unroll
        for (int ks = 0; ks < 2; ++ks) {
            const size_t rbase = (size_t)(b * 512 + qc * 64 + qg * 32 + m * 16 + lr) * 768 + hh * 64 + ks * 32 + lkc * 8;
            qf0[m][ks] = *(const short8v*)(qph + rbase);
            qf1[m][ks] = *(const short8v*)(qpm + rbase);
            qf2[m][ks] = *(const short8v*)(qpl + rbase);
        }

    // stage K(0)
    {
        const size_t srow = (size_t)(b * 512 + 0 * 64 + r8) * 768 + 256 + hh * 64 + (c8 ^ (r8 & 7)) * 8;
        __builtin_amdgcn_global_load_lds((const __attribute__((address_space(1))) void*)(qph + srow),
                                         (__attribute__((address_space(3))) void*)(KV0 + r8 * 64 + c8 * 8), 16, 0, 0);
        __builtin_amdgcn_global_load_lds((const __attribute__((address_space(1))) void*)(qpm + srow),
                                         (__attribute__((address_space(3))) void*)(KV1 + r8 * 64 + c8 * 8), 16, 0, 0);
        __builtin_amdgcn_global_load_lds((const __attribute__((address_space(1))) void*)(qpl + srow),
                                         (__attribute__((address_space(3))) void*)(KV2 + r8 * 64 + c8 * 8), 16, 0, 0);
    }

    // ---- scores: S[q][kv] = (Q.K)/8 ----
    for (int kv = 0; kv < 8; ++kv) {
        __syncthreads();                             // K(kv) resident (vmcnt drained)
        short8v kb0[2], kb1[2], kb2[2];
#pragma unroll
        for (int ks = 0; ks < 2; ++ks) {
            const int row = kg * 16 + lr;
            const int sc = (ks * 4 + lkc) ^ (row & 7);
            kb0[ks] = *(const short8v*)(KV0 + row * 64 + sc * 8);
            kb1[ks] = *(const short8v*)(KV1 + row * 64 + sc * 8);
            kb2[ks] = *(const short8v*)(KV2 + row * 64 + sc * 8);
        }
        __syncthreads();                             // all reads done; KV buffer free
        if (kv < 7) {                                // issue-early: K(kv+1) overlaps compute
            const size_t srow = (size_t)(b * 512 + (kv + 1) * 64 + r8) * 768 + 256 + hh * 64 + (c8 ^ (r8 & 7)) * 8;
            __builtin_amdgcn_global_load_lds((const __attribute__((address_space(1))) void*)(qph + srow),
                                             (__attribute__((address_space(3))) void*)(KV0 + r8 * 64 + c8 * 8), 16, 0, 0);
            __builtin_amdgcn_global_load_lds((const __attribute__((address_space(1))) void*)(qpm + srow),
                                             (__attribute__((address_space(3))) void*)(KV1 + r8 * 64 + c8 * 8), 16, 0, 0);
            __builtin_amdgcn_global_load_lds((const __attribute__((address_space(1))) void*)(qpl + srow),
                                             (__attribute__((address_space(3))) void*)(KV2 + r8 * 64 + c8 * 8), 16, 0, 0);
        } else {                                     // prefetch V(0) under softmax
            const size_t srow = (size_t)(z * 64 + r8) * 512 + 0 * 64 + (c8 ^ (r8 & 7)) * 8;
            __builtin_amdgcn_global_load_lds((const __attribute__((address_space(1))) void*)(vth + srow),
                                             (__attribute__((address_space(3))) void*)(KV0 + r8 * 64 + c8 * 8), 16, 0, 0);
            __builtin_amdgcn_global_load_lds((const __attribute__((address_space(1))) void*)(vtm + srow),
                                             (__attribute__((address_space(3))) void*)(KV1 + r8 * 64 + c8 * 8), 16, 0, 0);
            __builtin_amdgcn_global_load_lds((const __attribute__((address_space(1))) void*)(vtl + srow),
                                             (__attribute__((address_space(3))) void*)(KV2 + r8 * 64 + c8 * 8), 16, 0, 0);
        }
        f32x4v sa[2] = {zero, zero};
        S_PASS(qf0, kb0) S_PASS(qf0, kb1) S_PASS(qf1, kb0)
        S_PASS(qf0, kb2) S_PASS(qf2, kb0) S_PASS(qf1, kb1)
#pragma unroll
        for (int m = 0; m < 2; ++m)
#pragma unroll
            for (int j = 0; j < 4; ++j) {
                const int row = qg * 32 + m * 16 + (lane >> 4) * 4 + j;
                const int col = kv * 64 + kg * 16 + lr;
                const int chunk = (col >> 2) ^ (row & 7);
                *(float*)((char*)S + row * 2048 + chunk * 16 + (col & 3) * 4) = sa[m][j] * 0.125f;
            }
    }
    __syncthreads();                                 // S complete; V(0) resident

    // ---- exact softmax per row (wave w owns rows w*8..w*8+7) ----
    for (int r = 0; r < 8; ++r) {
        const int row = w * 8 + r;
        char* rowp = (char*)S + row * 2048;
        const int sw = row & 7;
        float4 x0 = *(float4*)(rowp + ((2 * lane) ^ sw) * 16);
        float4 x1 = *(float4*)(rowp + ((2 * lane + 1) ^ sw) * 16);
        float mx = fmaxf(fmaxf(fmaxf(x0.x, x0.y), fmaxf(x0.z, x0.w)),
                         fmaxf(fmaxf(x1.x, x1.y), fmaxf(x1.z, x1.w)));
#pragma unroll
        for (int d = 1; d < 64; d <<= 1) mx = fmaxf(mx, __shfl_xor(mx, d));
        const float e0 = expf(x0.x - mx), e1 = expf(x0.y - mx), e2 = expf(x0.z - mx), e3 = expf(x0.w - mx);
        const float e4 = expf(x1.x - mx), e5 = expf(x1.y - mx), e6 = expf(x1.z - mx), e7 = expf(x1.w - mx);
        float sm = ((e0 + e1) + (e2 + e3)) + ((e4 + e5) + (e6 + e7));
#pragma unroll
        for (int d = 1; d < 64; d <<= 1) sm += __shfl_xor(sm, d);
        x0.x = e0 / sm; x0.y = e1 / sm; x0.z = e2 / sm; x0.w = e3 / sm;
        x1.x = e4 / sm; x1.y = e5 / sm; x1.z = e6 / sm; x1.w = e7 / sm;
        *(float4*)(rowp + ((2 * lane) ^ sw) * 16) = x0;
        *(float4*)(rowp + ((2 * lane + 1) ^ sw) * 16) = x1;
    }
    __syncthreads();

    // ---- PV: O[q][d] = sum_kv P[q][kv] * VT[d][kv] ----
    f32x4v oa[2] = {zero, zero};
    for (int kv = 0; kv < 8; ++kv) {
        if (kv > 0) __syncthreads();                 // V(kv) resident
        short8v vb0[2], vb1[2], vb2[2];
#pragma unroll
        for (int ks = 0; ks < 2; ++ks) {
            const int rowd = kg * 16 + lr;
            const int sc = (ks * 4 + lkc) ^ (rowd & 7);
            vb0[ks] = *(const short8v*)(KV0 + rowd * 64 + sc * 8);
            vb1[ks] = *(const short8v*)(KV1 + rowd * 64 + sc * 8);
            vb2[ks] = *(const short8v*)(KV2 + rowd * 64 + sc * 8);
        }
        __syncthreads();                             // reads done; KV free
        if (kv < 7) {
            const size_t srow = (size_t)(z * 64 + r8) * 512 + (kv + 1) * 64 + (c8 ^ (r8 & 7)) * 8;
            __builtin_amdgcn_global_load_lds((const __attribute__((address_space(1))) void*)(vth + srow),
                                             (__attribute__((address_space(3))) void*)(KV0 + r8 * 64 + c8 * 8), 16, 0, 0);
            __builtin_amdgcn_global_load_lds((const __attribute__((address_space(1))) void*)(vtm + srow),
                                             (__attribute__((address_space(3))) void*)(KV1 + r8 * 64 + c8 * 8), 16, 0, 0);
            __builtin_amdgcn_global_load_lds((const __attribute__((address_space(1))) void*)(vtl + srow),
                                             (__attribute__((address_space(3))) void*)(KV2 + r8 * 64 + c8 * 8), 16, 0, 0);
        }
        short8v pah[2][2], pam[2][2], pal[2][2];
#pragma unroll
        for (int m = 0; m < 2; ++m)
#pragma unroll
            for (int ks = 0; ks < 2; ++ks) {
                const int row = qg * 32 + m * 16 + lr;
                const int c0 = kv * 16 + ks * 8 + lkc * 2;
                char* rp = (char*)S + row * 2048;
                const float4 y0 = *(const float4*)(rp + (c0 ^ (row & 7)) * 16);
                const float4 y1 = *(const float4*)(rp + ((c0 + 1) ^ (row & 7)) * 16);
                const float yy[8] = {y0.x, y0.y, y0.z, y0.w, y1.x, y1.y, y1.z, y1.w};
                short8v hv, mv, lv;
#pragma unroll
                for (int i = 0; i < 8; ++i) {
                    bf16 a, bq, c;
                    split3(yy[i], a, bq, c);
                    hv[i] = *(const short*)&a; mv[i] = *(const short*)&bq; lv[i] = *(const short*)&c;
                }
                pah[m][ks] = hv; pam[m][ks] = mv; pal[m][ks] = lv;
            }
        PV_PASS(pah, vb0) PV_PASS(pah, vb1) PV_PASS(pam, vb0)
        PV_PASS(pah, vb2) PV_PASS(pal, vb0) PV_PASS(pam, vb1)
    }
    // epilogue: O planes [8192][256]
#pragma unroll
    for (int m = 0; m < 2; ++m)
#pragma unroll
        for (int j = 0; j < 4; ++j) {
            const int grow = b * 512 + qc * 64 + qg * 32 + m * 16 + (lane >> 4) * 4 + j;
            const int col = hh * 64 + kg * 16 + lr;
            const size_t o = (size_t)grow * 256 + col;
            split3(oa[m][j], oh[o], om[o], ol[o]);
        }
}

// ---------------- x = LayerNorm(x + res) * g + b (+ split planes, optional COMB pack) ----------------
__global__ __launch_bounds__(256) void k_add_ln(float* __restrict__ x,
                                                const float* __restrict__ res,
                                                const float* __restrict__ g,
                                                const float* __restrict__ b,
                                                bf16* __restrict__ xh, bf16* __restrict__ xm,
                                                bf16* __restrict__ xl,
                                                bf16* __restrict__ comb) {
    const size_t row = blockIdx.x;
    const int t = threadIdx.x;
    float v = x[row * Hc + t] + res[row * Hc + t];
    __shared__ float red[256];
    red[t] = v;
    __syncthreads();
    for (int s = 128; s > 0; s >>= 1) { if (t < s) red[t] += red[t + s]; __syncthreads(); }
    const float mean = red[0] * (1.0f / 256.0f);
    __syncthreads();
    const float d = v - mean;
    red[t] = d * d;
    __syncthreads();
    for (int s = 128; s > 0; s >>= 1) { if (t < s) red[t] += red[t + s]; __syncthreads(); }
    const float var = red[0] * (1.0f / 256.0f);
    const float out = d / sqrtf(var + 1e-5f) * g[t] + b[t];
    const size_t o = row * Hc + t;
    x[o] = out;
    split3(out, xh[o], xm[o], xl[o]);
    if (comb != nullptr) comb[row * CH + 768 + t] = __float2bfloat16(out);   // plan pack (final LN only)
}

// ---------------- LIF scan (both heads; 8-row load batches for ILP) ----------------
__global__ __launch_bounds__(256) void k_lif2(const float* __restrict__ lm,
                                              bf16* __restrict__ comb) {
    const int b = blockIdx.x;
    const int half = blockIdx.y;
    const int h = threadIdx.x;
    const float* p = lm + (size_t)b * Sc * 512 + half * 256 + h;
    bf16* o = comb + (size_t)b * Sc * CH + half * 256 + h;
    float mem = 0.0f;
    for (int s0 = 0; s0 < Sc; s0 += 8) {
        float xs[8];
#pragma unroll
        for (int q = 0; q < 8; ++q) xs[q] = p[(size_t)(s0 + q) * 512];
#pragma unroll
        for (int q = 0; q < 8; ++q) {
            const float reset = (mem > 1.0f) ? 1.0f : 0.0f;
            float t1 = 0.9f * mem;
            asm volatile("" : "+v"(t1));           // block FMA contraction: match np rounding
            float t2 = t1 + xs[q];
            asm volatile("" : "+v"(t2));
            mem = t2 - reset;
            o[(size_t)(s0 + q) * CH] = __float2bfloat16((mem > 1.0f) ? 1.0f : 0.0f);
        }
    }
}

// ---------------- halo-expanded conv input planes (vectorized short4) ----------------
__global__ __launch_bounds__(256) void k_aext3(const bf16* __restrict__ xh,
                                               const bf16* __restrict__ xm,
                                               const bf16* __restrict__ xl,
                                               bf16* __restrict__ aeh, bf16* __restrict__ aem,
                                               bf16* __restrict__ ael) {
    const int idx = blockIdx.x * 256 + threadIdx.x;   // < 1,572,864 (8192*768/4)
    const int row = idx / 192, c4 = idx % 192;        // c4: short4 index in 768-wide row
    const int c = c4 * 4;
    const int k = c >> 8, i = c & 255;
    const int b = row >> 9, s = row & 511;
    const int ss = s + k - 1;
    const size_t dst = (size_t)row * 768 + c;
    if (ss >= 0 && ss < Sc) {
        const size_t src = (size_t)(b * Sc + ss) * Hc + i;
        *(short4v*)(aeh + dst) = *(const short4v*)(xh + src);
        *(short4v*)(aem + dst) = *(const short4v*)(xm + src);
        *(short4v*)(ael + dst) = *(const short4v*)(xl + src);
    } else {
        const short4v z = {0, 0, 0, 0};
        *(short4v*)(aeh + dst) = z;
        *(short4v*)(aem + dst) = z;
        *(short4v*)(ael + dst) = z;
    }
}

// ======== head GEMM: 128x256 tile, BK=32, 4 waves, 48KB LDS, 3 blocks/CU ========
__device__ __forceinline__ void stageA32(const bf16* __restrict__ g, int rbase,
                                         bf16* lbase, int kt, int t) {
#pragma unroll
    for (int q = 0; q < 2; ++q) {
        const int f = q * 256 + t;
        const int rowt = f >> 2, chunk = f & 3;
        const int sch = chunk ^ ((rowt >> 1) & 3);
        const bf16* gp = g + (size_t)(rbase + rowt) * CH + kt * 32 + sch * 8;
        __builtin_amdgcn_global_load_lds((const __attribute__((address_space(1))) void*)gp,
                                         (__attribute__((address_space(3))) void*)(lbase + rowt * 32 + chunk * 8),
                                         16, 0, 0);
    }
}
__device__ __forceinline__ void stageB32(const bf16* __restrict__ g, int rbase, int rmax,
                                         bf16* lbase, int kt, int t) {
#pragma unroll
    for (int q = 0; q < 4; ++q) {
        const int f = q * 256 + t;
        const int rowt = f >> 2, chunk = f & 3;
        const int sch = chunk ^ ((rowt >> 1) & 3);
        int grow = rbase + rowt;
        if (grow > rmax) grow = rmax;
        const bf16* gp = g + (size_t)grow * CH + kt * 32 + sch * 8;
        __builtin_amdgcn_global_load_lds((const __attribute__((address_space(1))) void*)gp,
                                         (__attribute__((address_space(3))) void*)(lbase + rowt * 32 + chunk * 8),
                                         16, 0, 0);
    }
}

__global__ __launch_bounds__(256, 3) void k_head8(const bf16* __restrict__ Abf,
                                                  const bf16* __restrict__ Bbf,
                                                  const float* __restrict__ bias,
                                                  float* __restrict__ C) {
    __shared__ bf16 LA[2][128 * 32];
    __shared__ bf16 LB[2][256 * 32];
    const int t = threadIdx.x;
    const int w = t >> 6, lane = t & 63;
    const int wn = w;
    const int tm = blockIdx.x * 128, tn = blockIdx.y * 256;
    const int lr = lane & 15, lkc = lane >> 4;

    f32x4v acc[8][4];
    const f32x4v zero = {0.f, 0.f, 0.f, 0.f};
#pragma unroll
    for (int m = 0; m < 8; ++m)
#pragma unroll
        for (int n = 0; n < 4; ++n) acc[m][n] = zero;

    stageA32(Abf, tm, LA[0], 0, t);
    stageB32(Bbf, tn, Vc - 1, LB[0], 0, t);
    stageA32(Abf, tm, LA[1], 1, t);
    asm volatile("s_waitcnt vmcnt(2)" ::: "memory");
    __builtin_amdgcn_s_barrier();
    __builtin_amdgcn_sched_barrier(0);

    for (int kt = 0; kt < NT2; ++kt) {
        bf16* la = LA[kt & 1];
        bf16* lb = LB[kt & 1];
        bf16* lbN = LB[(kt + 1) & 1];
        short8v a[8], b[4];
#pragma unroll
        for (int m = 0; m < 8; ++m) {
            const int row = m * 16 + lr;
            const int sc = lkc ^ ((row >> 1) & 3);
            a[m] = *(const short8v*)(la + row * 32 + sc * 8);
        }
#pragma unroll
        for (int n = 0; n < 4; ++n) {
            const int row = wn * 64 + n * 16 + lr;
            const int sc = lkc ^ ((row >> 1) & 3);
            b[n] = *(const short8v*)(lb + row * 32 + sc * 8);
        }
        if (kt + 1 < NT2) stageB32(Bbf, tn, Vc - 1, lbN, kt + 1, t);
        __builtin_amdgcn_s_barrier();
        __builtin_amdgcn_sched_barrier(0);
        __builtin_amdgcn_s_setprio(1);
#pragma unroll
        for (int m = 0; m < 8; ++m)
#pragma unroll
            for (int n = 0; n < 2; ++n)
                acc[m][n] = __builtin_amdgcn_mfma_f32_16x16x32_bf16(a[m], b[n], acc[m][n], 0, 0, 0);
        __builtin_amdgcn_s_setprio(0);
        __builtin_amdgcn_s_barrier();
        __builtin_amdgcn_sched_barrier(0);
        if (kt + 2 < NT2) stageA32(Abf, tm, la, kt + 2, t);
        __builtin_amdgcn_s_setprio(1);
#pragma unroll
        for (int m = 0; m < 8; ++m)
#pragma unroll
            for (int n = 2; n < 4; ++n)
                acc[m][n] = __builtin_amdgcn_mfma_f32_16x16x32_bf16(a[m], b[n], acc[m][n], 0, 0, 0);
        __builtin_amdgcn_s_setprio(0);
        if (kt + 2 < NT2) asm volatile("s_waitcnt vmcnt(2)" ::: "memory");
        else              asm volatile("s_waitcnt vmcnt(0)" ::: "memory");
        __builtin_amdgcn_s_barrier();
        __builtin_amdgcn_sched_barrier(0);
    }
    const int lq = (lane >> 4) * 4;
#pragma unroll
    for (int n = 0; n < 4; ++n) {
        const int col = tn + wn * 64 + n * 16 + lr;
        if (col >= Vc) continue;
        const float bv = bias[col];
#pragma unroll
        for (int m = 0; m < 8; ++m) {
            const int rbase = tm + m * 16 + lq;
#pragma unroll
            for (int j = 0; j < 4; ++j)
                C[(size_t)(rbase + j) * Vc + col] = acc[m][n][j] + bv;
        }
    }
}

// ---------------- plan mean partials ----------------
__global__ __launch_bounds__(256) void k_pmean(const float* __restrict__ plan, float* __restrict__ pm2) {
    const int b = blockIdx.x, c = blockIdx.y;
    const int h = threadIdx.x;
    const float* p = plan + ((size_t)(b * Sc + c * 64)) * Hc + h;
    float s = 0.0f;
    for (int i = 0; i < 64; ++i) s += p[(size_t)i * Hc];
    pm2[((size_t)b * 8 + c) * Hc + h] = s;
}

// ---------------- read softmax + memory read ----------------
__global__ __launch_bounds__(256) void k_memread(const float* __restrict__ pm2,
                                                 const float* __restrict__ rw,
                                                 const float* __restrict__ rb,
                                                 const float* __restrict__ memm,
                                                 float* __restrict__ out) {
    const int b = blockIdx.x;
    const int t = threadIdx.x;
    __shared__ float pms[256];
    __shared__ float lg[64];
    __shared__ float sm[64];
    float v = 0.0f;
    for (int c = 0; c < 8; ++c) v += pm2[((size_t)b * 8 + c) * Hc + t];
    pms[t] = v * (1.0f / 512.0f);
    __syncthreads();
    if (t < 64) {
        float s = rb[t];
        const float* wrow = rw + (size_t)t * Hc;
        for (int i = 0; i < Hc; ++i) s = fmaf(wrow[i], pms[i], s);
        lg[t] = s;
    }
    __syncthreads();
    if (t == 0) {
        float mx = lg[0];
        for (int i = 1; i < 64; ++i) mx = fmaxf(mx, lg[i]);
        float ssum = 0.0f;
        for (int i = 0; i < 64; ++i) { const float e = expf(lg[i] - mx); sm[i] = e; ssum += e; }
        for (int i = 0; i < 64; ++i) sm[i] /= ssum;
    }
    __syncthreads();
    float s = 0.0f;
    for (int m = 0; m < 64; ++m) s = fmaf(sm[m], memm[(size_t)m * Hc + t], s);
    out[(size_t)b * Hc + t] = s;
}

extern "C" void kernel_launch(void* const* d_in, const int* in_sizes, int n_in,
                              void* d_out, int out_size, void* d_ws, size_t ws_size,
                              hipStream_t stream) {
    const int*   ids    = (const int*)  d_in[0];
    const float* embed  = (const float*)d_in[1];
    const float* pos    = (const float*)d_in[2];
    const float* qkv_w  = (const float*)d_in[3];
    const float* qkv_b  = (const float*)d_in[4];
    const float* out_w  = (const float*)d_in[5];
    const float* out_b  = (const float*)d_in[6];
    const float* ln1_g  = (const float*)d_in[7];
    const float* ln1_b  = (const float*)d_in[8];
    const float* ff1_w  = (const float*)d_in[9];
    const float* ff1_b  = (const float*)d_in[10];
    const float* ff2_w  = (const float*)d_in[11];
    const float* ff2_b  = (const float*)d_in[12];
    const float* ln2_g  = (const float*)d_in[13];
    const float* ln2_b  = (const float*)d_in[14];
    const float* log_w  = (const float*)d_in[15];
    const float* log_b  = (const float*)d_in[16];
    const float* mat_w  = (const float*)d_in[17];
    const float* mat_b  = (const float*)d_in[18];
    const float* conv_w = (const float*)d_in[19];
    const float* conv_b = (const float*)d_in[20];
    const float* read_w = (const float*)d_in[21];
    const float* read_b = (const float*)d_in[22];
    const float* memory = (const float*)d_in[23];
    const float* head_w = (const float*)d_in[24];
    const float* head_b = (const float*)d_in[25];

    char* wsb = (char*)d_ws;
    const size_t MB = 1ull << 20;
    float* X    = (float*)(wsb + 0);           // 8 MB [8192,256]
    bf16*  XH   = (bf16*)(wsb + 8 * MB);
    bf16*  XM   = (bf16*)(wsb + 12 * MB);
    bf16*  XL   = (bf16*)(wsb + 16 * MB);
    float* RES  = (float*)(wsb + 20 * MB);     // 8 MB
    bf16*  QPH  = (bf16*)(wsb + 28 * MB);      // 12 MB each [8192,768] planes
    bf16*  QPM  = (bf16*)(wsb + 40 * MB);
    bf16*  QPL  = (bf16*)(wsb + 52 * MB);
    bf16*  OH   = (bf16*)(wsb + 64 * MB);      // 4 MB each
    bf16*  OM   = (bf16*)(wsb + 68 * MB);
    bf16*  OL   = (bf16*)(wsb + 72 * MB);
    // ---- alias region 76..128 MB ----
    bf16*  VTH  = (bf16*)(wsb + 76 * MB);      // 4 MB each (attention phase)
    bf16*  VTM  = (bf16*)(wsb + 80 * MB);
    bf16*  VTL  = (bf16*)(wsb + 84 * MB);
    bf16*  H1H  = (bf16*)(wsb + 88 * MB);      // 8 MB each (ff phase; disjoint from VT)
    bf16*  H1M  = (bf16*)(wsb + 96 * MB);
    bf16*  H1L  = (bf16*)(wsb + 104 * MB);
    float* LOGMAT = (float*)(wsb + 76 * MB);   // 16 MB [8192,512] (post-loop)
    bf16*  AEH  = (bf16*)(wsb + 92 * MB);      // 12 MB each (post-loop)
    bf16*  AEM  = (bf16*)(wsb + 104 * MB);
    bf16*  AEL  = (bf16*)(wsb + 116 * MB);
    // ---------------------------------
    bf16*  COMB = (bf16*)(wsb + 128 * MB);     // 16 MB [8192,1024]
    bf16*  HWB  = (bf16*)(wsb + 144 * MB);     // 16 MB [8000,1024]
    bf16*  WP   = (bf16*)(wsb + 160 * MB);     // weight planes
    float* PM2  = (float*)(wsb + 64 * MB);     // [16,8,256] partials (reuse OH post-loop)

    float* logits = (float*)d_out;
    float* mread  = logits + (size_t)ROWS * Vc;

    // weight plane sub-offsets (elements)
    bf16* qkvwh = WP;             bf16* qkvwm = qkvwh + 393216; bf16* qkvwl = qkvwm + 393216;
    bf16* outwh = qkvwl + 393216; bf16* outwm = outwh + 131072; bf16* outwl = outwm + 131072;
    bf16* ff1wh = outwl + 131072; bf16* ff1wm = ff1wh + 262144; bf16* ff1wl = ff1wm + 262144;
    bf16* ff2wh = ff1wl + 262144; bf16* ff2wm = ff2wh + 262144; bf16* ff2wl = ff2wm + 262144;
    bf16* lmwh  = ff2wl + 262144; bf16* lmwm  = lmwh + 131072;  bf16* lmwl  = lmwm + 131072;
    bf16* w2h   = lmwl + 131072;  bf16* w2m   = w2h + 196608;   bf16* w2l   = w2m + 196608;
    float* LMB  = (float*)(w2l + 196608);      // [512] concat bias (after weight planes)

    hipFuncSetAttribute((const void*)k_attn, hipFuncAttributeMaxDynamicSharedMemorySize, 155648);

    // consolidated weight prep (one launch)
    k_prep<<<dim3(9921), 256, 0, stream>>>(
        qkv_w, out_w, ff1_w, ff2_w, log_w, mat_w, conv_w, head_w, log_b, mat_b,
        qkvwh, qkvwm, qkvwl, outwh, outwm, outwl, ff1wh, ff1wm, ff1wl,
        ff2wh, ff2wm, ff2wl, lmwh, lmwm, lmwl, w2h, w2m, w2l, HWB, LMB);

    k_embed<<<dim3(ROWS), 256, 0, stream>>>(ids, embed, pos, X, XH, XM, XL);
    for (int l = 0; l < 2; ++l) {
        // qkv -> QP planes [8192,768]
        k_bg3<0, 1, 128><<<dim3(64, 6, 1), 256, 0, stream>>>(
            XH, XM, XL,
            qkvwh + (size_t)l * 196608, qkvwm + (size_t)l * 196608, qkvwl + (size_t)l * 196608,
            qkv_b + l * 768, nullptr, QPH, QPM, QPL,
            256, 256, 256, 768, 0, 0, 0, 0, 0, 0);
        k_vt<<<dim3(8, 64), 256, 0, stream>>>(QPH, QPM, QPL, VTH, VTM, VTL);
        // fused scores + softmax + PV -> O planes (pipelined LDS staging)
        k_attn<<<dim3(8, 64), 512, 155648, stream>>>(QPH, QPM, QPL, VTH, VTM, VTL, OH, OM, OL);
        // out proj -> RES fp32
        k_bg3<0, 0, 64><<<dim3(64, 4, 1), 256, 0, stream>>>(
            OH, OM, OL,
            outwh + (size_t)l * 65536, outwm + (size_t)l * 65536, outwl + (size_t)l * 65536,
            out_b + l * 256, RES, nullptr, nullptr, nullptr,
            256, 256, 256, 256, 0, 0, 0, 0, 0, 0);
        k_add_ln<<<dim3(ROWS), 256, 0, stream>>>(X, RES, ln1_g + l * 256, ln1_b + l * 256,
                                                 XH, XM, XL, nullptr);
        // ff1 + gelu -> H1 planes
        k_bg3<1, 1, 128><<<dim3(64, 4, 1), 256, 0, stream>>>(
            XH, XM, XL,
            ff1wh + (size_t)l * 131072, ff1wm + (size_t)l * 131072, ff1wl + (size_t)l * 131072,
            ff1_b + l * 512, nullptr, H1H, H1M, H1L,
            256, 256, 256, 512, 0, 0, 0, 0, 0, 0);
        // ff2 -> RES fp32
        k_bg3<0, 0, 64><<<dim3(64, 4, 1), 256, 0, stream>>>(
            H1H, H1M, H1L,
            ff2wh + (size_t)l * 131072, ff2wm + (size_t)l * 131072, ff2wl + (size_t)l * 131072,
            ff2_b + l * 256, RES, nullptr, nullptr, nullptr,
            512, 512, 512, 256, 0, 0, 0, 0, 0, 0);
        // final LN also packs plan into COMB (cols 768..1023)
        k_add_ln<<<dim3(ROWS), 256, 0, stream>>>(X, RES, ln2_g + l * 256, ln2_b + l * 256,
                                                 XH, XM, XL, (l == 1) ? COMB : nullptr);
    }
    // plan = X; fused log+mat projection -> LOGMAT [8192,512]
    k_bg3<0, 0, 128><<<dim3(64, 4, 1), 256, 0, stream>>>(
        XH, XM, XL, lmwh, lmwm, lmwl, LMB, LOGMAT, nullptr, nullptr, nullptr,
        256, 256, 256, 512, 0, 0, 0, 0, 0, 0);
    k_aext3<<<dim3(6144), 256, 0, stream>>>(XH, XM, XL, AEH, AEM, AEL);
    k_lif2<<<dim3(Bc, 2), 256, 0, stream>>>(LOGMAT, COMB);
    // conv as GEMM -> bf16 directly into COMB cols 512..767 (OUTS=3)
    k_bg3<0, 3, 64><<<dim3(64, 4, 1), 256, 0, stream>>>(
        AEH, AEM, AEL, w2h, w2m, w2l, conv_b, (float*)(COMB + 512), nullptr, nullptr, nullptr,
        768, 768, 768, CH, 0, 0, 0, 0, 0, 0);
    k_head8<<<dim3(64, 32), 256, 0, stream>>>(COMB, HWB, head_b, logits);
    k_pmean<<<dim3(Bc, 8), 256, 0, stream>>>(X, PM2);
    k_memread<<<dim3(Bc), 256, 0, stream>>>(PM2, read_w, read_b, memory, mread);
}

// Round 13
// 1220.942 us; speedup vs baseline: 1.0081x; 1.0081x over previous
//
#include <hip/hip_runtime.h>
#include <hip/hip_bf16.h>

// Problem constants
constexpr int Bc = 16, Sc = 512, Hc = 256, Vc = 8000, NHc = 4, HDc = 64;
constexpr int FFc = 512, Mc = 64;
constexpr int ROWS = Bc * Sc;      // 8192
constexpr int CH = 4 * Hc;         // 1024
constexpr int NT2 = CH / 32;       // 32 K-tiles (BK=32) for the head GEMM

typedef __attribute__((ext_vector_type(4))) float f32x4v;
typedef __attribute__((ext_vector_type(8))) short short8v;
typedef __attribute__((ext_vector_type(4))) short short4v;
typedef __hip_bfloat16 bf16;

// ---- 3-way bf16 split: x = h + m + l + O(2^-27 |x|) ----
__device__ inline void split3(float x, bf16& h, bf16& m, bf16& l) {
    h = __float2bfloat16(x);
    const float r = x - __bfloat162float(h);   // exact
    m = __float2bfloat16(r);
    const float r2 = r - __bfloat162float(m);  // exact
    l = __float2bfloat16(r2);
}

// ---------------- consolidated weight prep (one launch) ----------------
__device__ __forceinline__ void split_range(const float* __restrict__ in,
                                            bf16* __restrict__ h, bf16* __restrict__ m,
                                            bf16* __restrict__ l, int blk, int t) {
    const size_t i = ((size_t)blk * 256 + t) * 4;
    const float4 v = *(const float4*)&in[i];
    split3(v.x, h[i + 0], m[i + 0], l[i + 0]);
    split3(v.y, h[i + 1], m[i + 1], l[i + 1]);
    split3(v.z, h[i + 2], m[i + 2], l[i + 2]);
    split3(v.w, h[i + 3], m[i + 3], l[i + 3]);
}

__global__ __launch_bounds__(256) void k_prep(
    const float* __restrict__ qkv_w, const float* __restrict__ out_w,
    const float* __restrict__ ff1_w, const float* __restrict__ ff2_w,
    const float* __restrict__ log_w, const float* __restrict__ mat_w,
    const float* __restrict__ conv_w, const float* __restrict__ head_w,
    const float* __restrict__ log_b, const float* __restrict__ mat_b,
    bf16* qkvwh, bf16* qkvwm, bf16* qkvwl,
    bf16* outwh, bf16* outwm, bf16* outwl,
    bf16* ff1wh, bf16* ff1wm, bf16* ff1wl,
    bf16* ff2wh, bf16* ff2wm, bf16* ff2wl,
    bf16* lmwh, bf16* lmwm, bf16* lmwl,
    bf16* w2h, bf16* w2m, bf16* w2l,
    bf16* hwb, float* lmb) {
    const int blk = blockIdx.x;
    const int t = threadIdx.x;
    if (blk < 384) {
        split_range(qkv_w, qkvwh, qkvwm, qkvwl, blk, t);
    } else if (blk < 512) {
        split_range(out_w, outwh, outwm, outwl, blk - 384, t);
    } else if (blk < 768) {
        split_range(ff1_w, ff1wh, ff1wm, ff1wl, blk - 512, t);
    } else if (blk < 1024) {
        split_range(ff2_w, ff2wh, ff2wm, ff2wl, blk - 768, t);
    } else if (blk < 1088) {
        split_range(log_w, lmwh, lmwm, lmwl, blk - 1024, t);
    } else if (blk < 1152) {
        split_range(mat_w, lmwh + 65536, lmwm + 65536, lmwl + 65536, blk - 1088, t);
    } else if (blk < 1920) {
        const int idx = (blk - 1152) * 256 + t;       // conv re-layout + split
        const int o = idx / 768, rem = idx % 768;
        const int k = rem >> 8, i = rem & 255;
        split3(conv_w[(size_t)o * 768 + i * 3 + k], w2h[idx], w2m[idx], w2l[idx]);
    } else if (blk < 9920) {
        const size_t i = ((size_t)(blk - 1920) * 256 + t) * 4;   // head_w -> bf16, vector store
        const float4 v = *(const float4*)&head_w[i];
        bf16 b0 = __float2bfloat16(v.x), b1 = __float2bfloat16(v.y);
        bf16 b2 = __float2bfloat16(v.z), b3 = __float2bfloat16(v.w);
        short4v sv;
        sv[0] = *(const short*)&b0; sv[1] = *(const short*)&b1;
        sv[2] = *(const short*)&b2; sv[3] = *(const short*)&b3;
        *(short4v*)(hwb + i) = sv;
    } else {
        lmb[t] = log_b[t];
        lmb[256 + t] = mat_b[t];
    }
}

// ---------------- embed + pos (+ split planes) ----------------
__global__ __launch_bounds__(256) void k_embed(const int* __restrict__ ids,
                                               const float* __restrict__ emb,
                                               const float* __restrict__ pos,
                                               float* __restrict__ x,
                                               bf16* __restrict__ xh, bf16* __restrict__ xm,
                                               bf16* __restrict__ xl) {
    const int r = blockIdx.x;
    const int h = threadIdx.x;
    const int s = r & (Sc - 1);
    const int id = ids[r];
    const float v = emb[(size_t)id * Hc + h] + pos[(size_t)s * Hc + h];
    const size_t o = (size_t)r * Hc + h;
    x[o] = v;
    split3(v, xh[o], xm[o], xl[o]);
}

// ======== batched bf16x3 MFMA GEMM: C = A[M,K] @ B[N,K]^T ========
// EPI: 0 = +bias, 1 = gelu(x+bias), 3 = none
// OUTS: 0 = fp32 C, 1 = split3 planes, 3 = bf16 write into C (cast) at ldc stride
template <int EPI, int OUTS, int BN>
__global__ __launch_bounds__(256) void k_bg3(
    const bf16* __restrict__ Ah, const bf16* __restrict__ Am, const bf16* __restrict__ Al,
    const bf16* __restrict__ Bh, const bf16* __restrict__ Bm, const bf16* __restrict__ Bl,
    const float* __restrict__ bias, float* __restrict__ C,
    bf16* __restrict__ Oh, bf16* __restrict__ Om, bf16* __restrict__ Ol,
    int K, int lda, int ldb, int ldc,
    long zA2, long zA1, long zB2, long zB1, long zC2, long zC1) {
    constexpr int NF = BN / 32;
    __shared__ bf16 As[3][128 * 32];
    __shared__ bf16 Bs[3][BN * 32];
    const int z = blockIdx.z, z2 = z >> 2, z1 = z & 3;
    const size_t aoff = (size_t)z2 * zA2 + (size_t)z1 * zA1;
    const size_t boff = (size_t)z2 * zB2 + (size_t)z1 * zB1;
    const size_t coff = (size_t)z2 * zC2 + (size_t)z1 * zC1;
    const int t = threadIdx.x;
    const int tm = blockIdx.x * 128, tn = blockIdx.y * BN;
    const int w = t >> 6, l = t & 63;
    const int wr = w >> 1, wc = w & 1;
    const bf16* Ap[3] = {Ah, Am, Al};
    const bf16* Bp[3] = {Bh, Bm, Bl};
    f32x4v acc[4][NF];
    const f32x4v zero = {0.f, 0.f, 0.f, 0.f};
#pragma unroll
    for (int i = 0; i < 4; ++i)
#pragma unroll
        for (int j = 0; j < NF; ++j) acc[i][j] = zero;

    for (int kt = 0; kt < K; kt += 32) {
#pragma unroll
        for (int p = 0; p < 3; ++p) {
#pragma unroll
            for (int j = 0; j < 2; ++j) {
                const int c = j * 256 + t;
                const int row = c >> 2, kc = c & 3;
                const int skc = kc ^ ((row >> 1) & 3);
                const bf16* ga = Ap[p] + aoff + (size_t)(tm + row) * lda + kt + skc * 8;
                __builtin_amdgcn_global_load_lds((const __attribute__((address_space(1))) void*)ga,
                                                 (__attribute__((address_space(3))) void*)(&As[p][0] + c * 8),
                                                 16, 0, 0);
            }
            if (BN == 128) {
#pragma unroll
                for (int j = 0; j < 2; ++j) {
                    const int c = j * 256 + t;
                    const int row = c >> 2, kc = c & 3;
                    const int skc = kc ^ ((row >> 1) & 3);
                    const bf16* gb = Bp[p] + boff + (size_t)(tn + row) * ldb + kt + skc * 8;
                    __builtin_amdgcn_global_load_lds((const __attribute__((address_space(1))) void*)gb,
                                                     (__attribute__((address_space(3))) void*)(&Bs[p][0] + c * 8),
                                                     16, 0, 0);
                }
            } else {
                const int c = t;
                const int row = c >> 2, kc = c & 3;
                const int skc = kc ^ ((row >> 1) & 3);
                const bf16* gb = Bp[p] + boff + (size_t)(tn + row) * ldb + kt + skc * 8;
                __builtin_amdgcn_global_load_lds((const __attribute__((address_space(1))) void*)gb,
                                                 (__attribute__((address_space(3))) void*)(&Bs[p][0] + c * 8),
                                                 16, 0, 0);
            }
        }
        __syncthreads();
        const int lr = l & 15, lkc = l >> 4;
        short8v af[3][4], bfr[3][NF];
#pragma unroll
        for (int p = 0; p < 3; ++p)
#pragma unroll
            for (int m = 0; m < 4; ++m) {
                const int row = wr * 64 + m * 16 + lr;
                const int sc = lkc ^ ((row >> 1) & 3);
                af[p][m] = *(const short8v*)(&As[p][0] + row * 32 + sc * 8);
            }
#pragma unroll
        for (int p = 0; p < 3; ++p)
#pragma unroll
            for (int n = 0; n < NF; ++n) {
                const int row = wc * (BN / 2) + n * 16 + lr;
                const int sc = lkc ^ ((row >> 1) & 3);
                bfr[p][n] = *(const short8v*)(&Bs[p][0] + row * 32 + sc * 8);
            }
        // 6 term passes: hh, hm, mh, hl, lh, mm
#pragma unroll
        for (int m = 0; m < 4; ++m)
#pragma unroll
            for (int n = 0; n < NF; ++n)
                acc[m][n] = __builtin_amdgcn_mfma_f32_16x16x32_bf16(af[0][m], bfr[0][n], acc[m][n], 0, 0, 0);
#pragma unroll
        for (int m = 0; m < 4; ++m)
#pragma unroll
            for (int n = 0; n < NF; ++n)
                acc[m][n] = __builtin_amdgcn_mfma_f32_16x16x32_bf16(af[0][m], bfr[1][n], acc[m][n], 0, 0, 0);
#pragma unroll
        for (int m = 0; m < 4; ++m)
#pragma unroll
            for (int n = 0; n < NF; ++n)
                acc[m][n] = __builtin_amdgcn_mfma_f32_16x16x32_bf16(af[1][m], bfr[0][n], acc[m][n], 0, 0, 0);
#pragma unroll
        for (int m = 0; m < 4; ++m)
#pragma unroll
            for (int n = 0; n < NF; ++n)
                acc[m][n] = __builtin_amdgcn_mfma_f32_16x16x32_bf16(af[0][m], bfr[2][n], acc[m][n], 0, 0, 0);
#pragma unroll
        for (int m = 0; m < 4; ++m)
#pragma unroll
            for (int n = 0; n < NF; ++n)
                acc[m][n] = __builtin_amdgcn_mfma_f32_16x16x32_bf16(af[2][m], bfr[0][n], acc[m][n], 0, 0, 0);
#pragma unroll
        for (int m = 0; m < 4; ++m)
#pragma unroll
            for (int n = 0; n < NF; ++n)
                acc[m][n] = __builtin_amdgcn_mfma_f32_16x16x32_bf16(af[1][m], bfr[1][n], acc[m][n], 0, 0, 0);
        __syncthreads();
    }
    const int lr = l & 15, lq = (l >> 4) * 4;
#pragma unroll
    for (int n = 0; n < NF; ++n) {
        const int col = tn + wc * (BN / 2) + n * 16 + lr;
        const float bv = (EPI == 0 || EPI == 1) ? bias[col] : 0.0f;
#pragma unroll
        for (int m = 0; m < 4; ++m) {
            const int rbase = tm + wr * 64 + m * 16 + lq;
#pragma unroll
            for (int j = 0; j < 4; ++j) {
                float v = acc[m][n][j];
                if (EPI == 0) v += bv;
                if (EPI == 1) { v += bv; v = 0.5f * v * (1.0f + erff(v / 1.41421356237309515f)); }
                const size_t o = coff + (size_t)(rbase + j) * ldc + col;
                if (OUTS == 0) C[o] = v;
                else if (OUTS == 3) ((bf16*)C)[o] = __float2bfloat16(v);
                else split3(v, Oh[o], Om[o], Ol[o]);
            }
        }
    }
}

// ---------------- V-transpose: VT[z][d][s] from qkv planes ----------------
__global__ __launch_bounds__(256) void k_vt(const bf16* __restrict__ qh,
                                            const bf16* __restrict__ qm,
                                            const bf16* __restrict__ ql,
                                            bf16* __restrict__ vh, bf16* __restrict__ vm,
                                            bf16* __restrict__ vl) {
    __shared__ bf16 tile[64][72];
    const int sblk = blockIdx.x;           // 0..7
    const int z = blockIdx.y;              // 0..63
    const int b = z >> 2, h = z & 3;
    const int t = threadIdx.x;
    const int sr = t >> 2, c16 = (t & 3) * 16;
    const bf16* qp[3] = {qh, qm, ql};
    bf16* vp[3] = {vh, vm, vl};
    for (int p = 0; p < 3; ++p) {
        const bf16* src = qp[p] + (size_t)(b * Sc + sblk * 64 + sr) * 768 + 512 + h * 64 + c16;
        *(short8v*)&tile[sr][c16] = *(const short8v*)src;
        *(short8v*)&tile[sr][c16 + 8] = *(const short8v*)(src + 8);
        __syncthreads();
        bf16 out[16];
#pragma unroll
        for (int i = 0; i < 16; ++i) out[i] = tile[c16 + i][sr];
        bf16* dst = vp[p] + (size_t)(z * 64 + sr) * Sc + sblk * 64 + c16;
        *(short8v*)dst = *(short8v*)&out[0];
        *(short8v*)(dst + 8) = *(short8v*)&out[8];
        __syncthreads();
    }
}

// ======== fused attention (R8 version): pipelined LDS staging, issue-early ========
#define S_PASS(QA, KB)                                                                     \
    _Pragma("unroll") for (int m = 0; m < 2; ++m) _Pragma("unroll") for (int ks = 0; ks < 2; ++ks) \
        sa[m] = __builtin_amdgcn_mfma_f32_16x16x32_bf16(QA[m][ks], KB[ks], sa[m], 0, 0, 0);
#define PV_PASS(PA, VB)                                                                    \
    _Pragma("unroll") for (int m = 0; m < 2; ++m) _Pragma("unroll") for (int ks = 0; ks < 2; ++ks) \
        oa[m] = __builtin_amdgcn_mfma_f32_16x16x32_bf16(PA[m][ks], VB[ks], oa[m], 0, 0, 0);

__global__ __launch_bounds__(512) void k_attn(
    const bf16* __restrict__ qph, const bf16* __restrict__ qpm, const bf16* __restrict__ qpl,
    const bf16* __restrict__ vth, const bf16* __restrict__ vtm, const bf16* __restrict__ vtl,
    bf16* __restrict__ oh, bf16* __restrict__ om, bf16* __restrict__ ol) {
    extern __shared__ char smem[];
    float* S = (float*)smem;                        // 64 x 512 fp32, swizzled
    bf16* KV0 = (bf16*)(smem + 131072);             // 3 planes of [64][64]
    bf16* KV1 = KV0 + 4096;
    bf16* KV2 = KV1 + 4096;
    const int qc = blockIdx.x, z = blockIdx.y;
    const int b = z >> 2, hh = z & 3;
    const int t = threadIdx.x;
    const int w = t >> 6, lane = t & 63;
    const int lr = lane & 15, lkc = lane >> 4;      // lkc 0..3
    const int qg = w >> 2, kg = w & 3;
    const int r8 = t >> 3, c8 = t & 7;              // staging map
    const f32x4v zero = {0.f, 0.f, 0.f, 0.f};

    // Q A-frags in registers (one-time gather)
    short8v qf0[2][2], qf1[2][2], qf2[2][2];
#pragma unroll
    for (int m = 0; m < 2; ++m)
#pragma unroll
        for (int ks = 0; ks < 2; ++ks) {
            const size_t rbase = (size_t)(b * 512 + qc * 64 + qg * 32 + m * 16 + lr) * 768 + hh * 64 + ks * 32 + lkc * 8;
            qf0[m][ks] = *(const short8v*)(qph + rbase);
            qf1[m][ks] = *(const short8v*)(qpm + rbase);
            qf2[m][ks] = *(const short8v*)(qpl + rbase);
        }

    // stage K(0)
    {
        const size_t srow = (size_t)(b * 512 + 0 * 64 + r8) * 768 + 256 + hh * 64 + (c8 ^ (r8 & 7)) * 8;
        __builtin_amdgcn_global_load_lds((const __attribute__((address_space(1))) void*)(qph + srow),
                                         (__attribute__((address_space(3))) void*)(KV0 + r8 * 64 + c8 * 8), 16, 0, 0);
        __builtin_amdgcn_global_load_lds((const __attribute__((address_space(1))) void*)(qpm + srow),
                                         (__attribute__((address_space(3))) void*)(KV1 + r8 * 64 + c8 * 8), 16, 0, 0);
        __builtin_amdgcn_global_load_lds((const __attribute__((address_space(1))) void*)(qpl + srow),
                                         (__attribute__((address_space(3))) void*)(KV2 + r8 * 64 + c8 * 8), 16, 0, 0);
    }

    // ---- scores: S[q][kv] = (Q.K)/8 ----
    for (int kv = 0; kv < 8; ++kv) {
        __syncthreads();                             // K(kv) resident (vmcnt drained)
        short8v kb0[2], kb1[2], kb2[2];
#pragma unroll
        for (int ks = 0; ks < 2; ++ks) {
            const int row = kg * 16 + lr;
            const int sc = (ks * 4 + lkc) ^ (row & 7);
            kb0[ks] = *(const short8v*)(KV0 + row * 64 + sc * 8);
            kb1[ks] = *(const short8v*)(KV1 + row * 64 + sc * 8);
            kb2[ks] = *(const short8v*)(KV2 + row * 64 + sc * 8);
        }
        __syncthreads();                             // all reads done; KV buffer free
        if (kv < 7) {                                // issue-early: K(kv+1) overlaps compute
            const size_t srow = (size_t)(b * 512 + (kv + 1) * 64 + r8) * 768 + 256 + hh * 64 + (c8 ^ (r8 & 7)) * 8;
            __builtin_amdgcn_global_load_lds((const __attribute__((address_space(1))) void*)(qph + srow),
                                             (__attribute__((address_space(3))) void*)(KV0 + r8 * 64 + c8 * 8), 16, 0, 0);
            __builtin_amdgcn_global_load_lds((const __attribute__((address_space(1))) void*)(qpm + srow),
                                             (__attribute__((address_space(3))) void*)(KV1 + r8 * 64 + c8 * 8), 16, 0, 0);
            __builtin_amdgcn_global_load_lds((const __attribute__((address_space(1))) void*)(qpl + srow),
                                             (__attribute__((address_space(3))) void*)(KV2 + r8 * 64 + c8 * 8), 16, 0, 0);
        } else {                                     // prefetch V(0) under softmax
            const size_t srow = (size_t)(z * 64 + r8) * 512 + 0 * 64 + (c8 ^ (r8 & 7)) * 8;
            __builtin_amdgcn_global_load_lds((const __attribute__((address_space(1))) void*)(vth + srow),
                                             (__attribute__((address_space(3))) void*)(KV0 + r8 * 64 + c8 * 8), 16, 0, 0);
            __builtin_amdgcn_global_load_lds((const __attribute__((address_space(1))) void*)(vtm + srow),
                                             (__attribute__((address_space(3))) void*)(KV1 + r8 * 64 + c8 * 8), 16, 0, 0);
            __builtin_amdgcn_global_load_lds((const __attribute__((address_space(1))) void*)(vtl + srow),
                                             (__attribute__((address_space(3))) void*)(KV2 + r8 * 64 + c8 * 8), 16, 0, 0);
        }
        f32x4v sa[2] = {zero, zero};
        S_PASS(qf0, kb0) S_PASS(qf0, kb1) S_PASS(qf1, kb0)
        S_PASS(qf0, kb2) S_PASS(qf2, kb0) S_PASS(qf1, kb1)
#pragma unroll
        for (int m = 0; m < 2; ++m)
#pragma unroll
            for (int j = 0; j < 4; ++j) {
                const int row = qg * 32 + m * 16 + (lane >> 4) * 4 + j;
                const int col = kv * 64 + kg * 16 + lr;
                const int chunk = (col >> 2) ^ (row & 7);
                *(float*)((char*)S + row * 2048 + chunk * 16 + (col & 3) * 4) = sa[m][j] * 0.125f;
            }
    }
    __syncthreads();                                 // S complete; V(0) resident

    // ---- exact softmax per row (wave w owns rows w*8..w*8+7) ----
    for (int r = 0; r < 8; ++r) {
        const int row = w * 8 + r;
        char* rowp = (char*)S + row * 2048;
        const int sw = row & 7;
        float4 x0 = *(float4*)(rowp + ((2 * lane) ^ sw) * 16);
        float4 x1 = *(float4*)(rowp + ((2 * lane + 1) ^ sw) * 16);
        float mx = fmaxf(fmaxf(fmaxf(x0.x, x0.y), fmaxf(x0.z, x0.w)),
                         fmaxf(fmaxf(x1.x, x1.y), fmaxf(x1.z, x1.w)));
#pragma unroll
        for (int d = 1; d < 64; d <<= 1) mx = fmaxf(mx, __shfl_xor(mx, d));
        const float e0 = expf(x0.x - mx), e1 = expf(x0.y - mx), e2 = expf(x0.z - mx), e3 = expf(x0.w - mx);
        const float e4 = expf(x1.x - mx), e5 = expf(x1.y - mx), e6 = expf(x1.z - mx), e7 = expf(x1.w - mx);
        float sm = ((e0 + e1) + (e2 + e3)) + ((e4 + e5) + (e6 + e7));
#pragma unroll
        for (int d = 1; d < 64; d <<= 1) sm += __shfl_xor(sm, d);
        x0.x = e0 / sm; x0.y = e1 / sm; x0.z = e2 / sm; x0.w = e3 / sm;
        x1.x = e4 / sm; x1.y = e5 / sm; x1.z = e6 / sm; x1.w = e7 / sm;
        *(float4*)(rowp + ((2 * lane) ^ sw) * 16) = x0;
        *(float4*)(rowp + ((2 * lane + 1) ^ sw) * 16) = x1;
    }
    __syncthreads();

    // ---- PV: O[q][d] = sum_kv P[q][kv] * VT[d][kv] ----
    f32x4v oa[2] = {zero, zero};
    for (int kv = 0; kv < 8; ++kv) {
        if (kv > 0) __syncthreads();                 // V(kv) resident
        short8v vb0[2], vb1[2], vb2[2];
#pragma unroll
        for (int ks = 0; ks < 2; ++ks) {
            const int rowd = kg * 16 + lr;
            const int sc = (ks * 4 + lkc) ^ (rowd & 7);
            vb0[ks] = *(const short8v*)(KV0 + rowd * 64 + sc * 8);
            vb1[ks] = *(const short8v*)(KV1 + rowd * 64 + sc * 8);
            vb2[ks] = *(const short8v*)(KV2 + rowd * 64 + sc * 8);
        }
        __syncthreads();                             // reads done; KV free
        if (kv < 7) {
            const size_t srow = (size_t)(z * 64 + r8) * 512 + (kv + 1) * 64 + (c8 ^ (r8 & 7)) * 8;
            __builtin_amdgcn_global_load_lds((const __attribute__((address_space(1))) void*)(vth + srow),
                                             (__attribute__((address_space(3))) void*)(KV0 + r8 * 64 + c8 * 8), 16, 0, 0);
            __builtin_amdgcn_global_load_lds((const __attribute__((address_space(1))) void*)(vtm + srow),
                                             (__attribute__((address_space(3))) void*)(KV1 + r8 * 64 + c8 * 8), 16, 0, 0);
            __builtin_amdgcn_global_load_lds((const __attribute__((address_space(1))) void*)(vtl + srow),
                                             (__attribute__((address_space(3))) void*)(KV2 + r8 * 64 + c8 * 8), 16, 0, 0);
        }
        short8v pah[2][2], pam[2][2], pal[2][2];
#pragma unroll
        for (int m = 0; m < 2; ++m)
#pragma unroll
            for (int ks = 0; ks < 2; ++ks) {
                const int row = qg * 32 + m * 16 + lr;
                const int c0 = kv * 16 + ks * 8 + lkc * 2;
                char* rp = (char*)S + row * 2048;
                const float4 y0 = *(const float4*)(rp + (c0 ^ (row & 7)) * 16);
                const float4 y1 = *(const float4*)(rp + ((c0 + 1) ^ (row & 7)) * 16);
                const float yy[8] = {y0.x, y0.y, y0.z, y0.w, y1.x, y1.y, y1.z, y1.w};
                short8v hv, mv, lv;
#pragma unroll
                for (int i = 0; i < 8; ++i) {
                    bf16 a, bq, c;
                    split3(yy[i], a, bq, c);
                    hv[i] = *(const short*)&a; mv[i] = *(const short*)&bq; lv[i] = *(const short*)&c;
                }
                pah[m][ks] = hv; pam[m][ks] = mv; pal[m][ks] = lv;
            }
        PV_PASS(pah, vb0) PV_PASS(pah, vb1) PV_PASS(pam, vb0)
        PV_PASS(pah, vb2) PV_PASS(pal, vb0) PV_PASS(pam, vb1)
    }
    // epilogue: O planes [8192][256]
#pragma unroll
    for (int m = 0; m < 2; ++m)
#pragma unroll
        for (int j = 0; j < 4; ++j) {
            const int grow = b * 512 + qc * 64 + qg * 32 + m * 16 + (lane >> 4) * 4 + j;
            const int col = hh * 64 + kg * 16 + lr;
            const size_t o = (size_t)grow * 256 + col;
            split3(oa[m][j], oh[o], om[o], ol[o]);
        }
}

// ---------------- x = LayerNorm(x + res) * g + b (+ split planes, optional COMB pack) ----------------
__global__ __launch_bounds__(256) void k_add_ln(float* __restrict__ x,
                                                const float* __restrict__ res,
                                                const float* __restrict__ g,
                                                const float* __restrict__ b,
                                                bf16* __restrict__ xh, bf16* __restrict__ xm,
                                                bf16* __restrict__ xl,
                                                bf16* __restrict__ comb) {
    const size_t row = blockIdx.x;
    const int t = threadIdx.x;
    float v = x[row * Hc + t] + res[row * Hc + t];
    __shared__ float red[256];
    red[t] = v;
    __syncthreads();
    for (int s = 128; s > 0; s >>= 1) { if (t < s) red[t] += red[t + s]; __syncthreads(); }
    const float mean = red[0] * (1.0f / 256.0f);
    __syncthreads();
    const float d = v - mean;
    red[t] = d * d;
    __syncthreads();
    for (int s = 128; s > 0; s >>= 1) { if (t < s) red[t] += red[t + s]; __syncthreads(); }
    const float var = red[0] * (1.0f / 256.0f);
    const float out = d / sqrtf(var + 1e-5f) * g[t] + b[t];
    const size_t o = row * Hc + t;
    x[o] = out;
    split3(out, xh[o], xm[o], xl[o]);
    if (comb != nullptr) comb[row * CH + 768 + t] = __float2bfloat16(out);   // plan pack (final LN only)
}

// ---------------- LIF scan (both heads; 8-row load batches for ILP) ----------------
__global__ __launch_bounds__(256) void k_lif2(const float* __restrict__ lm,
                                              bf16* __restrict__ comb) {
    const int b = blockIdx.x;
    const int half = blockIdx.y;
    const int h = threadIdx.x;
    const float* p = lm + (size_t)b * Sc * 512 + half * 256 + h;
    bf16* o = comb + (size_t)b * Sc * CH + half * 256 + h;
    float mem = 0.0f;
    for (int s0 = 0; s0 < Sc; s0 += 8) {
        float xs[8];
#pragma unroll
        for (int q = 0; q < 8; ++q) xs[q] = p[(size_t)(s0 + q) * 512];
#pragma unroll
        for (int q = 0; q < 8; ++q) {
            const float reset = (mem > 1.0f) ? 1.0f : 0.0f;
            float t1 = 0.9f * mem;
            asm volatile("" : "+v"(t1));           // block FMA contraction: match np rounding
            float t2 = t1 + xs[q];
            asm volatile("" : "+v"(t2));
            mem = t2 - reset;
            o[(size_t)(s0 + q) * CH] = __float2bfloat16((mem > 1.0f) ? 1.0f : 0.0f);
        }
    }
}

// ---------------- halo-expanded conv input planes (vectorized short4) ----------------
__global__ __launch_bounds__(256) void k_aext3(const bf16* __restrict__ xh,
                                               const bf16* __restrict__ xm,
                                               const bf16* __restrict__ xl,
                                               bf16* __restrict__ aeh, bf16* __restrict__ aem,
                                               bf16* __restrict__ ael) {
    const int idx = blockIdx.x * 256 + threadIdx.x;   // < 1,572,864 (8192*768/4)
    const int row = idx / 192, c4 = idx % 192;        // c4: short4 index in 768-wide row
    const int c = c4 * 4;
    const int k = c >> 8, i = c & 255;
    const int b = row >> 9, s = row & 511;
    const int ss = s + k - 1;
    const size_t dst = (size_t)row * 768 + c;
    if (ss >= 0 && ss < Sc) {
        const size_t src = (size_t)(b * Sc + ss) * Hc + i;
        *(short4v*)(aeh + dst) = *(const short4v*)(xh + src);
        *(short4v*)(aem + dst) = *(const short4v*)(xm + src);
        *(short4v*)(ael + dst) = *(const short4v*)(xl + src);
    } else {
        const short4v z = {0, 0, 0, 0};
        *(short4v*)(aeh + dst) = z;
        *(short4v*)(aem + dst) = z;
        *(short4v*)(ael + dst) = z;
    }
}

// ======== head GEMM: 128x256 tile, BK=32, 4 waves, 48KB LDS, 3 blocks/CU ========
__device__ __forceinline__ void stageA32(const bf16* __restrict__ g, int rbase,
                                         bf16* lbase, int kt, int t) {
#pragma unroll
    for (int q = 0; q < 2; ++q) {
        const int f = q * 256 + t;
        const int rowt = f >> 2, chunk = f & 3;
        const int sch = chunk ^ ((rowt >> 1) & 3);
        const bf16* gp = g + (size_t)(rbase + rowt) * CH + kt * 32 + sch * 8;
        __builtin_amdgcn_global_load_lds((const __attribute__((address_space(1))) void*)gp,
                                         (__attribute__((address_space(3))) void*)(lbase + rowt * 32 + chunk * 8),
                                         16, 0, 0);
    }
}
__device__ __forceinline__ void stageB32(const bf16* __restrict__ g, int rbase, int rmax,
                                         bf16* lbase, int kt, int t) {
#pragma unroll
    for (int q = 0; q < 4; ++q) {
        const int f = q * 256 + t;
        const int rowt = f >> 2, chunk = f & 3;
        const int sch = chunk ^ ((rowt >> 1) & 3);
        int grow = rbase + rowt;
        if (grow > rmax) grow = rmax;
        const bf16* gp = g + (size_t)grow * CH + kt * 32 + sch * 8;
        __builtin_amdgcn_global_load_lds((const __attribute__((address_space(1))) void*)gp,
                                         (__attribute__((address_space(3))) void*)(lbase + rowt * 32 + chunk * 8),
                                         16, 0, 0);
    }
}

__global__ __launch_bounds__(256, 3) void k_head8(const bf16* __restrict__ Abf,
                                                  const bf16* __restrict__ Bbf,
                                                  const float* __restrict__ bias,
                                                  float* __restrict__ C) {
    __shared__ bf16 LA[2][128 * 32];
    __shared__ bf16 LB[2][256 * 32];
    const int t = threadIdx.x;
    const int w = t >> 6, lane = t & 63;
    const int wn = w;
    const int tm = blockIdx.x * 128, tn = blockIdx.y * 256;
    const int lr = lane & 15, lkc = lane >> 4;

    f32x4v acc[8][4];
    const f32x4v zero = {0.f, 0.f, 0.f, 0.f};
#pragma unroll
    for (int m = 0; m < 8; ++m)
#pragma unroll
        for (int n = 0; n < 4; ++n) acc[m][n] = zero;

    stageA32(Abf, tm, LA[0], 0, t);
    stageB32(Bbf, tn, Vc - 1, LB[0], 0, t);
    stageA32(Abf, tm, LA[1], 1, t);
    asm volatile("s_waitcnt vmcnt(2)" ::: "memory");
    __builtin_amdgcn_s_barrier();
    __builtin_amdgcn_sched_barrier(0);

    for (int kt = 0; kt < NT2; ++kt) {
        bf16* la = LA[kt & 1];
        bf16* lb = LB[kt & 1];
        bf16* lbN = LB[(kt + 1) & 1];
        short8v a[8], b[4];
#pragma unroll
        for (int m = 0; m < 8; ++m) {
            const int row = m * 16 + lr;
            const int sc = lkc ^ ((row >> 1) & 3);
            a[m] = *(const short8v*)(la + row * 32 + sc * 8);
        }
#pragma unroll
        for (int n = 0; n < 4; ++n) {
            const int row = wn * 64 + n * 16 + lr;
            const int sc = lkc ^ ((row >> 1) & 3);
            b[n] = *(const short8v*)(lb + row * 32 + sc * 8);
        }
        if (kt + 1 < NT2) stageB32(Bbf, tn, Vc - 1, lbN, kt + 1, t);
        __builtin_amdgcn_s_barrier();
        __builtin_amdgcn_sched_barrier(0);
        __builtin_amdgcn_s_setprio(1);
#pragma unroll
        for (int m = 0; m < 8; ++m)
#pragma unroll
            for (int n = 0; n < 2; ++n)
                acc[m][n] = __builtin_amdgcn_mfma_f32_16x16x32_bf16(a[m], b[n], acc[m][n], 0, 0, 0);
        __builtin_amdgcn_s_setprio(0);
        __builtin_amdgcn_s_barrier();
        __builtin_amdgcn_sched_barrier(0);
        if (kt + 2 < NT2) stageA32(Abf, tm, la, kt + 2, t);
        __builtin_amdgcn_s_setprio(1);
#pragma unroll
        for (int m = 0; m < 8; ++m)
#pragma unroll
            for (int n = 2; n < 4; ++n)
                acc[m][n] = __builtin_amdgcn_mfma_f32_16x16x32_bf16(a[m], b[n], acc[m][n], 0, 0, 0);
        __builtin_amdgcn_s_setprio(0);
        if (kt + 2 < NT2) asm volatile("s_waitcnt vmcnt(2)" ::: "memory");
        else              asm volatile("s_waitcnt vmcnt(0)" ::: "memory");
        __builtin_amdgcn_s_barrier();
        __builtin_amdgcn_sched_barrier(0);
    }
    const int lq = (lane >> 4) * 4;
#pragma unroll
    for (int n = 0; n < 4; ++n) {
        const int col = tn + wn * 64 + n * 16 + lr;
        if (col >= Vc) continue;
        const float bv = bias[col];
#pragma unroll
        for (int m = 0; m < 8; ++m) {
            const int rbase = tm + m * 16 + lq;
#pragma unroll
            for (int j = 0; j < 4; ++j)
                C[(size_t)(rbase + j) * Vc + col] = acc[m][n][j] + bv;
        }
    }
}

// ---------------- plan mean partials ----------------
__global__ __launch_bounds__(256) void k_pmean(const float* __restrict__ plan, float* __restrict__ pm2) {
    const int b = blockIdx.x, c = blockIdx.y;
    const int h = threadIdx.x;
    const float* p = plan + ((size_t)(b * Sc + c * 64)) * Hc + h;
    float s = 0.0f;
    for (int i = 0; i < 64; ++i) s += p[(size_t)i * Hc];
    pm2[((size_t)b * 8 + c) * Hc + h] = s;
}

// ---------------- read softmax + memory read ----------------
__global__ __launch_bounds__(256) void k_memread(const float* __restrict__ pm2,
                                                 const float* __restrict__ rw,
                                                 const float* __restrict__ rb,
                                                 const float* __restrict__ memm,
                                                 float* __restrict__ out) {
    const int b = blockIdx.x;
    const int t = threadIdx.x;
    __shared__ float pms[256];
    __shared__ float lg[64];
    __shared__ float sm[64];
    float v = 0.0f;
    for (int c = 0; c < 8; ++c) v += pm2[((size_t)b * 8 + c) * Hc + t];
    pms[t] = v * (1.0f / 512.0f);
    __syncthreads();
    if (t < 64) {
        float s = rb[t];
        const float* wrow = rw + (size_t)t * Hc;
        for (int i = 0; i < Hc; ++i) s = fmaf(wrow[i], pms[i], s);
        lg[t] = s;
    }
    __syncthreads();
    if (t == 0) {
        float mx = lg[0];
        for (int i = 1; i < 64; ++i) mx = fmaxf(mx, lg[i]);
        float ssum = 0.0f;
        for (int i = 0; i < 64; ++i) { const float e = expf(lg[i] - mx); sm[i] = e; ssum += e; }
        for (int i = 0; i < 64; ++i) sm[i] /= ssum;
    }
    __syncthreads();
    float s = 0.0f;
    for (int m = 0; m < 64; ++m) s = fmaf(sm[m], memm[(size_t)m * Hc + t], s);
    out[(size_t)b * Hc + t] = s;
}

extern "C" void kernel_launch(void* const* d_in, const int* in_sizes, int n_in,
                              void* d_out, int out_size, void* d_ws, size_t ws_size,
                              hipStream_t stream) {
    const int*   ids    = (const int*)  d_in[0];
    const float* embed  = (const float*)d_in[1];
    const float* pos    = (const float*)d_in[2];
    const float* qkv_w  = (const float*)d_in[3];
    const float* qkv_b  = (const float*)d_in[4];
    const float* out_w  = (const float*)d_in[5];
    const float* out_b  = (const float*)d_in[6];
    const float* ln1_g  = (const float*)d_in[7];
    const float* ln1_b  = (const float*)d_in[8];
    const float* ff1_w  = (const float*)d_in[9];
    const float* ff1_b  = (const float*)d_in[10];
    const float* ff2_w  = (const float*)d_in[11];
    const float* ff2_b  = (const float*)d_in[12];
    const float* ln2_g  = (const float*)d_in[13];
    const float* ln2_b  = (const float*)d_in[14];
    const float* log_w  = (const float*)d_in[15];
    const float* log_b  = (const float*)d_in[16];
    const float* mat_w  = (const float*)d_in[17];
    const float* mat_b  = (const float*)d_in[18];
    const float* conv_w = (const float*)d_in[19];
    const float* conv_b = (const float*)d_in[20];
    const float* read_w = (const float*)d_in[21];
    const float* read_b = (const float*)d_in[22];
    const float* memory = (const float*)d_in[23];
    const float* head_w = (const float*)d_in[24];
    const float* head_b = (const float*)d_in[25];

    char* wsb = (char*)d_ws;
    const size_t MB = 1ull << 20;
    float* X    = (float*)(wsb + 0);           // 8 MB [8192,256]
    bf16*  XH   = (bf16*)(wsb + 8 * MB);
    bf16*  XM   = (bf16*)(wsb + 12 * MB);
    bf16*  XL   = (bf16*)(wsb + 16 * MB);
    float* RES  = (float*)(wsb + 20 * MB);     // 8 MB
    bf16*  QPH  = (bf16*)(wsb + 28 * MB);      // 12 MB each [8192,768] planes
    bf16*  QPM  = (bf16*)(wsb + 40 * MB);
    bf16*  QPL  = (bf16*)(wsb + 52 * MB);
    bf16*  OH   = (bf16*)(wsb + 64 * MB);      // 4 MB each
    bf16*  OM   = (bf16*)(wsb + 68 * MB);
    bf16*  OL   = (bf16*)(wsb + 72 * MB);
    // ---- alias region 76..128 MB ----
    bf16*  VTH  = (bf16*)(wsb + 76 * MB);      // 4 MB each (attention phase)
    bf16*  VTM  = (bf16*)(wsb + 80 * MB);
    bf16*  VTL  = (bf16*)(wsb + 84 * MB);
    bf16*  H1H  = (bf16*)(wsb + 88 * MB);      // 8 MB each (ff phase; disjoint from VT)
    bf16*  H1M  = (bf16*)(wsb + 96 * MB);
    bf16*  H1L  = (bf16*)(wsb + 104 * MB);
    float* LOGMAT = (float*)(wsb + 76 * MB);   // 16 MB [8192,512] (post-loop)
    bf16*  AEH  = (bf16*)(wsb + 92 * MB);      // 12 MB each (post-loop)
    bf16*  AEM  = (bf16*)(wsb + 104 * MB);
    bf16*  AEL  = (bf16*)(wsb + 116 * MB);
    // ---------------------------------
    bf16*  COMB = (bf16*)(wsb + 128 * MB);     // 16 MB [8192,1024]
    bf16*  HWB  = (bf16*)(wsb + 144 * MB);     // 16 MB [8000,1024]
    bf16*  WP   = (bf16*)(wsb + 160 * MB);     // weight planes
    float* PM2  = (float*)(wsb + 64 * MB);     // [16,8,256] partials (reuse OH post-loop)

    float* logits = (float*)d_out;
    float* mread  = logits + (size_t)ROWS * Vc;

    // weight plane sub-offsets (elements)
    bf16* qkvwh = WP;             bf16* qkvwm = qkvwh + 393216; bf16* qkvwl = qkvwm + 393216;
    bf16* outwh = qkvwl + 393216; bf16* outwm = outwh + 131072; bf16* outwl = outwm + 131072;
    bf16* ff1wh = outwl + 131072; bf16* ff1wm = ff1wh + 262144; bf16* ff1wl = ff1wm + 262144;
    bf16* ff2wh = ff1wl + 262144; bf16* ff2wm = ff2wh + 262144; bf16* ff2wl = ff2wm + 262144;
    bf16* lmwh  = ff2wl + 262144; bf16* lmwm  = lmwh + 131072;  bf16* lmwl  = lmwm + 131072;
    bf16* w2h   = lmwl + 131072;  bf16* w2m   = w2h + 196608;   bf16* w2l   = w2m + 196608;
    float* LMB  = (float*)(w2l + 196608);      // [512] concat bias (after weight planes)

    hipFuncSetAttribute((const void*)k_attn, hipFuncAttributeMaxDynamicSharedMemorySize, 155648);

    // consolidated weight prep (one launch)
    k_prep<<<dim3(9921), 256, 0, stream>>>(
        qkv_w, out_w, ff1_w, ff2_w, log_w, mat_w, conv_w, head_w, log_b, mat_b,
        qkvwh, qkvwm, qkvwl, outwh, outwm, outwl, ff1wh, ff1wm, ff1wl,
        ff2wh, ff2wm, ff2wl, lmwh, lmwm, lmwl, w2h, w2m, w2l, HWB, LMB);

    k_embed<<<dim3(ROWS), 256, 0, stream>>>(ids, embed, pos, X, XH, XM, XL);
    for (int l = 0; l < 2; ++l) {
        // qkv -> QP planes [8192,768]
        k_bg3<0, 1, 128><<<dim3(64, 6, 1), 256, 0, stream>>>(
            XH, XM, XL,
            qkvwh + (size_t)l * 196608, qkvwm + (size_t)l * 196608, qkvwl + (size_t)l * 196608,
            qkv_b + l * 768, nullptr, QPH, QPM, QPL,
            256, 256, 256, 768, 0, 0, 0, 0, 0, 0);
        k_vt<<<dim3(8, 64), 256, 0, stream>>>(QPH, QPM, QPL, VTH, VTM, VTL);
        // fused scores + softmax + PV -> O planes (pipelined LDS staging)
        k_attn<<<dim3(8, 64), 512, 155648, stream>>>(QPH, QPM, QPL, VTH, VTM, VTL, OH, OM, OL);
        // out proj -> RES fp32
        k_bg3<0, 0, 64><<<dim3(64, 4, 1), 256, 0, stream>>>(
            OH, OM, OL,
            outwh + (size_t)l * 65536, outwm + (size_t)l * 65536, outwl + (size_t)l * 65536,
            out_b + l * 256, RES, nullptr, nullptr, nullptr,
            256, 256, 256, 256, 0, 0, 0, 0, 0, 0);
        k_add_ln<<<dim3(ROWS), 256, 0, stream>>>(X, RES, ln1_g + l * 256, ln1_b + l * 256,
                                                 XH, XM, XL, nullptr);
        // ff1 + gelu -> H1 planes
        k_bg3<1, 1, 128><<<dim3(64, 4, 1), 256, 0, stream>>>(
            XH, XM, XL,
            ff1wh + (size_t)l * 131072, ff1wm + (size_t)l * 131072, ff1wl + (size_t)l * 131072,
            ff1_b + l * 512, nullptr, H1H, H1M, H1L,
            256, 256, 256, 512, 0, 0, 0, 0, 0, 0);
        // ff2 -> RES fp32
        k_bg3<0, 0, 64><<<dim3(64, 4, 1), 256, 0, stream>>>(
            H1H, H1M, H1L,
            ff2wh + (size_t)l * 131072, ff2wm + (size_t)l * 131072, ff2wl + (size_t)l * 131072,
            ff2_b + l * 256, RES, nullptr, nullptr, nullptr,
            512, 512, 512, 256, 0, 0, 0, 0, 0, 0);
        // final LN also packs plan into COMB (cols 768..1023)
        k_add_ln<<<dim3(ROWS), 256, 0, stream>>>(X, RES, ln2_g + l * 256, ln2_b + l * 256,
                                                 XH, XM, XL, (l == 1) ? COMB : nullptr);
    }
    // plan = X; fused log+mat projection -> LOGMAT [8192,512]
    k_bg3<0, 0, 128><<<dim3(64, 4, 1), 256, 0, stream>>>(
        XH, XM, XL, lmwh, lmwm, lmwl, LMB, LOGMAT, nullptr, nullptr, nullptr,
        256, 256, 256, 512, 0, 0, 0, 0, 0, 0);
    k_aext3<<<dim3(6144), 256, 0, stream>>>(XH, XM, XL, AEH, AEM, AEL);
    k_lif2<<<dim3(Bc, 2), 256, 0, stream>>>(LOGMAT, COMB);
    // conv as GEMM -> bf16 directly into COMB cols 512..767 (OUTS=3)
    k_bg3<0, 3, 64><<<dim3(64, 4, 1), 256, 0, stream>>>(
        AEH, AEM, AEL, w2h, w2m, w2l, conv_b, (float*)(COMB + 512), nullptr, nullptr, nullptr,
        768, 768, 768, CH, 0, 0, 0, 0, 0, 0);
    k_head8<<<dim3(64, 32), 256, 0, stream>>>(COMB, HWB, head_b, logits);
    k_pmean<<<dim3(Bc, 8), 256, 0, stream>>>(X, PM2);
    k_memread<<<dim3(Bc), 256, 0, stream>>>(PM2, read_w, read_b, memory, mread);
}

// Round 14
// 735.815 us; speedup vs baseline: 1.6727x; 1.6593x over previous
//
#include <hip/hip_runtime.h>
#include <hip/hip_bf16.h>

// Problem constants
constexpr int Bc = 16, Sc = 512, Hc = 256, Vc = 8000, NHc = 4, HDc = 64;
constexpr int FFc = 512, Mc = 64;
constexpr int ROWS = Bc * Sc;      // 8192
constexpr int CH = 4 * Hc;         // 1024
constexpr int NT2 = CH / 32;       // 32 K-tiles (BK=32) for the head GEMM

typedef __attribute__((ext_vector_type(4))) float f32x4v;
typedef __attribute__((ext_vector_type(8))) short short8v;
typedef __attribute__((ext_vector_type(4))) short short4v;
typedef __hip_bfloat16 bf16;

// ---- 3-way bf16 split: x = h + m + l + O(2^-27 |x|) ----
__device__ inline void split3(float x, bf16& h, bf16& m, bf16& l) {
    h = __float2bfloat16(x);
    const float r = x - __bfloat162float(h);   // exact
    m = __float2bfloat16(r);
    const float r2 = r - __bfloat162float(m);  // exact
    l = __float2bfloat16(r2);
}

// ---------------- consolidated weight prep (one launch) ----------------
__device__ __forceinline__ void split_range(const float* __restrict__ in,
                                            bf16* __restrict__ h, bf16* __restrict__ m,
                                            bf16* __restrict__ l, int blk, int t) {
    const size_t i = ((size_t)blk * 256 + t) * 4;
    const float4 v = *(const float4*)&in[i];
    split3(v.x, h[i + 0], m[i + 0], l[i + 0]);
    split3(v.y, h[i + 1], m[i + 1], l[i + 1]);
    split3(v.z, h[i + 2], m[i + 2], l[i + 2]);
    split3(v.w, h[i + 3], m[i + 3], l[i + 3]);
}

__global__ __launch_bounds__(256) void k_prep(
    const float* __restrict__ qkv_w, const float* __restrict__ out_w,
    const float* __restrict__ ff1_w, const float* __restrict__ ff2_w,
    const float* __restrict__ log_w, const float* __restrict__ mat_w,
    const float* __restrict__ conv_w, const float* __restrict__ head_w,
    const float* __restrict__ log_b, const float* __restrict__ mat_b,
    bf16* qkvwh, bf16* qkvwm, bf16* qkvwl,
    bf16* outwh, bf16* outwm, bf16* outwl,
    bf16* ff1wh, bf16* ff1wm, bf16* ff1wl,
    bf16* ff2wh, bf16* ff2wm, bf16* ff2wl,
    bf16* lmwh, bf16* lmwm, bf16* lmwl,
    bf16* w2h, bf16* w2m, bf16* w2l,
    bf16* hwb, float* lmb) {
    const int blk = blockIdx.x;
    const int t = threadIdx.x;
    if (blk < 384) {
        split_range(qkv_w, qkvwh, qkvwm, qkvwl, blk, t);
    } else if (blk < 512) {
        split_range(out_w, outwh, outwm, outwl, blk - 384, t);
    } else if (blk < 768) {
        split_range(ff1_w, ff1wh, ff1wm, ff1wl, blk - 512, t);
    } else if (blk < 1024) {
        split_range(ff2_w, ff2wh, ff2wm, ff2wl, blk - 768, t);
    } else if (blk < 1088) {
        split_range(log_w, lmwh, lmwm, lmwl, blk - 1024, t);
    } else if (blk < 1152) {
        split_range(mat_w, lmwh + 65536, lmwm + 65536, lmwl + 65536, blk - 1088, t);
    } else if (blk < 1920) {
        const int idx = (blk - 1152) * 256 + t;       // conv re-layout + split
        const int o = idx / 768, rem = idx % 768;
        const int k = rem >> 8, i = rem & 255;
        split3(conv_w[(size_t)o * 768 + i * 3 + k], w2h[idx], w2m[idx], w2l[idx]);
    } else if (blk < 9920) {
        const size_t i = ((size_t)(blk - 1920) * 256 + t) * 4;   // head_w -> bf16, vector store
        const float4 v = *(const float4*)&head_w[i];
        bf16 b0 = __float2bfloat16(v.x), b1 = __float2bfloat16(v.y);
        bf16 b2 = __float2bfloat16(v.z), b3 = __float2bfloat16(v.w);
        short4v sv;
        sv[0] = *(const short*)&b0; sv[1] = *(const short*)&b1;
        sv[2] = *(const short*)&b2; sv[3] = *(const short*)&b3;
        *(short4v*)(hwb + i) = sv;
    } else {
        lmb[t] = log_b[t];
        lmb[256 + t] = mat_b[t];
    }
}

// ---------------- embed + pos (+ split planes) ----------------
__global__ __launch_bounds__(256) void k_embed(const int* __restrict__ ids,
                                               const float* __restrict__ emb,
                                               const float* __restrict__ pos,
                                               float* __restrict__ x,
                                               bf16* __restrict__ xh, bf16* __restrict__ xm,
                                               bf16* __restrict__ xl) {
    const int r = blockIdx.x;
    const int h = threadIdx.x;
    const int s = r & (Sc - 1);
    const int id = ids[r];
    const float v = emb[(size_t)id * Hc + h] + pos[(size_t)s * Hc + h];
    const size_t o = (size_t)r * Hc + h;
    x[o] = v;
    split3(v, xh[o], xm[o], xl[o]);
}

// ======== batched bf16x3 MFMA GEMM: C = A[M,K] @ B[N,K]^T ========
// EPI: 0 = +bias, 1 = gelu(x+bias), 3 = none
// OUTS: 0 = fp32 C, 1 = split3 planes, 3 = bf16 write into C (cast) at ldc stride
template <int EPI, int OUTS, int BN>
__global__ __launch_bounds__(256) void k_bg3(
    const bf16* __restrict__ Ah, const bf16* __restrict__ Am, const bf16* __restrict__ Al,
    const bf16* __restrict__ Bh, const bf16* __restrict__ Bm, const bf16* __restrict__ Bl,
    const float* __restrict__ bias, float* __restrict__ C,
    bf16* __restrict__ Oh, bf16* __restrict__ Om, bf16* __restrict__ Ol,
    int K, int lda, int ldb, int ldc,
    long zA2, long zA1, long zB2, long zB1, long zC2, long zC1) {
    constexpr int NF = BN / 32;
    __shared__ bf16 As[3][128 * 32];
    __shared__ bf16 Bs[3][BN * 32];
    const int z = blockIdx.z, z2 = z >> 2, z1 = z & 3;
    const size_t aoff = (size_t)z2 * zA2 + (size_t)z1 * zA1;
    const size_t boff = (size_t)z2 * zB2 + (size_t)z1 * zB1;
    const size_t coff = (size_t)z2 * zC2 + (size_t)z1 * zC1;
    const int t = threadIdx.x;
    const int tm = blockIdx.x * 128, tn = blockIdx.y * BN;
    const int w = t >> 6, l = t & 63;
    const int wr = w >> 1, wc = w & 1;
    const bf16* Ap[3] = {Ah, Am, Al};
    const bf16* Bp[3] = {Bh, Bm, Bl};
    f32x4v acc[4][NF];
    const f32x4v zero = {0.f, 0.f, 0.f, 0.f};
#pragma unroll
    for (int i = 0; i < 4; ++i)
#pragma unroll
        for (int j = 0; j < NF; ++j) acc[i][j] = zero;

    for (int kt = 0; kt < K; kt += 32) {
#pragma unroll
        for (int p = 0; p < 3; ++p) {
#pragma unroll
            for (int j = 0; j < 2; ++j) {
                const int c = j * 256 + t;
                const int row = c >> 2, kc = c & 3;
                const int skc = kc ^ ((row >> 1) & 3);
                const bf16* ga = Ap[p] + aoff + (size_t)(tm + row) * lda + kt + skc * 8;
                __builtin_amdgcn_global_load_lds((const __attribute__((address_space(1))) void*)ga,
                                                 (__attribute__((address_space(3))) void*)(&As[p][0] + c * 8),
                                                 16, 0, 0);
            }
            if (BN == 128) {
#pragma unroll
                for (int j = 0; j < 2; ++j) {
                    const int c = j * 256 + t;
                    const int row = c >> 2, kc = c & 3;
                    const int skc = kc ^ ((row >> 1) & 3);
                    const bf16* gb = Bp[p] + boff + (size_t)(tn + row) * ldb + kt + skc * 8;
                    __builtin_amdgcn_global_load_lds((const __attribute__((address_space(1))) void*)gb,
                                                     (__attribute__((address_space(3))) void*)(&Bs[p][0] + c * 8),
                                                     16, 0, 0);
                }
            } else {
                const int c = t;
                const int row = c >> 2, kc = c & 3;
                const int skc = kc ^ ((row >> 1) & 3);
                const bf16* gb = Bp[p] + boff + (size_t)(tn + row) * ldb + kt + skc * 8;
                __builtin_amdgcn_global_load_lds((const __attribute__((address_space(1))) void*)gb,
                                                 (__attribute__((address_space(3))) void*)(&Bs[p][0] + c * 8),
                                                 16, 0, 0);
            }
        }
        __syncthreads();
        const int lr = l & 15, lkc = l >> 4;
        short8v af[3][4], bfr[3][NF];
#pragma unroll
        for (int p = 0; p < 3; ++p)
#pragma unroll
            for (int m = 0; m < 4; ++m) {
                const int row = wr * 64 + m * 16 + lr;
                const int sc = lkc ^ ((row >> 1) & 3);
                af[p][m] = *(const short8v*)(&As[p][0] + row * 32 + sc * 8);
            }
#pragma unroll
        for (int p = 0; p < 3; ++p)
#pragma unroll
            for (int n = 0; n < NF; ++n) {
                const int row = wc * (BN / 2) + n * 16 + lr;
                const int sc = lkc ^ ((row >> 1) & 3);
                bfr[p][n] = *(const short8v*)(&Bs[p][0] + row * 32 + sc * 8);
            }
        // 6 term passes: hh, hm, mh, hl, lh, mm
#pragma unroll
        for (int m = 0; m < 4; ++m)
#pragma unroll
            for (int n = 0; n < NF; ++n)
                acc[m][n] = __builtin_amdgcn_mfma_f32_16x16x32_bf16(af[0][m], bfr[0][n], acc[m][n], 0, 0, 0);
#pragma unroll
        for (int m = 0; m < 4; ++m)
#pragma unroll
            for (int n = 0; n < NF; ++n)
                acc[m][n] = __builtin_amdgcn_mfma_f32_16x16x32_bf16(af[0][m], bfr[1][n], acc[m][n], 0, 0, 0);
#pragma unroll
        for (int m = 0; m < 4; ++m)
#pragma unroll
            for (int n = 0; n < NF; ++n)
                acc[m][n] = __builtin_amdgcn_mfma_f32_16x16x32_bf16(af[1][m], bfr[0][n], acc[m][n], 0, 0, 0);
#pragma unroll
        for (int m = 0; m < 4; ++m)
#pragma unroll
            for (int n = 0; n < NF; ++n)
                acc[m][n] = __builtin_amdgcn_mfma_f32_16x16x32_bf16(af[0][m], bfr[2][n], acc[m][n], 0, 0, 0);
#pragma unroll
        for (int m = 0; m < 4; ++m)
#pragma unroll
            for (int n = 0; n < NF; ++n)
                acc[m][n] = __builtin_amdgcn_mfma_f32_16x16x32_bf16(af[2][m], bfr[0][n], acc[m][n], 0, 0, 0);
#pragma unroll
        for (int m = 0; m < 4; ++m)
#pragma unroll
            for (int n = 0; n < NF; ++n)
                acc[m][n] = __builtin_amdgcn_mfma_f32_16x16x32_bf16(af[1][m], bfr[1][n], acc[m][n], 0, 0, 0);
        __syncthreads();
    }
    const int lr = l & 15, lq = (l >> 4) * 4;
#pragma unroll
    for (int n = 0; n < NF; ++n) {
        const int col = tn + wc * (BN / 2) + n * 16 + lr;
        const float bv = (EPI == 0 || EPI == 1) ? bias[col] : 0.0f;
#pragma unroll
        for (int m = 0; m < 4; ++m) {
            const int rbase = tm + wr * 64 + m * 16 + lq;
#pragma unroll
            for (int j = 0; j < 4; ++j) {
                float v = acc[m][n][j];
                if (EPI == 0) v += bv;
                if (EPI == 1) { v += bv; v = 0.5f * v * (1.0f + erff(v / 1.41421356237309515f)); }
                const size_t o = coff + (size_t)(rbase + j) * ldc + col;
                if (OUTS == 0) C[o] = v;
                else if (OUTS == 3) ((bf16*)C)[o] = __float2bfloat16(v);
                else split3(v, Oh[o], Om[o], Ol[o]);
            }
        }
    }
}

// ---------------- V-transpose: VT[z][d][s] from qkv planes ----------------
__global__ __launch_bounds__(256) void k_vt(const bf16* __restrict__ qh,
                                            const bf16* __restrict__ qm,
                                            const bf16* __restrict__ ql,
                                            bf16* __restrict__ vh, bf16* __restrict__ vm,
                                            bf16* __restrict__ vl) {
    __shared__ bf16 tile[64][72];
    const int sblk = blockIdx.x;           // 0..7
    const int z = blockIdx.y;              // 0..63
    const int b = z >> 2, h = z & 3;
    const int t = threadIdx.x;
    const int sr = t >> 2, c16 = (t & 3) * 16;
    const bf16* qp[3] = {qh, qm, ql};
    bf16* vp[3] = {vh, vm, vl};
    for (int p = 0; p < 3; ++p) {
        const bf16* src = qp[p] + (size_t)(b * Sc + sblk * 64 + sr) * 768 + 512 + h * 64 + c16;
        *(short8v*)&tile[sr][c16] = *(const short8v*)src;
        *(short8v*)&tile[sr][c16 + 8] = *(const short8v*)(src + 8);
        __syncthreads();
        bf16 out[16];
#pragma unroll
        for (int i = 0; i < 16; ++i) out[i] = tile[c16 + i][sr];
        bf16* dst = vp[p] + (size_t)(z * 64 + sr) * Sc + sblk * 64 + c16;
        *(short8v*)dst = *(short8v*)&out[0];
        *(short8v*)(dst + 8) = *(short8v*)&out[8];
        __syncthreads();
    }
}

// ======== fused attention (R8 version): pipelined LDS staging, issue-early ========
#define S_PASS(QA, KB)                                                                     \
    _Pragma("unroll") for (int m = 0; m < 2; ++m) _Pragma("unroll") for (int ks = 0; ks < 2; ++ks) \
        sa[m] = __builtin_amdgcn_mfma_f32_16x16x32_bf16(QA[m][ks], KB[ks], sa[m], 0, 0, 0);
#define PV_PASS(PA, VB)                                                                    \
    _Pragma("unroll") for (int m = 0; m < 2; ++m) _Pragma("unroll") for (int ks = 0; ks < 2; ++ks) \
        oa[m] = __builtin_amdgcn_mfma_f32_16x16x32_bf16(PA[m][ks], VB[ks], oa[m], 0, 0, 0);

__global__ __launch_bounds__(512) void k_attn(
    const bf16* __restrict__ qph, const bf16* __restrict__ qpm, const bf16* __restrict__ qpl,
    const bf16* __restrict__ vth, const bf16* __restrict__ vtm, const bf16* __restrict__ vtl,
    bf16* __restrict__ oh, bf16* __restrict__ om, bf16* __restrict__ ol) {
    extern __shared__ char smem[];
    float* S = (float*)smem;                        // 64 x 512 fp32, swizzled
    bf16* KV0 = (bf16*)(smem + 131072);             // 3 planes of [64][64]
    bf16* KV1 = KV0 + 4096;
    bf16* KV2 = KV1 + 4096;
    const int qc = blockIdx.x, z = blockIdx.y;
    const int b = z >> 2, hh = z & 3;
    const int t = threadIdx.x;
    const int w = t >> 6, lane = t & 63;
    const int lr = lane & 15, lkc = lane >> 4;      // lkc 0..3
    const int qg = w >> 2, kg = w & 3;
    const int r8 = t >> 3, c8 = t & 7;              // staging map
    const f32x4v zero = {0.f, 0.f, 0.f, 0.f};

    // Q A-frags in registers (one-time gather)
    short8v qf0[2][2], qf1[2][2], qf2[2][2];
#pragma unroll
    for (int m = 0; m < 2; ++m)
#pragma unroll
        for (int ks = 0; ks < 2; ++ks) {
            const size_t rbase = (size_t)(b * 512 + qc * 64 + qg * 32 + m * 16 + lr) * 768 + hh * 64 + ks * 32 + lkc * 8;
            qf0[m][ks] = *(const short8v*)(qph + rbase);
            qf1[m][ks] = *(const short8v*)(qpm + rbase);
            qf2[m][ks] = *(const short8v*)(qpl + rbase);
        }

    // stage K(0)
    {
        const size_t srow = (size_t)(b * 512 + 0 * 64 + r8) * 768 + 256 + hh * 64 + (c8 ^ (r8 & 7)) * 8;
        __builtin_amdgcn_global_load_lds((const __attribute__((address_space(1))) void*)(qph + srow),
                                         (__attribute__((address_space(3))) void*)(KV0 + r8 * 64 + c8 * 8), 16, 0, 0);
        __builtin_amdgcn_global_load_lds((const __attribute__((address_space(1))) void*)(qpm + srow),
                                         (__attribute__((address_space(3))) void*)(KV1 + r8 * 64 + c8 * 8), 16, 0, 0);
        __builtin_amdgcn_global_load_lds((const __attribute__((address_space(1))) void*)(qpl + srow),
                                         (__attribute__((address_space(3))) void*)(KV2 + r8 * 64 + c8 * 8), 16, 0, 0);
    }

    // ---- scores: S[q][kv] = (Q.K)/8 ----
    for (int kv = 0; kv < 8; ++kv) {
        __syncthreads();                             // K(kv) resident (vmcnt drained)
        short8v kb0[2], kb1[2], kb2[2];
#pragma unroll
        for (int ks = 0; ks < 2; ++ks) {
            const int row = kg * 16 + lr;
            const int sc = (ks * 4 + lkc) ^ (row & 7);
            kb0[ks] = *(const short8v*)(KV0 + row * 64 + sc * 8);
            kb1[ks] = *(const short8v*)(KV1 + row * 64 + sc * 8);
            kb2[ks] = *(const short8v*)(KV2 + row * 64 + sc * 8);
        }
        __syncthreads();                             // all reads done; KV buffer free
        if (kv < 7) {                                // issue-early: K(kv+1) overlaps compute
            const size_t srow = (size_t)(b * 512 + (kv + 1) * 64 + r8) * 768 + 256 + hh * 64 + (c8 ^ (r8 & 7)) * 8;
            __builtin_amdgcn_global_load_lds((const __attribute__((address_space(1))) void*)(qph + srow),
                                             (__attribute__((address_space(3))) void*)(KV0 + r8 * 64 + c8 * 8), 16, 0, 0);
            __builtin_amdgcn_global_load_lds((const __attribute__((address_space(1))) void*)(qpm + srow),
                                             (__attribute__((address_space(3))) void*)(KV1 + r8 * 64 + c8 * 8), 16, 0, 0);
            __builtin_amdgcn_global_load_lds((const __attribute__((address_space(1))) void*)(qpl + srow),
                                             (__attribute__((address_space(3))) void*)(KV2 + r8 * 64 + c8 * 8), 16, 0, 0);
        } else {                                     // prefetch V(0) under softmax
            const size_t srow = (size_t)(z * 64 + r8) * 512 + 0 * 64 + (c8 ^ (r8 & 7)) * 8;
            __builtin_amdgcn_global_load_lds((const __attribute__((address_space(1))) void*)(vth + srow),
                                             (__attribute__((address_space(3))) void*)(KV0 + r8 * 64 + c8 * 8), 16, 0, 0);
            __builtin_amdgcn_global_load_lds((const __attribute__((address_space(1))) void*)(vtm + srow),
                                             (__attribute__((address_space(3))) void*)(KV1 + r8 * 64 + c8 * 8), 16, 0, 0);
            __builtin_amdgcn_global_load_lds((const __attribute__((address_space(1))) void*)(vtl + srow),
                                             (__attribute__((address_space(3))) void*)(KV2 + r8 * 64 + c8 * 8), 16, 0, 0);
        }
        f32x4v sa[2] = {zero, zero};
        S_PASS(qf0, kb0) S_PASS(qf0, kb1) S_PASS(qf1, kb0)
        S_PASS(qf0, kb2) S_PASS(qf2, kb0) S_PASS(qf1, kb1)
#pragma unroll
        for (int m = 0; m < 2; ++m)
#pragma unroll
            for (int j = 0; j < 4; ++j) {
                const int row = qg * 32 + m * 16 + (lane >> 4) * 4 + j;
                const int col = kv * 64 + kg * 16 + lr;
                const int chunk = (col >> 2) ^ (row & 7);
                *(float*)((char*)S + row * 2048 + chunk * 16 + (col & 3) * 4) = sa[m][j] * 0.125f;
            }
    }
    __syncthreads();                                 // S complete; V(0) resident

    // ---- exact softmax per row (wave w owns rows w*8..w*8+7) ----
    for (int r = 0; r < 8; ++r) {
        const int row = w * 8 + r;
        char* rowp = (char*)S + row * 2048;
        const int sw = row & 7;
        float4 x0 = *(float4*)(rowp + ((2 * lane) ^ sw) * 16);
        float4 x1 = *(float4*)(rowp + ((2 * lane + 1) ^ sw) * 16);
        float mx = fmaxf(fmaxf(fmaxf(x0.x, x0.y), fmaxf(x0.z, x0.w)),
                         fmaxf(fmaxf(x1.x, x1.y), fmaxf(x1.z, x1.w)));
#pragma unroll
        for (int d = 1; d < 64; d <<= 1) mx = fmaxf(mx, __shfl_xor(mx, d));
        const float e0 = expf(x0.x - mx), e1 = expf(x0.y - mx), e2 = expf(x0.z - mx), e3 = expf(x0.w - mx);
        const float e4 = expf(x1.x - mx), e5 = expf(x1.y - mx), e6 = expf(x1.z - mx), e7 = expf(x1.w - mx);
        float sm = ((e0 + e1) + (e2 + e3)) + ((e4 + e5) + (e6 + e7));
#pragma unroll
        for (int d = 1; d < 64; d <<= 1) sm += __shfl_xor(sm, d);
        x0.x = e0 / sm; x0.y = e1 / sm; x0.z = e2 / sm; x0.w = e3 / sm;
        x1.x = e4 / sm; x1.y = e5 / sm; x1.z = e6 / sm; x1.w = e7 / sm;
        *(float4*)(rowp + ((2 * lane) ^ sw) * 16) = x0;
        *(float4*)(rowp + ((2 * lane + 1) ^ sw) * 16) = x1;
    }
    __syncthreads();

    // ---- PV: O[q][d] = sum_kv P[q][kv] * VT[d][kv] ----
    f32x4v oa[2] = {zero, zero};
    for (int kv = 0; kv < 8; ++kv) {
        if (kv > 0) __syncthreads();                 // V(kv) resident
        short8v vb0[2], vb1[2], vb2[2];
#pragma unroll
        for (int ks = 0; ks < 2; ++ks) {
            const int rowd = kg * 16 + lr;
            const int sc = (ks * 4 + lkc) ^ (rowd & 7);
            vb0[ks] = *(const short8v*)(KV0 + rowd * 64 + sc * 8);
            vb1[ks] = *(const short8v*)(KV1 + rowd * 64 + sc * 8);
            vb2[ks] = *(const short8v*)(KV2 + rowd * 64 + sc * 8);
        }
        __syncthreads();                             // reads done; KV free
        if (kv < 7) {
            const size_t srow = (size_t)(z * 64 + r8) * 512 + (kv + 1) * 64 + (c8 ^ (r8 & 7)) * 8;
            __builtin_amdgcn_global_load_lds((const __attribute__((address_space(1))) void*)(vth + srow),
                                             (__attribute__((address_space(3))) void*)(KV0 + r8 * 64 + c8 * 8), 16, 0, 0);
            __builtin_amdgcn_global_load_lds((const __attribute__((address_space(1))) void*)(vtm + srow),
                                             (__attribute__((address_space(3))) void*)(KV1 + r8 * 64 + c8 * 8), 16, 0, 0);
            __builtin_amdgcn_global_load_lds((const __attribute__((address_space(1))) void*)(vtl + srow),
                                             (__attribute__((address_space(3))) void*)(KV2 + r8 * 64 + c8 * 8), 16, 0, 0);
        }
        short8v pah[2][2], pam[2][2], pal[2][2];
#pragma unroll
        for (int m = 0; m < 2; ++m)
#pragma unroll
            for (int ks = 0; ks < 2; ++ks) {
                const int row = qg * 32 + m * 16 + lr;
                const int c0 = kv * 16 + ks * 8 + lkc * 2;
                char* rp = (char*)S + row * 2048;
                const float4 y0 = *(const float4*)(rp + (c0 ^ (row & 7)) * 16);
                const float4 y1 = *(const float4*)(rp + ((c0 + 1) ^ (row & 7)) * 16);
                const float yy[8] = {y0.x, y0.y, y0.z, y0.w, y1.x, y1.y, y1.z, y1.w};
                short8v hv, mv, lv;
#pragma unroll
                for (int i = 0; i < 8; ++i) {
                    bf16 a, bq, c;
                    split3(yy[i], a, bq, c);
                    hv[i] = *(const short*)&a; mv[i] = *(const short*)&bq; lv[i] = *(const short*)&c;
                }
                pah[m][ks] = hv; pam[m][ks] = mv; pal[m][ks] = lv;
            }
        PV_PASS(pah, vb0) PV_PASS(pah, vb1) PV_PASS(pam, vb0)
        PV_PASS(pah, vb2) PV_PASS(pal, vb0) PV_PASS(pam, vb1)
    }
    // epilogue: O planes [8192][256]
#pragma unroll
    for (int m = 0; m < 2; ++m)
#pragma unroll
        for (int j = 0; j < 4; ++j) {
            const int grow = b * 512 + qc * 64 + qg * 32 + m * 16 + (lane >> 4) * 4 + j;
            const int col = hh * 64 + kg * 16 + lr;
            const size_t o = (size_t)grow * 256 + col;
            split3(oa[m][j], oh[o], om[o], ol[o]);
        }
}

// ---------------- x = LayerNorm(x + res) * g + b (+ split planes, optional COMB pack) ----------------
__global__ __launch_bounds__(256) void k_add_ln(float* __restrict__ x,
                                                const float* __restrict__ res,
                                                const float* __restrict__ g,
                                                const float* __restrict__ b,
                                                bf16* __restrict__ xh, bf16* __restrict__ xm,
                                                bf16* __restrict__ xl,
                                                bf16* __restrict__ comb) {
    const size_t row = blockIdx.x;
    const int t = threadIdx.x;
    float v = x[row * Hc + t] + res[row * Hc + t];
    __shared__ float red[256];
    red[t] = v;
    __syncthreads();
    for (int s = 128; s > 0; s >>= 1) { if (t < s) red[t] += red[t + s]; __syncthreads(); }
    const float mean = red[0] * (1.0f / 256.0f);
    __syncthreads();
    const float d = v - mean;
    red[t] = d * d;
    __syncthreads();
    for (int s = 128; s > 0; s >>= 1) { if (t < s) red[t] += red[t + s]; __syncthreads(); }
    const float var = red[0] * (1.0f / 256.0f);
    const float out = d / sqrtf(var + 1e-5f) * g[t] + b[t];
    const size_t o = row * Hc + t;
    x[o] = out;
    split3(out, xh[o], xm[o], xl[o]);
    if (comb != nullptr) comb[row * CH + 768 + t] = __float2bfloat16(out);   // plan pack (final LN only)
}

// ---------------- LIF scan (both heads; 8-row load batches for ILP) ----------------
__global__ __launch_bounds__(256) void k_lif2(const float* __restrict__ lm,
                                              bf16* __restrict__ comb) {
    const int b = blockIdx.x;
    const int half = blockIdx.y;
    const int h = threadIdx.x;
    const float* p = lm + (size_t)b * Sc * 512 + half * 256 + h;
    bf16* o = comb + (size_t)b * Sc * CH + half * 256 + h;
    float mem = 0.0f;
    for (int s0 = 0; s0 < Sc; s0 += 8) {
        float xs[8];
#pragma unroll
        for (int q = 0; q < 8; ++q) xs[q] = p[(size_t)(s0 + q) * 512];
#pragma unroll
        for (int q = 0; q < 8; ++q) {
            const float reset = (mem > 1.0f) ? 1.0f : 0.0f;
            float t1 = 0.9f * mem;
            asm volatile("" : "+v"(t1));           // block FMA contraction: match np rounding
            float t2 = t1 + xs[q];
            asm volatile("" : "+v"(t2));
            mem = t2 - reset;
            o[(size_t)(s0 + q) * CH] = __float2bfloat16((mem > 1.0f) ? 1.0f : 0.0f);
        }
    }
}

// ---------------- halo-expanded conv input planes (vectorized short4) ----------------
__global__ __launch_bounds__(256) void k_aext3(const bf16* __restrict__ xh,
                                               const bf16* __restrict__ xm,
                                               const bf16* __restrict__ xl,
                                               bf16* __restrict__ aeh, bf16* __restrict__ aem,
                                               bf16* __restrict__ ael) {
    const int idx = blockIdx.x * 256 + threadIdx.x;   // < 1,572,864 (8192*768/4)
    const int row = idx / 192, c4 = idx % 192;        // c4: short4 index in 768-wide row
    const int c = c4 * 4;
    const int k = c >> 8, i = c & 255;
    const int b = row >> 9, s = row & 511;
    const int ss = s + k - 1;
    const size_t dst = (size_t)row * 768 + c;
    if (ss >= 0 && ss < Sc) {
        const size_t src = (size_t)(b * Sc + ss) * Hc + i;
        *(short4v*)(aeh + dst) = *(const short4v*)(xh + src);
        *(short4v*)(aem + dst) = *(const short4v*)(xm + src);
        *(short4v*)(ael + dst) = *(const short4v*)(xl + src);
    } else {
        const short4v z = {0, 0, 0, 0};
        *(short4v*)(aeh + dst) = z;
        *(short4v*)(aem + dst) = z;
        *(short4v*)(ael + dst) = z;
    }
}

// ======== head GEMM: 128x256 tile, BK=32, 4 waves, 48KB LDS, 2 blocks/CU ========
__device__ __forceinline__ void stageA32(const bf16* __restrict__ g, int rbase,
                                         bf16* lbase, int kt, int t) {
#pragma unroll
    for (int q = 0; q < 2; ++q) {
        const int f = q * 256 + t;
        const int rowt = f >> 2, chunk = f & 3;
        const int sch = chunk ^ ((rowt >> 1) & 3);
        const bf16* gp = g + (size_t)(rbase + rowt) * CH + kt * 32 + sch * 8;
        __builtin_amdgcn_global_load_lds((const __attribute__((address_space(1))) void*)gp,
                                         (__attribute__((address_space(3))) void*)(lbase + rowt * 32 + chunk * 8),
                                         16, 0, 0);
    }
}
__device__ __forceinline__ void stageB32(const bf16* __restrict__ g, int rbase, int rmax,
                                         bf16* lbase, int kt, int t) {
#pragma unroll
    for (int q = 0; q < 4; ++q) {
        const int f = q * 256 + t;
        const int rowt = f >> 2, chunk = f & 3;
        const int sch = chunk ^ ((rowt >> 1) & 3);
        int grow = rbase + rowt;
        if (grow > rmax) grow = rmax;
        const bf16* gp = g + (size_t)grow * CH + kt * 32 + sch * 8;
        __builtin_amdgcn_global_load_lds((const __attribute__((address_space(1))) void*)gp,
                                         (__attribute__((address_space(3))) void*)(lbase + rowt * 32 + chunk * 8),
                                         16, 0, 0);
    }
}

__global__ __launch_bounds__(256, 2) void k_head8(const bf16* __restrict__ Abf,
                                                  const bf16* __restrict__ Bbf,
                                                  const float* __restrict__ bias,
                                                  float* __restrict__ C) {
    __shared__ bf16 LA[2][128 * 32];
    __shared__ bf16 LB[2][256 * 32];
    const int t = threadIdx.x;
    const int w = t >> 6, lane = t & 63;
    const int wn = w;
    const int tm = blockIdx.x * 128, tn = blockIdx.y * 256;
    const int lr = lane & 15, lkc = lane >> 4;

    f32x4v acc[8][4];
    const f32x4v zero = {0.f, 0.f, 0.f, 0.f};
#pragma unroll
    for (int m = 0; m < 8; ++m)
#pragma unroll
        for (int n = 0; n < 4; ++n) acc[m][n] = zero;

    stageA32(Abf, tm, LA[0], 0, t);
    stageB32(Bbf, tn, Vc - 1, LB[0], 0, t);
    stageA32(Abf, tm, LA[1], 1, t);
    asm volatile("s_waitcnt vmcnt(2)" ::: "memory");
    __builtin_amdgcn_s_barrier();
    __builtin_amdgcn_sched_barrier(0);

    for (int kt = 0; kt < NT2; ++kt) {
        bf16* la = LA[kt & 1];
        bf16* lb = LB[kt & 1];
        bf16* lbN = LB[(kt + 1) & 1];
        short8v a[8], b[4];
#pragma unroll
        for (int m = 0; m < 8; ++m) {
            const int row = m * 16 + lr;
            const int sc = lkc ^ ((row >> 1) & 3);
            a[m] = *(const short8v*)(la + row * 32 + sc * 8);
        }
#pragma unroll
        for (int n = 0; n < 4; ++n) {
            const int row = wn * 64 + n * 16 + lr;
            const int sc = lkc ^ ((row >> 1) & 3);
            b[n] = *(const short8v*)(lb + row * 32 + sc * 8);
        }
        if (kt + 1 < NT2) stageB32(Bbf, tn, Vc - 1, lbN, kt + 1, t);
        __builtin_amdgcn_s_barrier();
        __builtin_amdgcn_sched_barrier(0);
        __builtin_amdgcn_s_setprio(1);
#pragma unroll
        for (int m = 0; m < 8; ++m)
#pragma unroll
            for (int n = 0; n < 2; ++n)
                acc[m][n] = __builtin_amdgcn_mfma_f32_16x16x32_bf16(a[m], b[n], acc[m][n], 0, 0, 0);
        __builtin_amdgcn_s_setprio(0);
        __builtin_amdgcn_s_barrier();
        __builtin_amdgcn_sched_barrier(0);
        if (kt + 2 < NT2) stageA32(Abf, tm, la, kt + 2, t);
        __builtin_amdgcn_s_setprio(1);
#pragma unroll
        for (int m = 0; m < 8; ++m)
#pragma unroll
            for (int n = 2; n < 4; ++n)
                acc[m][n] = __builtin_amdgcn_mfma_f32_16x16x32_bf16(a[m], b[n], acc[m][n], 0, 0, 0);
        __builtin_amdgcn_s_setprio(0);
        if (kt + 2 < NT2) asm volatile("s_waitcnt vmcnt(2)" ::: "memory");
        else              asm volatile("s_waitcnt vmcnt(0)" ::: "memory");
        __builtin_amdgcn_s_barrier();
        __builtin_amdgcn_sched_barrier(0);
    }
    const int lq = (lane >> 4) * 4;
#pragma unroll
    for (int n = 0; n < 4; ++n) {
        const int col = tn + wn * 64 + n * 16 + lr;
        if (col >= Vc) continue;
        const float bv = bias[col];
#pragma unroll
        for (int m = 0; m < 8; ++m) {
            const int rbase = tm + m * 16 + lq;
#pragma unroll
            for (int j = 0; j < 4; ++j)
                C[(size_t)(rbase + j) * Vc + col] = acc[m][n][j] + bv;
        }
    }
}

// ---------------- plan mean partials ----------------
__global__ __launch_bounds__(256) void k_pmean(const float* __restrict__ plan, float* __restrict__ pm2) {
    const int b = blockIdx.x, c = blockIdx.y;
    const int h = threadIdx.x;
    const float* p = plan + ((size_t)(b * Sc + c * 64)) * Hc + h;
    float s = 0.0f;
    for (int i = 0; i < 64; ++i) s += p[(size_t)i * Hc];
    pm2[((size_t)b * 8 + c) * Hc + h] = s;
}

// ---------------- read softmax + memory read ----------------
__global__ __launch_bounds__(256) void k_memread(const float* __restrict__ pm2,
                                                 const float* __restrict__ rw,
                                                 const float* __restrict__ rb,
                                                 const float* __restrict__ memm,
                                                 float* __restrict__ out) {
    const int b = blockIdx.x;
    const int t = threadIdx.x;
    __shared__ float pms[256];
    __shared__ float lg[64];
    __shared__ float sm[64];
    float v = 0.0f;
    for (int c = 0; c < 8; ++c) v += pm2[((size_t)b * 8 + c) * Hc + t];
    pms[t] = v * (1.0f / 512.0f);
    __syncthreads();
    if (t < 64) {
        float s = rb[t];
        const float* wrow = rw + (size_t)t * Hc;
        for (int i = 0; i < Hc; ++i) s = fmaf(wrow[i], pms[i], s);
        lg[t] = s;
    }
    __syncthreads();
    if (t == 0) {
        float mx = lg[0];
        for (int i = 1; i < 64; ++i) mx = fmaxf(mx, lg[i]);
        float ssum = 0.0f;
        for (int i = 0; i < 64; ++i) { const float e = expf(lg[i] - mx); sm[i] = e; ssum += e; }
        for (int i = 0; i < 64; ++i) sm[i] /= ssum;
    }
    __syncthreads();
    float s = 0.0f;
    for (int m = 0; m < 64; ++m) s = fmaf(sm[m], memm[(size_t)m * Hc + t], s);
    out[(size_t)b * Hc + t] = s;
}

extern "C" void kernel_launch(void* const* d_in, const int* in_sizes, int n_in,
                              void* d_out, int out_size, void* d_ws, size_t ws_size,
                              hipStream_t stream) {
    const int*   ids    = (const int*)  d_in[0];
    const float* embed  = (const float*)d_in[1];
    const float* pos    = (const float*)d_in[2];
    const float* qkv_w  = (const float*)d_in[3];
    const float* qkv_b  = (const float*)d_in[4];
    const float* out_w  = (const float*)d_in[5];
    const float* out_b  = (const float*)d_in[6];
    const float* ln1_g  = (const float*)d_in[7];
    const float* ln1_b  = (const float*)d_in[8];
    const float* ff1_w  = (const float*)d_in[9];
    const float* ff1_b  = (const float*)d_in[10];
    const float* ff2_w  = (const float*)d_in[11];
    const float* ff2_b  = (const float*)d_in[12];
    const float* ln2_g  = (const float*)d_in[13];
    const float* ln2_b  = (const float*)d_in[14];
    const float* log_w  = (const float*)d_in[15];
    const float* log_b  = (const float*)d_in[16];
    const float* mat_w  = (const float*)d_in[17];
    const float* mat_b  = (const float*)d_in[18];
    const float* conv_w = (const float*)d_in[19];
    const float* conv_b = (const float*)d_in[20];
    const float* read_w = (const float*)d_in[21];
    const float* read_b = (const float*)d_in[22];
    const float* memory = (const float*)d_in[23];
    const float* head_w = (const float*)d_in[24];
    const float* head_b = (const float*)d_in[25];

    char* wsb = (char*)d_ws;
    const size_t MB = 1ull << 20;
    float* X    = (float*)(wsb + 0);           // 8 MB [8192,256]
    bf16*  XH   = (bf16*)(wsb + 8 * MB);
    bf16*  XM   = (bf16*)(wsb + 12 * MB);
    bf16*  XL   = (bf16*)(wsb + 16 * MB);
    float* RES  = (float*)(wsb + 20 * MB);     // 8 MB
    bf16*  QPH  = (bf16*)(wsb + 28 * MB);      // 12 MB each [8192,768] planes
    bf16*  QPM  = (bf16*)(wsb + 40 * MB);
    bf16*  QPL  = (bf16*)(wsb + 52 * MB);
    bf16*  OH   = (bf16*)(wsb + 64 * MB);      // 4 MB each
    bf16*  OM   = (bf16*)(wsb + 68 * MB);
    bf16*  OL   = (bf16*)(wsb + 72 * MB);
    // ---- alias region 76..128 MB ----
    bf16*  VTH  = (bf16*)(wsb + 76 * MB);      // 4 MB each (attention phase)
    bf16*  VTM  = (bf16*)(wsb + 80 * MB);
    bf16*  VTL  = (bf16*)(wsb + 84 * MB);
    bf16*  H1H  = (bf16*)(wsb + 88 * MB);      // 8 MB each (ff phase; disjoint from VT)
    bf16*  H1M  = (bf16*)(wsb + 96 * MB);
    bf16*  H1L  = (bf16*)(wsb + 104 * MB);
    float* LOGMAT = (float*)(wsb + 76 * MB);   // 16 MB [8192,512] (post-loop)
    bf16*  AEH  = (bf16*)(wsb + 92 * MB);      // 12 MB each (post-loop)
    bf16*  AEM  = (bf16*)(wsb + 104 * MB);
    bf16*  AEL  = (bf16*)(wsb + 116 * MB);
    // ---------------------------------
    bf16*  COMB = (bf16*)(wsb + 128 * MB);     // 16 MB [8192,1024]
    bf16*  HWB  = (bf16*)(wsb + 144 * MB);     // 16 MB [8000,1024]
    bf16*  WP   = (bf16*)(wsb + 160 * MB);     // weight planes
    float* PM2  = (float*)(wsb + 64 * MB);     // [16,8,256] partials (reuse OH post-loop)

    float* logits = (float*)d_out;
    float* mread  = logits + (size_t)ROWS * Vc;

    // weight plane sub-offsets (elements)
    bf16* qkvwh = WP;             bf16* qkvwm = qkvwh + 393216; bf16* qkvwl = qkvwm + 393216;
    bf16* outwh = qkvwl + 393216; bf16* outwm = outwh + 131072; bf16* outwl = outwm + 131072;
    bf16* ff1wh = outwl + 131072; bf16* ff1wm = ff1wh + 262144; bf16* ff1wl = ff1wm + 262144;
    bf16* ff2wh = ff1wl + 262144; bf16* ff2wm = ff2wh + 262144; bf16* ff2wl = ff2wm + 262144;
    bf16* lmwh  = ff2wl + 262144; bf16* lmwm  = lmwh + 131072;  bf16* lmwl  = lmwm + 131072;
    bf16* w2h   = lmwl + 131072;  bf16* w2m   = w2h + 196608;   bf16* w2l   = w2m + 196608;
    float* LMB  = (float*)(w2l + 196608);      // [512] concat bias (after weight planes)

    hipFuncSetAttribute((const void*)k_attn, hipFuncAttributeMaxDynamicSharedMemorySize, 155648);

    // consolidated weight prep (one launch)
    k_prep<<<dim3(9921), 256, 0, stream>>>(
        qkv_w, out_w, ff1_w, ff2_w, log_w, mat_w, conv_w, head_w, log_b, mat_b,
        qkvwh, qkvwm, qkvwl, outwh, outwm, outwl, ff1wh, ff1wm, ff1wl,
        ff2wh, ff2wm, ff2wl, lmwh, lmwm, lmwl, w2h, w2m, w2l, HWB, LMB);

    k_embed<<<dim3(ROWS), 256, 0, stream>>>(ids, embed, pos, X, XH, XM, XL);
    for (int l = 0; l < 2; ++l) {
        // qkv -> QP planes [8192,768]
        k_bg3<0, 1, 128><<<dim3(64, 6, 1), 256, 0, stream>>>(
            XH, XM, XL,
            qkvwh + (size_t)l * 196608, qkvwm + (size_t)l * 196608, qkvwl + (size_t)l * 196608,
            qkv_b + l * 768, nullptr, QPH, QPM, QPL,
            256, 256, 256, 768, 0, 0, 0, 0, 0, 0);
        k_vt<<<dim3(8, 64), 256, 0, stream>>>(QPH, QPM, QPL, VTH, VTM, VTL);
        // fused scores + softmax + PV -> O planes (pipelined LDS staging)
        k_attn<<<dim3(8, 64), 512, 155648, stream>>>(QPH, QPM, QPL, VTH, VTM, VTL, OH, OM, OL);
        // out proj -> RES fp32
        k_bg3<0, 0, 64><<<dim3(64, 4, 1), 256, 0, stream>>>(
            OH, OM, OL,
            outwh + (size_t)l * 65536, outwm + (size_t)l * 65536, outwl + (size_t)l * 65536,
            out_b + l * 256, RES, nullptr, nullptr, nullptr,
            256, 256, 256, 256, 0, 0, 0, 0, 0, 0);
        k_add_ln<<<dim3(ROWS), 256, 0, stream>>>(X, RES, ln1_g + l * 256, ln1_b + l * 256,
                                                 XH, XM, XL, nullptr);
        // ff1 + gelu -> H1 planes
        k_bg3<1, 1, 128><<<dim3(64, 4, 1), 256, 0, stream>>>(
            XH, XM, XL,
            ff1wh + (size_t)l * 131072, ff1wm + (size_t)l * 131072, ff1wl + (size_t)l * 131072,
            ff1_b + l * 512, nullptr, H1H, H1M, H1L,
            256, 256, 256, 512, 0, 0, 0, 0, 0, 0);
        // ff2 -> RES fp32
        k_bg3<0, 0, 64><<<dim3(64, 4, 1), 256, 0, stream>>>(
            H1H, H1M, H1L,
            ff2wh + (size_t)l * 131072, ff2wm + (size_t)l * 131072, ff2wl + (size_t)l * 131072,
            ff2_b + l * 256, RES, nullptr, nullptr, nullptr,
            512, 512, 512, 256, 0, 0, 0, 0, 0, 0);
        // final LN also packs plan into COMB (cols 768..1023)
        k_add_ln<<<dim3(ROWS), 256, 0, stream>>>(X, RES, ln2_g + l * 256, ln2_b + l * 256,
                                                 XH, XM, XL, (l == 1) ? COMB : nullptr);
    }
    // plan = X; fused log+mat projection -> LOGMAT [8192,512]
    k_bg3<0, 0, 128><<<dim3(64, 4, 1), 256, 0, stream>>>(
        XH, XM, XL, lmwh, lmwm, lmwl, LMB, LOGMAT, nullptr, nullptr, nullptr,
        256, 256, 256, 512, 0, 0, 0, 0, 0, 0);
    k_aext3<<<dim3(6144), 256, 0, stream>>>(XH, XM, XL, AEH, AEM, AEL);
    k_lif2<<<dim3(Bc, 2), 256, 0, stream>>>(LOGMAT, COMB);
    // conv as GEMM -> bf16 directly into COMB cols 512..767 (OUTS=3)
    k_bg3<0, 3, 64><<<dim3(64, 4, 1), 256, 0, stream>>>(
        AEH, AEM, AEL, w2h, w2m, w2l, conv_b, (float*)(COMB + 512), nullptr, nullptr, nullptr,
        768, 768, 768, CH, 0, 0, 0, 0, 0, 0);
    k_head8<<<dim3(64, 32), 256, 0, stream>>>(COMB, HWB, head_b, logits);
    k_pmean<<<dim3(Bc, 8), 256, 0, stream>>>(X, PM2);
    k_memread<<<dim3(Bc), 256, 0, stream>>>(PM2, read_w, read_b, memory, mread);
}

// Round 15
// 720.824 us; speedup vs baseline: 1.7075x; 1.0208x over previous
//
#include <hip/hip_runtime.h>
#include <hip/hip_bf16.h>

// Problem constants
constexpr int Bc = 16, Sc = 512, Hc = 256, Vc = 8000, NHc = 4, HDc = 64;
constexpr int FFc = 512, Mc = 64;
constexpr int ROWS = Bc * Sc;      // 8192
constexpr int CH = 4 * Hc;         // 1024
constexpr int NT2 = CH / 32;       // 32 K-tiles (BK=32) for the head GEMM

typedef __attribute__((ext_vector_type(4))) float f32x4v;
typedef __attribute__((ext_vector_type(8))) short short8v;
typedef __attribute__((ext_vector_type(4))) short short4v;
typedef __hip_bfloat16 bf16;

// ---- 3-way bf16 split: x = h + m + l + O(2^-27 |x|) ----
__device__ inline void split3(float x, bf16& h, bf16& m, bf16& l) {
    h = __float2bfloat16(x);
    const float r = x - __bfloat162float(h);   // exact
    m = __float2bfloat16(r);
    const float r2 = r - __bfloat162float(m);  // exact
    l = __float2bfloat16(r2);
}

// ---------------- consolidated weight prep (one launch) ----------------
__device__ __forceinline__ void split_range(const float* __restrict__ in,
                                            bf16* __restrict__ h, bf16* __restrict__ m,
                                            bf16* __restrict__ l, int blk, int t) {
    const size_t i = ((size_t)blk * 256 + t) * 4;
    const float4 v = *(const float4*)&in[i];
    split3(v.x, h[i + 0], m[i + 0], l[i + 0]);
    split3(v.y, h[i + 1], m[i + 1], l[i + 1]);
    split3(v.z, h[i + 2], m[i + 2], l[i + 2]);
    split3(v.w, h[i + 3], m[i + 3], l[i + 3]);
}

__global__ __launch_bounds__(256) void k_prep(
    const float* __restrict__ qkv_w, const float* __restrict__ out_w,
    const float* __restrict__ ff1_w, const float* __restrict__ ff2_w,
    const float* __restrict__ log_w, const float* __restrict__ mat_w,
    const float* __restrict__ conv_w, const float* __restrict__ head_w,
    const float* __restrict__ log_b, const float* __restrict__ mat_b,
    bf16* qkvwh, bf16* qkvwm, bf16* qkvwl,
    bf16* outwh, bf16* outwm, bf16* outwl,
    bf16* ff1wh, bf16* ff1wm, bf16* ff1wl,
    bf16* ff2wh, bf16* ff2wm, bf16* ff2wl,
    bf16* lmwh, bf16* lmwm, bf16* lmwl,
    bf16* w2h, bf16* w2m, bf16* w2l,
    bf16* hwb, float* lmb) {
    const int blk = blockIdx.x;
    const int t = threadIdx.x;
    if (blk < 384) {
        split_range(qkv_w, qkvwh, qkvwm, qkvwl, blk, t);
    } else if (blk < 512) {
        split_range(out_w, outwh, outwm, outwl, blk - 384, t);
    } else if (blk < 768) {
        split_range(ff1_w, ff1wh, ff1wm, ff1wl, blk - 512, t);
    } else if (blk < 1024) {
        split_range(ff2_w, ff2wh, ff2wm, ff2wl, blk - 768, t);
    } else if (blk < 1088) {
        split_range(log_w, lmwh, lmwm, lmwl, blk - 1024, t);
    } else if (blk < 1152) {
        split_range(mat_w, lmwh + 65536, lmwm + 65536, lmwl + 65536, blk - 1088, t);
    } else if (blk < 1920) {
        const int idx = (blk - 1152) * 256 + t;       // conv re-layout + split
        const int o = idx / 768, rem = idx % 768;
        const int k = rem >> 8, i = rem & 255;
        split3(conv_w[(size_t)o * 768 + i * 3 + k], w2h[idx], w2m[idx], w2l[idx]);
    } else if (blk < 9920) {
        const size_t i = ((size_t)(blk - 1920) * 256 + t) * 4;   // head_w -> bf16, vector store
        const float4 v = *(const float4*)&head_w[i];
        bf16 b0 = __float2bfloat16(v.x), b1 = __float2bfloat16(v.y);
        bf16 b2 = __float2bfloat16(v.z), b3 = __float2bfloat16(v.w);
        short4v sv;
        sv[0] = *(const short*)&b0; sv[1] = *(const short*)&b1;
        sv[2] = *(const short*)&b2; sv[3] = *(const short*)&b3;
        *(short4v*)(hwb + i) = sv;
    } else {
        lmb[t] = log_b[t];
        lmb[256 + t] = mat_b[t];
    }
}

// ---------------- embed + pos (+ split planes) ----------------
__global__ __launch_bounds__(256) void k_embed(const int* __restrict__ ids,
                                               const float* __restrict__ emb,
                                               const float* __restrict__ pos,
                                               float* __restrict__ x,
                                               bf16* __restrict__ xh, bf16* __restrict__ xm,
                                               bf16* __restrict__ xl) {
    const int r = blockIdx.x;
    const int h = threadIdx.x;
    const int s = r & (Sc - 1);
    const int id = ids[r];
    const float v = emb[(size_t)id * Hc + h] + pos[(size_t)s * Hc + h];
    const size_t o = (size_t)r * Hc + h;
    x[o] = v;
    split3(v, xh[o], xm[o], xl[o]);
}

// ======== batched bf16x3 MFMA GEMM: C = A[M,K] @ B[N,K]^T ========
// EPI: 0 = +bias, 1 = gelu(x+bias), 3 = none
// OUTS: 0 = fp32 C, 1 = split3 planes, 3 = bf16 write into C (cast) at ldc stride
template <int EPI, int OUTS, int BN>
__global__ __launch_bounds__(256) void k_bg3(
    const bf16* __restrict__ Ah, const bf16* __restrict__ Am, const bf16* __restrict__ Al,
    const bf16* __restrict__ Bh, const bf16* __restrict__ Bm, const bf16* __restrict__ Bl,
    const float* __restrict__ bias, float* __restrict__ C,
    bf16* __restrict__ Oh, bf16* __restrict__ Om, bf16* __restrict__ Ol,
    int K, int lda, int ldb, int ldc,
    long zA2, long zA1, long zB2, long zB1, long zC2, long zC1) {
    constexpr int NF = BN / 32;
    __shared__ bf16 As[3][128 * 32];
    __shared__ bf16 Bs[3][BN * 32];
    const int z = blockIdx.z, z2 = z >> 2, z1 = z & 3;
    const size_t aoff = (size_t)z2 * zA2 + (size_t)z1 * zA1;
    const size_t boff = (size_t)z2 * zB2 + (size_t)z1 * zB1;
    const size_t coff = (size_t)z2 * zC2 + (size_t)z1 * zC1;
    const int t = threadIdx.x;
    const int tm = blockIdx.x * 128, tn = blockIdx.y * BN;
    const int w = t >> 6, l = t & 63;
    const int wr = w >> 1, wc = w & 1;
    const bf16* Ap[3] = {Ah, Am, Al};
    const bf16* Bp[3] = {Bh, Bm, Bl};
    f32x4v acc[4][NF];
    const f32x4v zero = {0.f, 0.f, 0.f, 0.f};
#pragma unroll
    for (int i = 0; i < 4; ++i)
#pragma unroll
        for (int j = 0; j < NF; ++j) acc[i][j] = zero;

    for (int kt = 0; kt < K; kt += 32) {
#pragma unroll
        for (int p = 0; p < 3; ++p) {
#pragma unroll
            for (int j = 0; j < 2; ++j) {
                const int c = j * 256 + t;
                const int row = c >> 2, kc = c & 3;
                const int skc = kc ^ ((row >> 1) & 3);
                const bf16* ga = Ap[p] + aoff + (size_t)(tm + row) * lda + kt + skc * 8;
                __builtin_amdgcn_global_load_lds((const __attribute__((address_space(1))) void*)ga,
                                                 (__attribute__((address_space(3))) void*)(&As[p][0] + c * 8),
                                                 16, 0, 0);
            }
            if (BN == 128) {
#pragma unroll
                for (int j = 0; j < 2; ++j) {
                    const int c = j * 256 + t;
                    const int row = c >> 2, kc = c & 3;
                    const int skc = kc ^ ((row >> 1) & 3);
                    const bf16* gb = Bp[p] + boff + (size_t)(tn + row) * ldb + kt + skc * 8;
                    __builtin_amdgcn_global_load_lds((const __attribute__((address_space(1))) void*)gb,
                                                     (__attribute__((address_space(3))) void*)(&Bs[p][0] + c * 8),
                                                     16, 0, 0);
                }
            } else {
                const int c = t;
                const int row = c >> 2, kc = c & 3;
                const int skc = kc ^ ((row >> 1) & 3);
                const bf16* gb = Bp[p] + boff + (size_t)(tn + row) * ldb + kt + skc * 8;
                __builtin_amdgcn_global_load_lds((const __attribute__((address_space(1))) void*)gb,
                                                 (__attribute__((address_space(3))) void*)(&Bs[p][0] + c * 8),
                                                 16, 0, 0);
            }
        }
        __syncthreads();
        const int lr = l & 15, lkc = l >> 4;
        short8v af[3][4], bfr[3][NF];
#pragma unroll
        for (int p = 0; p < 3; ++p)
#pragma unroll
            for (int m = 0; m < 4; ++m) {
                const int row = wr * 64 + m * 16 + lr;
                const int sc = lkc ^ ((row >> 1) & 3);
                af[p][m] = *(const short8v*)(&As[p][0] + row * 32 + sc * 8);
            }
#pragma unroll
        for (int p = 0; p < 3; ++p)
#pragma unroll
            for (int n = 0; n < NF; ++n) {
                const int row = wc * (BN / 2) + n * 16 + lr;
                const int sc = lkc ^ ((row >> 1) & 3);
                bfr[p][n] = *(const short8v*)(&Bs[p][0] + row * 32 + sc * 8);
            }
        // 6 term passes: hh, hm, mh, hl, lh, mm
#pragma unroll
        for (int m = 0; m < 4; ++m)
#pragma unroll
            for (int n = 0; n < NF; ++n)
                acc[m][n] = __builtin_amdgcn_mfma_f32_16x16x32_bf16(af[0][m], bfr[0][n], acc[m][n], 0, 0, 0);
#pragma unroll
        for (int m = 0; m < 4; ++m)
#pragma unroll
            for (int n = 0; n < NF; ++n)
                acc[m][n] = __builtin_amdgcn_mfma_f32_16x16x32_bf16(af[0][m], bfr[1][n], acc[m][n], 0, 0, 0);
#pragma unroll
        for (int m = 0; m < 4; ++m)
#pragma unroll
            for (int n = 0; n < NF; ++n)
                acc[m][n] = __builtin_amdgcn_mfma_f32_16x16x32_bf16(af[1][m], bfr[0][n], acc[m][n], 0, 0, 0);
#pragma unroll
        for (int m = 0; m < 4; ++m)
#pragma unroll
            for (int n = 0; n < NF; ++n)
                acc[m][n] = __builtin_amdgcn_mfma_f32_16x16x32_bf16(af[0][m], bfr[2][n], acc[m][n], 0, 0, 0);
#pragma unroll
        for (int m = 0; m < 4; ++m)
#pragma unroll
            for (int n = 0; n < NF; ++n)
                acc[m][n] = __builtin_amdgcn_mfma_f32_16x16x32_bf16(af[2][m], bfr[0][n], acc[m][n], 0, 0, 0);
#pragma unroll
        for (int m = 0; m < 4; ++m)
#pragma unroll
            for (int n = 0; n < NF; ++n)
                acc[m][n] = __builtin_amdgcn_mfma_f32_16x16x32_bf16(af[1][m], bfr[1][n], acc[m][n], 0, 0, 0);
        __syncthreads();
    }
    const int lr = l & 15, lq = (l >> 4) * 4;
#pragma unroll
    for (int n = 0; n < NF; ++n) {
        const int col = tn + wc * (BN / 2) + n * 16 + lr;
        const float bv = (EPI == 0 || EPI == 1) ? bias[col] : 0.0f;
#pragma unroll
        for (int m = 0; m < 4; ++m) {
            const int rbase = tm + wr * 64 + m * 16 + lq;
#pragma unroll
            for (int j = 0; j < 4; ++j) {
                float v = acc[m][n][j];
                if (EPI == 0) v += bv;
                if (EPI == 1) { v += bv; v = 0.5f * v * (1.0f + erff(v / 1.41421356237309515f)); }
                const size_t o = coff + (size_t)(rbase + j) * ldc + col;
                if (OUTS == 0) C[o] = v;
                else if (OUTS == 3) ((bf16*)C)[o] = __float2bfloat16(v);
                else split3(v, Oh[o], Om[o], Ol[o]);
            }
        }
    }
}

// ---------------- V-transpose: VT[z][d][s] from qkv planes ----------------
__global__ __launch_bounds__(256) void k_vt(const bf16* __restrict__ qh,
                                            const bf16* __restrict__ qm,
                                            const bf16* __restrict__ ql,
                                            bf16* __restrict__ vh, bf16* __restrict__ vm,
                                            bf16* __restrict__ vl) {
    __shared__ bf16 tile[64][72];
    const int sblk = blockIdx.x;           // 0..7
    const int z = blockIdx.y;              // 0..63
    const int b = z >> 2, h = z & 3;
    const int t = threadIdx.x;
    const int sr = t >> 2, c16 = (t & 3) * 16;
    const bf16* qp[3] = {qh, qm, ql};
    bf16* vp[3] = {vh, vm, vl};
    for (int p = 0; p < 3; ++p) {
        const bf16* src = qp[p] + (size_t)(b * Sc + sblk * 64 + sr) * 768 + 512 + h * 64 + c16;
        *(short8v*)&tile[sr][c16] = *(const short8v*)src;
        *(short8v*)&tile[sr][c16 + 8] = *(const short8v*)(src + 8);
        __syncthreads();
        bf16 out[16];
#pragma unroll
        for (int i = 0; i < 16; ++i) out[i] = tile[c16 + i][sr];
        bf16* dst = vp[p] + (size_t)(z * 64 + sr) * Sc + sblk * 64 + c16;
        *(short8v*)dst = *(short8v*)&out[0];
        *(short8v*)(dst + 8) = *(short8v*)&out[8];
        __syncthreads();
    }
}

// ======== fused attention (R8 version): pipelined LDS staging, issue-early ========
#define S_PASS(QA, KB)                                                                     \
    _Pragma("unroll") for (int m = 0; m < 2; ++m) _Pragma("unroll") for (int ks = 0; ks < 2; ++ks) \
        sa[m] = __builtin_amdgcn_mfma_f32_16x16x32_bf16(QA[m][ks], KB[ks], sa[m], 0, 0, 0);
#define PV_PASS(PA, VB)                                                                    \
    _Pragma("unroll") for (int m = 0; m < 2; ++m) _Pragma("unroll") for (int ks = 0; ks < 2; ++ks) \
        oa[m] = __builtin_amdgcn_mfma_f32_16x16x32_bf16(PA[m][ks], VB[ks], oa[m], 0, 0, 0);

__global__ __launch_bounds__(512) void k_attn(
    const bf16* __restrict__ qph, const bf16* __restrict__ qpm, const bf16* __restrict__ qpl,
    const bf16* __restrict__ vth, const bf16* __restrict__ vtm, const bf16* __restrict__ vtl,
    bf16* __restrict__ oh, bf16* __restrict__ om, bf16* __restrict__ ol) {
    extern __shared__ char smem[];
    float* S = (float*)smem;                        // 64 x 512 fp32, swizzled
    bf16* KV0 = (bf16*)(smem + 131072);             // 3 planes of [64][64]
    bf16* KV1 = KV0 + 4096;
    bf16* KV2 = KV1 + 4096;
    const int qc = blockIdx.x, z = blockIdx.y;
    const int b = z >> 2, hh = z & 3;
    const int t = threadIdx.x;
    const int w = t >> 6, lane = t & 63;
    const int lr = lane & 15, lkc = lane >> 4;      // lkc 0..3
    const int qg = w >> 2, kg = w & 3;
    const int r8 = t >> 3, c8 = t & 7;              // staging map
    const f32x4v zero = {0.f, 0.f, 0.f, 0.f};

    // Q A-frags in registers (one-time gather)
    short8v qf0[2][2], qf1[2][2], qf2[2][2];
#pragma unroll
    for (int m = 0; m < 2; ++m)
#pragma unroll
        for (int ks = 0; ks < 2; ++ks) {
            const size_t rbase = (size_t)(b * 512 + qc * 64 + qg * 32 + m * 16 + lr) * 768 + hh * 64 + ks * 32 + lkc * 8;
            qf0[m][ks] = *(const short8v*)(qph + rbase);
            qf1[m][ks] = *(const short8v*)(qpm + rbase);
            qf2[m][ks] = *(const short8v*)(qpl + rbase);
        }

    // stage K(0)
    {
        const size_t srow = (size_t)(b * 512 + 0 * 64 + r8) * 768 + 256 + hh * 64 + (c8 ^ (r8 & 7)) * 8;
        __builtin_amdgcn_global_load_lds((const __attribute__((address_space(1))) void*)(qph + srow),
                                         (__attribute__((address_space(3))) void*)(KV0 + r8 * 64 + c8 * 8), 16, 0, 0);
        __builtin_amdgcn_global_load_lds((const __attribute__((address_space(1))) void*)(qpm + srow),
                                         (__attribute__((address_space(3))) void*)(KV1 + r8 * 64 + c8 * 8), 16, 0, 0);
        __builtin_amdgcn_global_load_lds((const __attribute__((address_space(1))) void*)(qpl + srow),
                                         (__attribute__((address_space(3))) void*)(KV2 + r8 * 64 + c8 * 8), 16, 0, 0);
    }

    // ---- scores: S[q][kv] = (Q.K)/8 ----
    for (int kv = 0; kv < 8; ++kv) {
        __syncthreads();                             // K(kv) resident (vmcnt drained)
        short8v kb0[2], kb1[2], kb2[2];
#pragma unroll
        for (int ks = 0; ks < 2; ++ks) {
            const int row = kg * 16 + lr;
            const int sc = (ks * 4 + lkc) ^ (row & 7);
            kb0[ks] = *(const short8v*)(KV0 + row * 64 + sc * 8);
            kb1[ks] = *(const short8v*)(KV1 + row * 64 + sc * 8);
            kb2[ks] = *(const short8v*)(KV2 + row * 64 + sc * 8);
        }
        __syncthreads();                             // all reads done; KV buffer free
        if (kv < 7) {                                // issue-early: K(kv+1) overlaps compute
            const size_t srow = (size_t)(b * 512 + (kv + 1) * 64 + r8) * 768 + 256 + hh * 64 + (c8 ^ (r8 & 7)) * 8;
            __builtin_amdgcn_global_load_lds((const __attribute__((address_space(1))) void*)(qph + srow),
                                             (__attribute__((address_space(3))) void*)(KV0 + r8 * 64 + c8 * 8), 16, 0, 0);
            __builtin_amdgcn_global_load_lds((const __attribute__((address_space(1))) void*)(qpm + srow),
                                             (__attribute__((address_space(3))) void*)(KV1 + r8 * 64 + c8 * 8), 16, 0, 0);
            __builtin_amdgcn_global_load_lds((const __attribute__((address_space(1))) void*)(qpl + srow),
                                             (__attribute__((address_space(3))) void*)(KV2 + r8 * 64 + c8 * 8), 16, 0, 0);
        } else {                                     // prefetch V(0) under softmax
            const size_t srow = (size_t)(z * 64 + r8) * 512 + 0 * 64 + (c8 ^ (r8 & 7)) * 8;
            __builtin_amdgcn_global_load_lds((const __attribute__((address_space(1))) void*)(vth + srow),
                                             (__attribute__((address_space(3))) void*)(KV0 + r8 * 64 + c8 * 8), 16, 0, 0);
            __builtin_amdgcn_global_load_lds((const __attribute__((address_space(1))) void*)(vtm + srow),
                                             (__attribute__((address_space(3))) void*)(KV1 + r8 * 64 + c8 * 8), 16, 0, 0);
            __builtin_amdgcn_global_load_lds((const __attribute__((address_space(1))) void*)(vtl + srow),
                                             (__attribute__((address_space(3))) void*)(KV2 + r8 * 64 + c8 * 8), 16, 0, 0);
        }
        f32x4v sa[2] = {zero, zero};
        S_PASS(qf0, kb0) S_PASS(qf0, kb1) S_PASS(qf1, kb0)
        S_PASS(qf0, kb2) S_PASS(qf2, kb0) S_PASS(qf1, kb1)
#pragma unroll
        for (int m = 0; m < 2; ++m)
#pragma unroll
            for (int j = 0; j < 4; ++j) {
                const int row = qg * 32 + m * 16 + (lane >> 4) * 4 + j;
                const int col = kv * 64 + kg * 16 + lr;
                const int chunk = (col >> 2) ^ (row & 7);
                *(float*)((char*)S + row * 2048 + chunk * 16 + (col & 3) * 4) = sa[m][j] * 0.125f;
            }
    }
    __syncthreads();                                 // S complete; V(0) resident

    // ---- exact softmax per row (wave w owns rows w*8..w*8+7) ----
    for (int r = 0; r < 8; ++r) {
        const int row = w * 8 + r;
        char* rowp = (char*)S + row * 2048;
        const int sw = row & 7;
        float4 x0 = *(float4*)(rowp + ((2 * lane) ^ sw) * 16);
        float4 x1 = *(float4*)(rowp + ((2 * lane + 1) ^ sw) * 16);
        float mx = fmaxf(fmaxf(fmaxf(x0.x, x0.y), fmaxf(x0.z, x0.w)),
                         fmaxf(fmaxf(x1.x, x1.y), fmaxf(x1.z, x1.w)));
#pragma unroll
        for (int d = 1; d < 64; d <<= 1) mx = fmaxf(mx, __shfl_xor(mx, d));
        const float e0 = expf(x0.x - mx), e1 = expf(x0.y - mx), e2 = expf(x0.z - mx), e3 = expf(x0.w - mx);
        const float e4 = expf(x1.x - mx), e5 = expf(x1.y - mx), e6 = expf(x1.z - mx), e7 = expf(x1.w - mx);
        float sm = ((e0 + e1) + (e2 + e3)) + ((e4 + e5) + (e6 + e7));
#pragma unroll
        for (int d = 1; d < 64; d <<= 1) sm += __shfl_xor(sm, d);
        x0.x = e0 / sm; x0.y = e1 / sm; x0.z = e2 / sm; x0.w = e3 / sm;
        x1.x = e4 / sm; x1.y = e5 / sm; x1.z = e6 / sm; x1.w = e7 / sm;
        *(float4*)(rowp + ((2 * lane) ^ sw) * 16) = x0;
        *(float4*)(rowp + ((2 * lane + 1) ^ sw) * 16) = x1;
    }
    __syncthreads();

    // ---- PV: O[q][d] = sum_kv P[q][kv] * VT[d][kv] ----
    f32x4v oa[2] = {zero, zero};
    for (int kv = 0; kv < 8; ++kv) {
        if (kv > 0) __syncthreads();                 // V(kv) resident
        short8v vb0[2], vb1[2], vb2[2];
#pragma unroll
        for (int ks = 0; ks < 2; ++ks) {
            const int rowd = kg * 16 + lr;
            const int sc = (ks * 4 + lkc) ^ (rowd & 7);
            vb0[ks] = *(const short8v*)(KV0 + rowd * 64 + sc * 8);
            vb1[ks] = *(const short8v*)(KV1 + rowd * 64 + sc * 8);
            vb2[ks] = *(const short8v*)(KV2 + rowd * 64 + sc * 8);
        }
        __syncthreads();                             // reads done; KV free
        if (kv < 7) {
            const size_t srow = (size_t)(z * 64 + r8) * 512 + (kv + 1) * 64 + (c8 ^ (r8 & 7)) * 8;
            __builtin_amdgcn_global_load_lds((const __attribute__((address_space(1))) void*)(vth + srow),
                                             (__attribute__((address_space(3))) void*)(KV0 + r8 * 64 + c8 * 8), 16, 0, 0);
            __builtin_amdgcn_global_load_lds((const __attribute__((address_space(1))) void*)(vtm + srow),
                                             (__attribute__((address_space(3))) void*)(KV1 + r8 * 64 + c8 * 8), 16, 0, 0);
            __builtin_amdgcn_global_load_lds((const __attribute__((address_space(1))) void*)(vtl + srow),
                                             (__attribute__((address_space(3))) void*)(KV2 + r8 * 64 + c8 * 8), 16, 0, 0);
        }
        short8v pah[2][2], pam[2][2], pal[2][2];
#pragma unroll
        for (int m = 0; m < 2; ++m)
#pragma unroll
            for (int ks = 0; ks < 2; ++ks) {
                const int row = qg * 32 + m * 16 + lr;
                const int c0 = kv * 16 + ks * 8 + lkc * 2;
                char* rp = (char*)S + row * 2048;
                const float4 y0 = *(const float4*)(rp + (c0 ^ (row & 7)) * 16);
                const float4 y1 = *(const float4*)(rp + ((c0 + 1) ^ (row & 7)) * 16);
                const float yy[8] = {y0.x, y0.y, y0.z, y0.w, y1.x, y1.y, y1.z, y1.w};
                short8v hv, mv, lv;
#pragma unroll
                for (int i = 0; i < 8; ++i) {
                    bf16 a, bq, c;
                    split3(yy[i], a, bq, c);
                    hv[i] = *(const short*)&a; mv[i] = *(const short*)&bq; lv[i] = *(const short*)&c;
                }
                pah[m][ks] = hv; pam[m][ks] = mv; pal[m][ks] = lv;
            }
        PV_PASS(pah, vb0) PV_PASS(pah, vb1) PV_PASS(pam, vb0)
        PV_PASS(pah, vb2) PV_PASS(pal, vb0) PV_PASS(pam, vb1)
    }
    // epilogue: O planes [8192][256]
#pragma unroll
    for (int m = 0; m < 2; ++m)
#pragma unroll
        for (int j = 0; j < 4; ++j) {
            const int grow = b * 512 + qc * 64 + qg * 32 + m * 16 + (lane >> 4) * 4 + j;
            const int col = hh * 64 + kg * 16 + lr;
            const size_t o = (size_t)grow * 256 + col;
            split3(oa[m][j], oh[o], om[o], ol[o]);
        }
}

// ---------------- x = LayerNorm(x + res) * g + b — wave-parallel, bit-identical tree ----------------
// 4 waves/block, one row per wave, zero barriers. Lane j-element mapping e = lane + j*64
// reproduces the exact binary reduction tree of the old 256-thread LDS version:
//   s=128 level: a = v0+v2, b = v1+v3 ; s=64 level: c = a+b ; s=32..1: shfl_xor tree.
__global__ __launch_bounds__(256) void k_add_ln(float* __restrict__ x,
                                                const float* __restrict__ res,
                                                const float* __restrict__ g,
                                                const float* __restrict__ b,
                                                bf16* __restrict__ xh, bf16* __restrict__ xm,
                                                bf16* __restrict__ xl,
                                                bf16* __restrict__ comb) {
    const int w = threadIdx.x >> 6, lane = threadIdx.x & 63;
    const size_t row = (size_t)blockIdx.x * 4 + w;
    float v[4];
#pragma unroll
    for (int j = 0; j < 4; ++j) {
        const int e = lane + j * 64;
        v[j] = x[row * Hc + e] + res[row * Hc + e];
    }
    // mean: exact same tree as LDS version
    float a = v[0] + v[2];
    float bb = v[1] + v[3];
    float c = a + bb;
#pragma unroll
    for (int d = 32; d >= 1; d >>= 1) c += __shfl_xor(c, d);
    const float mean = c * (1.0f / 256.0f);
    // variance: squares kept un-contracted (match LDS-store rounding), same tree
    float dd[4], sq[4];
#pragma unroll
    for (int j = 0; j < 4; ++j) {
        dd[j] = v[j] - mean;
        sq[j] = dd[j] * dd[j];
        asm volatile("" : "+v"(sq[j]));    // block FMA contraction across the adds below
    }
    float a2 = sq[0] + sq[2];
    float b2 = sq[1] + sq[3];
    float c2 = a2 + b2;
#pragma unroll
    for (int d = 32; d >= 1; d >>= 1) c2 += __shfl_xor(c2, d);
    const float var = c2 * (1.0f / 256.0f);
    const float rstd = sqrtf(var + 1e-5f);
#pragma unroll
    for (int j = 0; j < 4; ++j) {
        const int e = lane + j * 64;
        const float out = dd[j] / rstd * g[e] + b[e];
        const size_t o = row * Hc + e;
        x[o] = out;
        split3(out, xh[o], xm[o], xl[o]);
        if (comb != nullptr) comb[row * CH + 768 + e] = __float2bfloat16(out);
    }
}

// ---------------- LIF scan (both heads; 8-row load batches for ILP) ----------------
__global__ __launch_bounds__(256) void k_lif2(const float* __restrict__ lm,
                                              bf16* __restrict__ comb) {
    const int b = blockIdx.x;
    const int half = blockIdx.y;
    const int h = threadIdx.x;
    const float* p = lm + (size_t)b * Sc * 512 + half * 256 + h;
    bf16* o = comb + (size_t)b * Sc * CH + half * 256 + h;
    float mem = 0.0f;
    for (int s0 = 0; s0 < Sc; s0 += 8) {
        float xs[8];
#pragma unroll
        for (int q = 0; q < 8; ++q) xs[q] = p[(size_t)(s0 + q) * 512];
#pragma unroll
        for (int q = 0; q < 8; ++q) {
            const float reset = (mem > 1.0f) ? 1.0f : 0.0f;
            float t1 = 0.9f * mem;
            asm volatile("" : "+v"(t1));           // block FMA contraction: match np rounding
            float t2 = t1 + xs[q];
            asm volatile("" : "+v"(t2));
            mem = t2 - reset;
            o[(size_t)(s0 + q) * CH] = __float2bfloat16((mem > 1.0f) ? 1.0f : 0.0f);
        }
    }
}

// ---------------- halo-expanded conv input planes (vectorized short4) ----------------
__global__ __launch_bounds__(256) void k_aext3(const bf16* __restrict__ xh,
                                               const bf16* __restrict__ xm,
                                               const bf16* __restrict__ xl,
                                               bf16* __restrict__ aeh, bf16* __restrict__ aem,
                                               bf16* __restrict__ ael) {
    const int idx = blockIdx.x * 256 + threadIdx.x;   // < 1,572,864 (8192*768/4)
    const int row = idx / 192, c4 = idx % 192;        // c4: short4 index in 768-wide row
    const int c = c4 * 4;
    const int k = c >> 8, i = c & 255;
    const int b = row >> 9, s = row & 511;
    const int ss = s + k - 1;
    const size_t dst = (size_t)row * 768 + c;
    if (ss >= 0 && ss < Sc) {
        const size_t src = (size_t)(b * Sc + ss) * Hc + i;
        *(short4v*)(aeh + dst) = *(const short4v*)(xh + src);
        *(short4v*)(aem + dst) = *(const short4v*)(xm + src);
        *(short4v*)(ael + dst) = *(const short4v*)(xl + src);
    } else {
        const short4v z = {0, 0, 0, 0};
        *(short4v*)(aeh + dst) = z;
        *(short4v*)(aem + dst) = z;
        *(short4v*)(ael + dst) = z;
    }
}

// ======== head GEMM: 128x256 tile, BK=32, 4 waves, 48KB LDS, 2 blocks/CU ========
__device__ __forceinline__ void stageA32(const bf16* __restrict__ g, int rbase,
                                         bf16* lbase, int kt, int t) {
#pragma unroll
    for (int q = 0; q < 2; ++q) {
        const int f = q * 256 + t;
        const int rowt = f >> 2, chunk = f & 3;
        const int sch = chunk ^ ((rowt >> 1) & 3);
        const bf16* gp = g + (size_t)(rbase + rowt) * CH + kt * 32 + sch * 8;
        __builtin_amdgcn_global_load_lds((const __attribute__((address_space(1))) void*)gp,
                                         (__attribute__((address_space(3))) void*)(lbase + rowt * 32 + chunk * 8),
                                         16, 0, 0);
    }
}
__device__ __forceinline__ void stageB32(const bf16* __restrict__ g, int rbase, int rmax,
                                         bf16* lbase, int kt, int t) {
#pragma unroll
    for (int q = 0; q < 4; ++q) {
        const int f = q * 256 + t;
        const int rowt = f >> 2, chunk = f & 3;
        const int sch = chunk ^ ((rowt >> 1) & 3);
        int grow = rbase + rowt;
        if (grow > rmax) grow = rmax;
        const bf16* gp = g + (size_t)grow * CH + kt * 32 + sch * 8;
        __builtin_amdgcn_global_load_lds((const __attribute__((address_space(1))) void*)gp,
                                         (__attribute__((address_space(3))) void*)(lbase + rowt * 32 + chunk * 8),
                                         16, 0, 0);
    }
}

__global__ __launch_bounds__(256, 2) void k_head8(const bf16* __restrict__ Abf,
                                                  const bf16* __restrict__ Bbf,
                                                  const float* __restrict__ bias,
                                                  float* __restrict__ C) {
    __shared__ bf16 LA[2][128 * 32];
    __shared__ bf16 LB[2][256 * 32];
    const int t = threadIdx.x;
    const int w = t >> 6, lane = t & 63;
    const int wn = w;
    const int tm = blockIdx.x * 128, tn = blockIdx.y * 256;
    const int lr = lane & 15, lkc = lane >> 4;

    f32x4v acc[8][4];
    const f32x4v zero = {0.f, 0.f, 0.f, 0.f};
#pragma unroll
    for (int m = 0; m < 8; ++m)
#pragma unroll
        for (int n = 0; n < 4; ++n) acc[m][n] = zero;

    stageA32(Abf, tm, LA[0], 0, t);
    stageB32(Bbf, tn, Vc - 1, LB[0], 0, t);
    stageA32(Abf, tm, LA[1], 1, t);
    asm volatile("s_waitcnt vmcnt(2)" ::: "memory");
    __builtin_amdgcn_s_barrier();
    __builtin_amdgcn_sched_barrier(0);

    for (int kt = 0; kt < NT2; ++kt) {
        bf16* la = LA[kt & 1];
        bf16* lb = LB[kt & 1];
        bf16* lbN = LB[(kt + 1) & 1];
        short8v a[8], b[4];
#pragma unroll
        for (int m = 0; m < 8; ++m) {
            const int row = m * 16 + lr;
            const int sc = lkc ^ ((row >> 1) & 3);
            a[m] = *(const short8v*)(la + row * 32 + sc * 8);
        }
#pragma unroll
        for (int n = 0; n < 4; ++n) {
            const int row = wn * 64 + n * 16 + lr;
            const int sc = lkc ^ ((row >> 1) & 3);
            b[n] = *(const short8v*)(lb + row * 32 + sc * 8);
        }
        if (kt + 1 < NT2) stageB32(Bbf, tn, Vc - 1, lbN, kt + 1, t);
        __builtin_amdgcn_s_barrier();
        __builtin_amdgcn_sched_barrier(0);
        __builtin_amdgcn_s_setprio(1);
#pragma unroll
        for (int m = 0; m < 8; ++m)
#pragma unroll
            for (int n = 0; n < 2; ++n)
                acc[m][n] = __builtin_amdgcn_mfma_f32_16x16x32_bf16(a[m], b[n], acc[m][n], 0, 0, 0);
        __builtin_amdgcn_s_setprio(0);
        __builtin_amdgcn_s_barrier();
        __builtin_amdgcn_sched_barrier(0);
        if (kt + 2 < NT2) stageA32(Abf, tm, la, kt + 2, t);
        __builtin_amdgcn_s_setprio(1);
#pragma unroll
        for (int m = 0; m < 8; ++m)
#pragma unroll
            for (int n = 2; n < 4; ++n)
                acc[m][n] = __builtin_amdgcn_mfma_f32_16x16x32_bf16(a[m], b[n], acc[m][n], 0, 0, 0);
        __builtin_amdgcn_s_setprio(0);
        if (kt + 2 < NT2) asm volatile("s_waitcnt vmcnt(2)" ::: "memory");
        else              asm volatile("s_waitcnt vmcnt(0)" ::: "memory");
        __builtin_amdgcn_s_barrier();
        __builtin_amdgcn_sched_barrier(0);
    }
    const int lq = (lane >> 4) * 4;
#pragma unroll
    for (int n = 0; n < 4; ++n) {
        const int col = tn + wn * 64 + n * 16 + lr;
        if (col >= Vc) continue;
        const float bv = bias[col];
#pragma unroll
        for (int m = 0; m < 8; ++m) {
            const int rbase = tm + m * 16 + lq;
#pragma unroll
            for (int j = 0; j < 4; ++j)
                C[(size_t)(rbase + j) * Vc + col] = acc[m][n][j] + bv;
        }
    }
}

// ---------------- plan mean partials ----------------
__global__ __launch_bounds__(256) void k_pmean(const float* __restrict__ plan, float* __restrict__ pm2) {
    const int b = blockIdx.x, c = blockIdx.y;
    const int h = threadIdx.x;
    const float* p = plan + ((size_t)(b * Sc + c * 64)) * Hc + h;
    float s = 0.0f;
    for (int i = 0; i < 64; ++i) s += p[(size_t)i * Hc];
    pm2[((size_t)b * 8 + c) * Hc + h] = s;
}

// ---------------- read softmax + memory read ----------------
__global__ __launch_bounds__(256) void k_memread(const float* __restrict__ pm2,
                                                 const float* __restrict__ rw,
                                                 const float* __restrict__ rb,
                                                 const float* __restrict__ memm,
                                                 float* __restrict__ out) {
    const int b = blockIdx.x;
    const int t = threadIdx.x;
    __shared__ float pms[256];
    __shared__ float lg[64];
    __shared__ float sm[64];
    float v = 0.0f;
    for (int c = 0; c < 8; ++c) v += pm2[((size_t)b * 8 + c) * Hc + t];
    pms[t] = v * (1.0f / 512.0f);
    __syncthreads();
    if (t < 64) {
        float s = rb[t];
        const float* wrow = rw + (size_t)t * Hc;
        for (int i = 0; i < Hc; ++i) s = fmaf(wrow[i], pms[i], s);
        lg[t] = s;
    }
    __syncthreads();
    if (t == 0) {
        float mx = lg[0];
        for (int i = 1; i < 64; ++i) mx = fmaxf(mx, lg[i]);
        float ssum = 0.0f;
        for (int i = 0; i < 64; ++i) { const float e = expf(lg[i] - mx); sm[i] = e; ssum += e; }
        for (int i = 0; i < 64; ++i) sm[i] /= ssum;
    }
    __syncthreads();
    float s = 0.0f;
    for (int m = 0; m < 64; ++m) s = fmaf(sm[m], memm[(size_t)m * Hc + t], s);
    out[(size_t)b * Hc + t] = s;
}

extern "C" void kernel_launch(void* const* d_in, const int* in_sizes, int n_in,
                              void* d_out, int out_size, void* d_ws, size_t ws_size,
                              hipStream_t stream) {
    const int*   ids    = (const int*)  d_in[0];
    const float* embed  = (const float*)d_in[1];
    const float* pos    = (const float*)d_in[2];
    const float* qkv_w  = (const float*)d_in[3];
    const float* qkv_b  = (const float*)d_in[4];
    const float* out_w  = (const float*)d_in[5];
    const float* out_b  = (const float*)d_in[6];
    const float* ln1_g  = (const float*)d_in[7];
    const float* ln1_b  = (const float*)d_in[8];
    const float* ff1_w  = (const float*)d_in[9];
    const float* ff1_b  = (const float*)d_in[10];
    const float* ff2_w  = (const float*)d_in[11];
    const float* ff2_b  = (const float*)d_in[12];
    const float* ln2_g  = (const float*)d_in[13];
    const float* ln2_b  = (const float*)d_in[14];
    const float* log_w  = (const float*)d_in[15];
    const float* log_b  = (const float*)d_in[16];
    const float* mat_w  = (const float*)d_in[17];
    const float* mat_b  = (const float*)d_in[18];
    const float* conv_w = (const float*)d_in[19];
    const float* conv_b = (const float*)d_in[20];
    const float* read_w = (const float*)d_in[21];
    const float* read_b = (const float*)d_in[22];
    const float* memory = (const float*)d_in[23];
    const float* head_w = (const float*)d_in[24];
    const float* head_b = (const float*)d_in[25];

    char* wsb = (char*)d_ws;
    const size_t MB = 1ull << 20;
    float* X    = (float*)(wsb + 0);           // 8 MB [8192,256]
    bf16*  XH   = (bf16*)(wsb + 8 * MB);
    bf16*  XM   = (bf16*)(wsb + 12 * MB);
    bf16*  XL   = (bf16*)(wsb + 16 * MB);
    float* RES  = (float*)(wsb + 20 * MB);     // 8 MB
    bf16*  QPH  = (bf16*)(wsb + 28 * MB);      // 12 MB each [8192,768] planes
    bf16*  QPM  = (bf16*)(wsb + 40 * MB);
    bf16*  QPL  = (bf16*)(wsb + 52 * MB);
    bf16*  OH   = (bf16*)(wsb + 64 * MB);      // 4 MB each
    bf16*  OM   = (bf16*)(wsb + 68 * MB);
    bf16*  OL   = (bf16*)(wsb + 72 * MB);
    // ---- alias region 76..128 MB ----
    bf16*  VTH  = (bf16*)(wsb + 76 * MB);      // 4 MB each (attention phase)
    bf16*  VTM  = (bf16*)(wsb + 80 * MB);
    bf16*  VTL  = (bf16*)(wsb + 84 * MB);
    bf16*  H1H  = (bf16*)(wsb + 88 * MB);      // 8 MB each (ff phase; disjoint from VT)
    bf16*  H1M  = (bf16*)(wsb + 96 * MB);
    bf16*  H1L  = (bf16*)(wsb + 104 * MB);
    float* LOGMAT = (float*)(wsb + 76 * MB);   // 16 MB [8192,512] (post-loop)
    bf16*  AEH  = (bf16*)(wsb + 92 * MB);      // 12 MB each (post-loop)
    bf16*  AEM  = (bf16*)(wsb + 104 * MB);
    bf16*  AEL  = (bf16*)(wsb + 116 * MB);
    // ---------------------------------
    bf16*  COMB = (bf16*)(wsb + 128 * MB);     // 16 MB [8192,1024]
    bf16*  HWB  = (bf16*)(wsb + 144 * MB);     // 16 MB [8000,1024]
    bf16*  WP   = (bf16*)(wsb + 160 * MB);     // weight planes
    float* PM2  = (float*)(wsb + 64 * MB);     // [16,8,256] partials (reuse OH post-loop)

    float* logits = (float*)d_out;
    float* mread  = logits + (size_t)ROWS * Vc;

    // weight plane sub-offsets (elements)
    bf16* qkvwh = WP;             bf16* qkvwm = qkvwh + 393216; bf16* qkvwl = qkvwm + 393216;
    bf16* outwh = qkvwl + 393216; bf16* outwm = outwh + 131072; bf16* outwl = outwm + 131072;
    bf16* ff1wh = outwl + 131072; bf16* ff1wm = ff1wh + 262144; bf16* ff1wl = ff1wm + 262144;
    bf16* ff2wh = ff1wl + 262144; bf16* ff2wm = ff2wh + 262144; bf16* ff2wl = ff2wm + 262144;
    bf16* lmwh  = ff2wl + 262144; bf16* lmwm  = lmwh + 131072;  bf16* lmwl  = lmwm + 131072;
    bf16* w2h   = lmwl + 131072;  bf16* w2m   = w2h + 196608;   bf16* w2l   = w2m + 196608;
    float* LMB  = (float*)(w2l + 196608);      // [512] concat bias (after weight planes)

    hipFuncSetAttribute((const void*)k_attn, hipFuncAttributeMaxDynamicSharedMemorySize, 155648);

    // consolidated weight prep (one launch)
    k_prep<<<dim3(9921), 256, 0, stream>>>(
        qkv_w, out_w, ff1_w, ff2_w, log_w, mat_w, conv_w, head_w, log_b, mat_b,
        qkvwh, qkvwm, qkvwl, outwh, outwm, outwl, ff1wh, ff1wm, ff1wl,
        ff2wh, ff2wm, ff2wl, lmwh, lmwm, lmwl, w2h, w2m, w2l, HWB, LMB);

    k_embed<<<dim3(ROWS), 256, 0, stream>>>(ids, embed, pos, X, XH, XM, XL);
    for (int l = 0; l < 2; ++l) {
        // qkv -> QP planes [8192,768]
        k_bg3<0, 1, 128><<<dim3(64, 6, 1), 256, 0, stream>>>(
            XH, XM, XL,
            qkvwh + (size_t)l * 196608, qkvwm + (size_t)l * 196608, qkvwl + (size_t)l * 196608,
            qkv_b + l * 768, nullptr, QPH, QPM, QPL,
            256, 256, 256, 768, 0, 0, 0, 0, 0, 0);
        k_vt<<<dim3(8, 64), 256, 0, stream>>>(QPH, QPM, QPL, VTH, VTM, VTL);
        // fused scores + softmax + PV -> O planes (pipelined LDS staging)
        k_attn<<<dim3(8, 64), 512, 155648, stream>>>(QPH, QPM, QPL, VTH, VTM, VTL, OH, OM, OL);
        // out proj -> RES fp32
        k_bg3<0, 0, 64><<<dim3(64, 4, 1), 256, 0, stream>>>(
            OH, OM, OL,
            outwh + (size_t)l * 65536, outwm + (size_t)l * 65536, outwl + (size_t)l * 65536,
            out_b + l * 256, RES, nullptr, nullptr, nullptr,
            256, 256, 256, 256, 0, 0, 0, 0, 0, 0);
        k_add_ln<<<dim3(ROWS / 4), 256, 0, stream>>>(X, RES, ln1_g + l * 256, ln1_b + l * 256,
                                                     XH, XM, XL, nullptr);
        // ff1 + gelu -> H1 planes
        k_bg3<1, 1, 128><<<dim3(64, 4, 1), 256, 0, stream>>>(
            XH, XM, XL,
            ff1wh + (size_t)l * 131072, ff1wm + (size_t)l * 131072, ff1wl + (size_t)l * 131072,
            ff1_b + l * 512, nullptr, H1H, H1M, H1L,
            256, 256, 256, 512, 0, 0, 0, 0, 0, 0);
        // ff2 -> RES fp32
        k_bg3<0, 0, 64><<<dim3(64, 4, 1), 256, 0, stream>>>(
            H1H, H1M, H1L,
            ff2wh + (size_t)l * 131072, ff2wm + (size_t)l * 131072, ff2wl + (size_t)l * 131072,
            ff2_b + l * 256, RES, nullptr, nullptr, nullptr,
            512, 512, 512, 256, 0, 0, 0, 0, 0, 0);
        // final LN also packs plan into COMB (cols 768..1023)
        k_add_ln<<<dim3(ROWS / 4), 256, 0, stream>>>(X, RES, ln2_g + l * 256, ln2_b + l * 256,
                                                     XH, XM, XL, (l == 1) ? COMB : nullptr);
    }
    // plan = X; fused log+mat projection -> LOGMAT [8192,512]
    k_bg3<0, 0, 128><<<dim3(64, 4, 1), 256, 0, stream>>>(
        XH, XM, XL, lmwh, lmwm, lmwl, LMB, LOGMAT, nullptr, nullptr, nullptr,
        256, 256, 256, 512, 0, 0, 0, 0, 0, 0);
    k_aext3<<<dim3(6144), 256, 0, stream>>>(XH, XM, XL, AEH, AEM, AEL);
    k_lif2<<<dim3(Bc, 2), 256, 0, stream>>>(LOGMAT, COMB);
    // conv as GEMM -> bf16 directly into COMB cols 512..767 (OUTS=3)
    k_bg3<0, 3, 64><<<dim3(64, 4, 1), 256, 0, stream>>>(
        AEH, AEM, AEL, w2h, w2m, w2l, conv_b, (float*)(COMB + 512), nullptr, nullptr, nullptr,
        768, 768, 768, CH, 0, 0, 0, 0, 0, 0);
    k_head8<<<dim3(64, 32), 256, 0, stream>>>(COMB, HWB, head_b, logits);
    k_pmean<<<dim3(Bc, 8), 256, 0, stream>>>(X, PM2);
    k_memread<<<dim3(Bc), 256, 0, stream>>>(PM2, read_w, read_b, memory, mread);
}

// Round 16
// 705.601 us; speedup vs baseline: 1.7444x; 1.0216x over previous
//
#include <hip/hip_runtime.h>
#include <hip/hip_bf16.h>

// Problem constants
constexpr int Bc = 16, Sc = 512, Hc = 256, Vc = 8000, NHc = 4, HDc = 64;
constexpr int FFc = 512, Mc = 64;
constexpr int ROWS = Bc * Sc;      // 8192
constexpr int CH = 4 * Hc;         // 1024
constexpr int NT2 = CH / 32;       // 32 K-tiles (BK=32) for the head GEMM

typedef __attribute__((ext_vector_type(4))) float f32x4v;
typedef __attribute__((ext_vector_type(8))) short short8v;
typedef __attribute__((ext_vector_type(4))) short short4v;
typedef __hip_bfloat16 bf16;

// ---- 3-way bf16 split: x = h + m + l + O(2^-27 |x|) ----
__device__ inline void split3(float x, bf16& h, bf16& m, bf16& l) {
    h = __float2bfloat16(x);
    const float r = x - __bfloat162float(h);   // exact
    m = __float2bfloat16(r);
    const float r2 = r - __bfloat162float(m);  // exact
    l = __float2bfloat16(r2);
}

// ---------------- consolidated weight prep (one launch) ----------------
__device__ __forceinline__ void split_range(const float* __restrict__ in,
                                            bf16* __restrict__ h, bf16* __restrict__ m,
                                            bf16* __restrict__ l, int blk, int t) {
    const size_t i = ((size_t)blk * 256 + t) * 4;
    const float4 v = *(const float4*)&in[i];
    split3(v.x, h[i + 0], m[i + 0], l[i + 0]);
    split3(v.y, h[i + 1], m[i + 1], l[i + 1]);
    split3(v.z, h[i + 2], m[i + 2], l[i + 2]);
    split3(v.w, h[i + 3], m[i + 3], l[i + 3]);
}

__global__ __launch_bounds__(256) void k_prep(
    const float* __restrict__ qkv_w, const float* __restrict__ out_w,
    const float* __restrict__ ff1_w, const float* __restrict__ ff2_w,
    const float* __restrict__ log_w, const float* __restrict__ mat_w,
    const float* __restrict__ conv_w, const float* __restrict__ head_w,
    const float* __restrict__ log_b, const float* __restrict__ mat_b,
    bf16* qkvwh, bf16* qkvwm, bf16* qkvwl,
    bf16* outwh, bf16* outwm, bf16* outwl,
    bf16* ff1wh, bf16* ff1wm, bf16* ff1wl,
    bf16* ff2wh, bf16* ff2wm, bf16* ff2wl,
    bf16* lmwh, bf16* lmwm, bf16* lmwl,
    bf16* w2h, bf16* w2m, bf16* w2l,
    bf16* hwb, float* lmb, bf16* zb) {
    const int blk = blockIdx.x;
    const int t = threadIdx.x;
    if (blk < 384) {
        split_range(qkv_w, qkvwh, qkvwm, qkvwl, blk, t);
    } else if (blk < 512) {
        split_range(out_w, outwh, outwm, outwl, blk - 384, t);
    } else if (blk < 768) {
        split_range(ff1_w, ff1wh, ff1wm, ff1wl, blk - 512, t);
    } else if (blk < 1024) {
        split_range(ff2_w, ff2wh, ff2wm, ff2wl, blk - 768, t);
    } else if (blk < 1088) {
        split_range(log_w, lmwh, lmwm, lmwl, blk - 1024, t);
    } else if (blk < 1152) {
        split_range(mat_w, lmwh + 65536, lmwm + 65536, lmwl + 65536, blk - 1088, t);
    } else if (blk < 1920) {
        const int idx = (blk - 1152) * 256 + t;       // conv re-layout + split
        const int o = idx / 768, rem = idx % 768;
        const int k = rem >> 8, i = rem & 255;
        split3(conv_w[(size_t)o * 768 + i * 3 + k], w2h[idx], w2m[idx], w2l[idx]);
    } else if (blk < 9920) {
        const size_t i = ((size_t)(blk - 1920) * 256 + t) * 4;   // head_w -> bf16, vector store
        const float4 v = *(const float4*)&head_w[i];
        bf16 b0 = __float2bfloat16(v.x), b1 = __float2bfloat16(v.y);
        bf16 b2 = __float2bfloat16(v.z), b3 = __float2bfloat16(v.w);
        short4v sv;
        sv[0] = *(const short*)&b0; sv[1] = *(const short*)&b1;
        sv[2] = *(const short*)&b2; sv[3] = *(const short*)&b3;
        *(short4v*)(hwb + i) = sv;
    } else {
        lmb[t] = log_b[t];
        lmb[256 + t] = mat_b[t];
        if (t < 64) ((short*)zb)[t] = 0;              // zero stub for conv halo OOB rows
    }
}

// ---------------- embed + pos (+ split planes), wave-per-row vectorized ----------------
__global__ __launch_bounds__(256) void k_embed(const int* __restrict__ ids,
                                               const float* __restrict__ emb,
                                               const float* __restrict__ pos,
                                               float* __restrict__ x,
                                               bf16* __restrict__ xh, bf16* __restrict__ xm,
                                               bf16* __restrict__ xl) {
    const int w = threadIdx.x >> 6, lane = threadIdx.x & 63;
    const int r = blockIdx.x * 4 + w;
    const int s = r & (Sc - 1);
    const int id = ids[r];
    const int e0 = lane * 4;
    const float4 ev = *(const float4*)&emb[(size_t)id * Hc + e0];
    const float4 pv = *(const float4*)&pos[(size_t)s * Hc + e0];
    const float v[4] = {ev.x + pv.x, ev.y + pv.y, ev.z + pv.z, ev.w + pv.w};
    const size_t o = (size_t)r * Hc + e0;
    *(float4*)(x + o) = *(const float4*)&v[0];
    short4v sh, sm, sl;
#pragma unroll
    for (int j = 0; j < 4; ++j) {
        bf16 a, b, c;
        split3(v[j], a, b, c);
        sh[j] = *(const short*)&a; sm[j] = *(const short*)&b; sl[j] = *(const short*)&c;
    }
    *(short4v*)(xh + o) = sh;
    *(short4v*)(xm + o) = sm;
    *(short4v*)(xl + o) = sl;
}

// ======== batched bf16x3 MFMA GEMM: C = A[M,K] @ B[N,K]^T ========
// EPI: 0 = +bias, 1 = gelu(x+bias), 3 = none
// OUTS: 0 = fp32 C, 1 = split3 planes, 3 = bf16 write into C (cast) at ldc stride
// HALO: A planes are X [8192,256]; logical A[row][k] = X[b*512 + s + (k>>8) - 1][k&255],
//       zero (via zb stub) when the shifted row is out of range. Bytes in LDS identical
//       to the materialized AEXT, so results are bit-identical.
template <int EPI, int OUTS, int BN, int HALO = 0>
__global__ __launch_bounds__(256) void k_bg3(
    const bf16* __restrict__ Ah, const bf16* __restrict__ Am, const bf16* __restrict__ Al,
    const bf16* __restrict__ Bh, const bf16* __restrict__ Bm, const bf16* __restrict__ Bl,
    const float* __restrict__ bias, float* __restrict__ C,
    bf16* __restrict__ Oh, bf16* __restrict__ Om, bf16* __restrict__ Ol,
    int K, int lda, int ldb, int ldc,
    long zA2, long zA1, long zB2, long zB1, long zC2, long zC1,
    const bf16* __restrict__ zb) {
    constexpr int NF = BN / 32;
    __shared__ bf16 As[3][128 * 32];
    __shared__ bf16 Bs[3][BN * 32];
    const int z = blockIdx.z, z2 = z >> 2, z1 = z & 3;
    const size_t aoff = (size_t)z2 * zA2 + (size_t)z1 * zA1;
    const size_t boff = (size_t)z2 * zB2 + (size_t)z1 * zB1;
    const size_t coff = (size_t)z2 * zC2 + (size_t)z1 * zC1;
    const int t = threadIdx.x;
    const int tm = blockIdx.x * 128, tn = blockIdx.y * BN;
    const int w = t >> 6, l = t & 63;
    const int wr = w >> 1, wc = w & 1;
    const bf16* Ap[3] = {Ah, Am, Al};
    const bf16* Bp[3] = {Bh, Bm, Bl};
    f32x4v acc[4][NF];
    const f32x4v zero = {0.f, 0.f, 0.f, 0.f};
#pragma unroll
    for (int i = 0; i < 4; ++i)
#pragma unroll
        for (int j = 0; j < NF; ++j) acc[i][j] = zero;

    for (int kt = 0; kt < K; kt += 32) {
#pragma unroll
        for (int p = 0; p < 3; ++p) {
#pragma unroll
            for (int j = 0; j < 2; ++j) {
                const int c = j * 256 + t;
                const int row = c >> 2, kc = c & 3;
                const int skc = kc ^ ((row >> 1) & 3);
                const bf16* ga;
                if (HALO) {
                    const int kk = kt + skc * 8;
                    const int dk = kk >> 8, ii = kk & 255;
                    const int grow = tm + row;
                    const int bb = grow >> 9, s = grow & 511;
                    const int ss = s + dk - 1;
                    ga = (ss >= 0 && ss < Sc) ? (Ap[p] + ((size_t)(bb * Sc + ss) * Hc + ii)) : zb;
                } else {
                    ga = Ap[p] + aoff + (size_t)(tm + row) * lda + kt + skc * 8;
                }
                __builtin_amdgcn_global_load_lds((const __attribute__((address_space(1))) void*)ga,
                                                 (__attribute__((address_space(3))) void*)(&As[p][0] + c * 8),
                                                 16, 0, 0);
            }
            if (BN == 128) {
#pragma unroll
                for (int j = 0; j < 2; ++j) {
                    const int c = j * 256 + t;
                    const int row = c >> 2, kc = c & 3;
                    const int skc = kc ^ ((row >> 1) & 3);
                    const bf16* gb = Bp[p] + boff + (size_t)(tn + row) * ldb + kt + skc * 8;
                    __builtin_amdgcn_global_load_lds((const __attribute__((address_space(1))) void*)gb,
                                                     (__attribute__((address_space(3))) void*)(&Bs[p][0] + c * 8),
                                                     16, 0, 0);
                }
            } else {
                const int c = t;
                const int row = c >> 2, kc = c & 3;
                const int skc = kc ^ ((row >> 1) & 3);
                const bf16* gb = Bp[p] + boff + (size_t)(tn + row) * ldb + kt + skc * 8;
                __builtin_amdgcn_global_load_lds((const __attribute__((address_space(1))) void*)gb,
                                                 (__attribute__((address_space(3))) void*)(&Bs[p][0] + c * 8),
                                                 16, 0, 0);
            }
        }
        __syncthreads();
        const int lr = l & 15, lkc = l >> 4;
        short8v af[3][4], bfr[3][NF];
#pragma unroll
        for (int p = 0; p < 3; ++p)
#pragma unroll
            for (int m = 0; m < 4; ++m) {
                const int row = wr * 64 + m * 16 + lr;
                const int sc = lkc ^ ((row >> 1) & 3);
                af[p][m] = *(const short8v*)(&As[p][0] + row * 32 + sc * 8);
            }
#pragma unroll
        for (int p = 0; p < 3; ++p)
#pragma unroll
            for (int n = 0; n < NF; ++n) {
                const int row = wc * (BN / 2) + n * 16 + lr;
                const int sc = lkc ^ ((row >> 1) & 3);
                bfr[p][n] = *(const short8v*)(&Bs[p][0] + row * 32 + sc * 8);
            }
        // 6 term passes: hh, hm, mh, hl, lh, mm
#pragma unroll
        for (int m = 0; m < 4; ++m)
#pragma unroll
            for (int n = 0; n < NF; ++n)
                acc[m][n] = __builtin_amdgcn_mfma_f32_16x16x32_bf16(af[0][m], bfr[0][n], acc[m][n], 0, 0, 0);
#pragma unroll
        for (int m = 0; m < 4; ++m)
#pragma unroll
            for (int n = 0; n < NF; ++n)
                acc[m][n] = __builtin_amdgcn_mfma_f32_16x16x32_bf16(af[0][m], bfr[1][n], acc[m][n], 0, 0, 0);
#pragma unroll
        for (int m = 0; m < 4; ++m)
#pragma unroll
            for (int n = 0; n < NF; ++n)
                acc[m][n] = __builtin_amdgcn_mfma_f32_16x16x32_bf16(af[1][m], bfr[0][n], acc[m][n], 0, 0, 0);
#pragma unroll
        for (int m = 0; m < 4; ++m)
#pragma unroll
            for (int n = 0; n < NF; ++n)
                acc[m][n] = __builtin_amdgcn_mfma_f32_16x16x32_bf16(af[0][m], bfr[2][n], acc[m][n], 0, 0, 0);
#pragma unroll
        for (int m = 0; m < 4; ++m)
#pragma unroll
            for (int n = 0; n < NF; ++n)
                acc[m][n] = __builtin_amdgcn_mfma_f32_16x16x32_bf16(af[2][m], bfr[0][n], acc[m][n], 0, 0, 0);
#pragma unroll
        for (int m = 0; m < 4; ++m)
#pragma unroll
            for (int n = 0; n < NF; ++n)
                acc[m][n] = __builtin_amdgcn_mfma_f32_16x16x32_bf16(af[1][m], bfr[1][n], acc[m][n], 0, 0, 0);
        __syncthreads();
    }
    const int lr = l & 15, lq = (l >> 4) * 4;
#pragma unroll
    for (int n = 0; n < NF; ++n) {
        const int col = tn + wc * (BN / 2) + n * 16 + lr;
        const float bv = (EPI == 0 || EPI == 1) ? bias[col] : 0.0f;
#pragma unroll
        for (int m = 0; m < 4; ++m) {
            const int rbase = tm + wr * 64 + m * 16 + lq;
#pragma unroll
            for (int j = 0; j < 4; ++j) {
                float v = acc[m][n][j];
                if (EPI == 0) v += bv;
                if (EPI == 1) { v += bv; v = 0.5f * v * (1.0f + erff(v / 1.41421356237309515f)); }
                const size_t o = coff + (size_t)(rbase + j) * ldc + col;
                if (OUTS == 0) C[o] = v;
                else if (OUTS == 3) ((bf16*)C)[o] = __float2bfloat16(v);
                else split3(v, Oh[o], Om[o], Ol[o]);
            }
        }
    }
}

// ---------------- V-transpose: VT[z][d][s] from qkv planes (single barrier) ----------------
__global__ __launch_bounds__(256) void k_vt(const bf16* __restrict__ qh,
                                            const bf16* __restrict__ qm,
                                            const bf16* __restrict__ ql,
                                            bf16* __restrict__ vh, bf16* __restrict__ vm,
                                            bf16* __restrict__ vl) {
    __shared__ bf16 tile[3][64][72];
    const int sblk = blockIdx.x;           // 0..7
    const int z = blockIdx.y;              // 0..63
    const int b = z >> 2, h = z & 3;
    const int t = threadIdx.x;
    const int sr = t >> 2, c16 = (t & 3) * 16;
    const bf16* qp[3] = {qh, qm, ql};
    bf16* vp[3] = {vh, vm, vl};
#pragma unroll
    for (int p = 0; p < 3; ++p) {
        const bf16* src = qp[p] + (size_t)(b * Sc + sblk * 64 + sr) * 768 + 512 + h * 64 + c16;
        *(short8v*)&tile[p][sr][c16] = *(const short8v*)src;
        *(short8v*)&tile[p][sr][c16 + 8] = *(const short8v*)(src + 8);
    }
    __syncthreads();
#pragma unroll
    for (int p = 0; p < 3; ++p) {
        bf16 out[16];
#pragma unroll
        for (int i = 0; i < 16; ++i) out[i] = tile[p][c16 + i][sr];
        bf16* dst = vp[p] + (size_t)(z * 64 + sr) * Sc + sblk * 64 + c16;
        *(short8v*)dst = *(short8v*)&out[0];
        *(short8v*)(dst + 8) = *(short8v*)&out[8];
    }
}

// ======== fused attention (R8 version): pipelined LDS staging, issue-early ========
#define S_PASS(QA, KB)                                                                     \
    _Pragma("unroll") for (int m = 0; m < 2; ++m) _Pragma("unroll") for (int ks = 0; ks < 2; ++ks) \
        sa[m] = __builtin_amdgcn_mfma_f32_16x16x32_bf16(QA[m][ks], KB[ks], sa[m], 0, 0, 0);
#define PV_PASS(PA, VB)                                                                    \
    _Pragma("unroll") for (int m = 0; m < 2; ++m) _Pragma("unroll") for (int ks = 0; ks < 2; ++ks) \
        oa[m] = __builtin_amdgcn_mfma_f32_16x16x32_bf16(PA[m][ks], VB[ks], oa[m], 0, 0, 0);

__global__ __launch_bounds__(512) void k_attn(
    const bf16* __restrict__ qph, const bf16* __restrict__ qpm, const bf16* __restrict__ qpl,
    const bf16* __restrict__ vth, const bf16* __restrict__ vtm, const bf16* __restrict__ vtl,
    bf16* __restrict__ oh, bf16* __restrict__ om, bf16* __restrict__ ol) {
    extern __shared__ char smem[];
    float* S = (float*)smem;                        // 64 x 512 fp32, swizzled
    bf16* KV0 = (bf16*)(smem + 131072);             // 3 planes of [64][64]
    bf16* KV1 = KV0 + 4096;
    bf16* KV2 = KV1 + 4096;
    const int qc = blockIdx.x, z = blockIdx.y;
    const int b = z >> 2, hh = z & 3;
    const int t = threadIdx.x;
    const int w = t >> 6, lane = t & 63;
    const int lr = lane & 15, lkc = lane >> 4;      // lkc 0..3
    const int qg = w >> 2, kg = w & 3;
    const int r8 = t >> 3, c8 = t & 7;              // staging map
    const f32x4v zero = {0.f, 0.f, 0.f, 0.f};

    // Q A-frags in registers (one-time gather)
    short8v qf0[2][2], qf1[2][2], qf2[2][2];
#pragma unroll
    for (int m = 0; m < 2; ++m)
#pragma unroll
        for (int ks = 0; ks < 2; ++ks) {
            const size_t rbase = (size_t)(b * 512 + qc * 64 + qg * 32 + m * 16 + lr) * 768 + hh * 64 + ks * 32 + lkc * 8;
            qf0[m][ks] = *(const short8v*)(qph + rbase);
            qf1[m][ks] = *(const short8v*)(qpm + rbase);
            qf2[m][ks] = *(const short8v*)(qpl + rbase);
        }

    // stage K(0)
    {
        const size_t srow = (size_t)(b * 512 + 0 * 64 + r8) * 768 + 256 + hh * 64 + (c8 ^ (r8 & 7)) * 8;
        __builtin_amdgcn_global_load_lds((const __attribute__((address_space(1))) void*)(qph + srow),
                                         (__attribute__((address_space(3))) void*)(KV0 + r8 * 64 + c8 * 8), 16, 0, 0);
        __builtin_amdgcn_global_load_lds((const __attribute__((address_space(1))) void*)(qpm + srow),
                                         (__attribute__((address_space(3))) void*)(KV1 + r8 * 64 + c8 * 8), 16, 0, 0);
        __builtin_amdgcn_global_load_lds((const __attribute__((address_space(1))) void*)(qpl + srow),
                                         (__attribute__((address_space(3))) void*)(KV2 + r8 * 64 + c8 * 8), 16, 0, 0);
    }

    // ---- scores: S[q][kv] = (Q.K)/8 ----
    for (int kv = 0; kv < 8; ++kv) {
        __syncthreads();                             // K(kv) resident (vmcnt drained)
        short8v kb0[2], kb1[2], kb2[2];
#pragma unroll
        for (int ks = 0; ks < 2; ++ks) {
            const int row = kg * 16 + lr;
            const int sc = (ks * 4 + lkc) ^ (row & 7);
            kb0[ks] = *(const short8v*)(KV0 + row * 64 + sc * 8);
            kb1[ks] = *(const short8v*)(KV1 + row * 64 + sc * 8);
            kb2[ks] = *(const short8v*)(KV2 + row * 64 + sc * 8);
        }
        __syncthreads();                             // all reads done; KV buffer free
        if (kv < 7) {                                // issue-early: K(kv+1) overlaps compute
            const size_t srow = (size_t)(b * 512 + (kv + 1) * 64 + r8) * 768 + 256 + hh * 64 + (c8 ^ (r8 & 7)) * 8;
            __builtin_amdgcn_global_load_lds((const __attribute__((address_space(1))) void*)(qph + srow),
                                             (__attribute__((address_space(3))) void*)(KV0 + r8 * 64 + c8 * 8), 16, 0, 0);
            __builtin_amdgcn_global_load_lds((const __attribute__((address_space(1))) void*)(qpm + srow),
                                             (__attribute__((address_space(3))) void*)(KV1 + r8 * 64 + c8 * 8), 16, 0, 0);
            __builtin_amdgcn_global_load_lds((const __attribute__((address_space(1))) void*)(qpl + srow),
                                             (__attribute__((address_space(3))) void*)(KV2 + r8 * 64 + c8 * 8), 16, 0, 0);
        } else {                                     // prefetch V(0) under softmax
            const size_t srow = (size_t)(z * 64 + r8) * 512 + 0 * 64 + (c8 ^ (r8 & 7)) * 8;
            __builtin_amdgcn_global_load_lds((const __attribute__((address_space(1))) void*)(vth + srow),
                                             (__attribute__((address_space(3))) void*)(KV0 + r8 * 64 + c8 * 8), 16, 0, 0);
            __builtin_amdgcn_global_load_lds((const __attribute__((address_space(1))) void*)(vtm + srow),
                                             (__attribute__((address_space(3))) void*)(KV1 + r8 * 64 + c8 * 8), 16, 0, 0);
            __builtin_amdgcn_global_load_lds((const __attribute__((address_space(1))) void*)(vtl + srow),
                                             (__attribute__((address_space(3))) void*)(KV2 + r8 * 64 + c8 * 8), 16, 0, 0);
        }
        f32x4v sa[2] = {zero, zero};
        S_PASS(qf0, kb0) S_PASS(qf0, kb1) S_PASS(qf1, kb0)
        S_PASS(qf0, kb2) S_PASS(qf2, kb0) S_PASS(qf1, kb1)
#pragma unroll
        for (int m = 0; m < 2; ++m)
#pragma unroll
            for (int j = 0; j < 4; ++j) {
                const int row = qg * 32 + m * 16 + (lane >> 4) * 4 + j;
                const int col = kv * 64 + kg * 16 + lr;
                const int chunk = (col >> 2) ^ (row & 7);
                *(float*)((char*)S + row * 2048 + chunk * 16 + (col & 3) * 4) = sa[m][j] * 0.125f;
            }
    }
    __syncthreads();                                 // S complete; V(0) resident

    // ---- exact softmax per row (wave w owns rows w*8..w*8+7) ----
    for (int r = 0; r < 8; ++r) {
        const int row = w * 8 + r;
        char* rowp = (char*)S + row * 2048;
        const int sw = row & 7;
        float4 x0 = *(float4*)(rowp + ((2 * lane) ^ sw) * 16);
        float4 x1 = *(float4*)(rowp + ((2 * lane + 1) ^ sw) * 16);
        float mx = fmaxf(fmaxf(fmaxf(x0.x, x0.y), fmaxf(x0.z, x0.w)),
                         fmaxf(fmaxf(x1.x, x1.y), fmaxf(x1.z, x1.w)));
#pragma unroll
        for (int d = 1; d < 64; d <<= 1) mx = fmaxf(mx, __shfl_xor(mx, d));
        const float e0 = expf(x0.x - mx), e1 = expf(x0.y - mx), e2 = expf(x0.z - mx), e3 = expf(x0.w - mx);
        const float e4 = expf(x1.x - mx), e5 = expf(x1.y - mx), e6 = expf(x1.z - mx), e7 = expf(x1.w - mx);
        float sm = ((e0 + e1) + (e2 + e3)) + ((e4 + e5) + (e6 + e7));
#pragma unroll
        for (int d = 1; d < 64; d <<= 1) sm += __shfl_xor(sm, d);
        x0.x = e0 / sm; x0.y = e1 / sm; x0.z = e2 / sm; x0.w = e3 / sm;
        x1.x = e4 / sm; x1.y = e5 / sm; x1.z = e6 / sm; x1.w = e7 / sm;
        *(float4*)(rowp + ((2 * lane) ^ sw) * 16) = x0;
        *(float4*)(rowp + ((2 * lane + 1) ^ sw) * 16) = x1;
    }
    __syncthreads();

    // ---- PV: O[q][d] = sum_kv P[q][kv] * VT[d][kv] ----
    f32x4v oa[2] = {zero, zero};
    for (int kv = 0; kv < 8; ++kv) {
        if (kv > 0) __syncthreads();                 // V(kv) resident
        short8v vb0[2], vb1[2], vb2[2];
#pragma unroll
        for (int ks = 0; ks < 2; ++ks) {
            const int rowd = kg * 16 + lr;
            const int sc = (ks * 4 + lkc) ^ (rowd & 7);
            vb0[ks] = *(const short8v*)(KV0 + rowd * 64 + sc * 8);
            vb1[ks] = *(const short8v*)(KV1 + rowd * 64 + sc * 8);
            vb2[ks] = *(const short8v*)(KV2 + rowd * 64 + sc * 8);
        }
        __syncthreads();                             // reads done; KV free
        if (kv < 7) {
            const size_t srow = (size_t)(z * 64 + r8) * 512 + (kv + 1) * 64 + (c8 ^ (r8 & 7)) * 8;
            __builtin_amdgcn_global_load_lds((const __attribute__((address_space(1))) void*)(vth + srow),
                                             (__attribute__((address_space(3))) void*)(KV0 + r8 * 64 + c8 * 8), 16, 0, 0);
            __builtin_amdgcn_global_load_lds((const __attribute__((address_space(1))) void*)(vtm + srow),
                                             (__attribute__((address_space(3))) void*)(KV1 + r8 * 64 + c8 * 8), 16, 0, 0);
            __builtin_amdgcn_global_load_lds((const __attribute__((address_space(1))) void*)(vtl + srow),
                                             (__attribute__((address_space(3))) void*)(KV2 + r8 * 64 + c8 * 8), 16, 0, 0);
        }
        short8v pah[2][2], pam[2][2], pal[2][2];
#pragma unroll
        for (int m = 0; m < 2; ++m)
#pragma unroll
            for (int ks = 0; ks < 2; ++ks) {
                const int row = qg * 32 + m * 16 + lr;
                const int c0 = kv * 16 + ks * 8 + lkc * 2;
                char* rp = (char*)S + row * 2048;
                const float4 y0 = *(const float4*)(rp + (c0 ^ (row & 7)) * 16);
                const float4 y1 = *(const float4*)(rp + ((c0 + 1) ^ (row & 7)) * 16);
                const float yy[8] = {y0.x, y0.y, y0.z, y0.w, y1.x, y1.y, y1.z, y1.w};
                short8v hv, mv, lv;
#pragma unroll
                for (int i = 0; i < 8; ++i) {
                    bf16 a, bq, c;
                    split3(yy[i], a, bq, c);
                    hv[i] = *(const short*)&a; mv[i] = *(const short*)&bq; lv[i] = *(const short*)&c;
                }
                pah[m][ks] = hv; pam[m][ks] = mv; pal[m][ks] = lv;
            }
        PV_PASS(pah, vb0) PV_PASS(pah, vb1) PV_PASS(pam, vb0)
        PV_PASS(pah, vb2) PV_PASS(pal, vb0) PV_PASS(pam, vb1)
    }
    // epilogue: O planes [8192][256]
#pragma unroll
    for (int m = 0; m < 2; ++m)
#pragma unroll
        for (int j = 0; j < 4; ++j) {
            const int grow = b * 512 + qc * 64 + qg * 32 + m * 16 + (lane >> 4) * 4 + j;
            const int col = hh * 64 + kg * 16 + lr;
            const size_t o = (size_t)grow * 256 + col;
            split3(oa[m][j], oh[o], om[o], ol[o]);
        }
}

// ---------------- x = LayerNorm(x + res) * g + b — wave-parallel, bit-identical tree ----------------
__global__ __launch_bounds__(256) void k_add_ln(float* __restrict__ x,
                                                const float* __restrict__ res,
                                                const float* __restrict__ g,
                                                const float* __restrict__ b,
                                                bf16* __restrict__ xh, bf16* __restrict__ xm,
                                                bf16* __restrict__ xl,
                                                bf16* __restrict__ comb) {
    const int w = threadIdx.x >> 6, lane = threadIdx.x & 63;
    const size_t row = (size_t)blockIdx.x * 4 + w;
    float v[4];
#pragma unroll
    for (int j = 0; j < 4; ++j) {
        const int e = lane + j * 64;
        v[j] = x[row * Hc + e] + res[row * Hc + e];
    }
    float a = v[0] + v[2];
    float bb = v[1] + v[3];
    float c = a + bb;
#pragma unroll
    for (int d = 32; d >= 1; d >>= 1) c += __shfl_xor(c, d);
    const float mean = c * (1.0f / 256.0f);
    float dd[4], sq[4];
#pragma unroll
    for (int j = 0; j < 4; ++j) {
        dd[j] = v[j] - mean;
        sq[j] = dd[j] * dd[j];
        asm volatile("" : "+v"(sq[j]));
    }
    float a2 = sq[0] + sq[2];
    float b2 = sq[1] + sq[3];
    float c2 = a2 + b2;
#pragma unroll
    for (int d = 32; d >= 1; d >>= 1) c2 += __shfl_xor(c2, d);
    const float var = c2 * (1.0f / 256.0f);
    const float rstd = sqrtf(var + 1e-5f);
#pragma unroll
    for (int j = 0; j < 4; ++j) {
        const int e = lane + j * 64;
        const float out = dd[j] / rstd * g[e] + b[e];
        const size_t o = row * Hc + e;
        x[o] = out;
        split3(out, xh[o], xm[o], xl[o]);
        if (comb != nullptr) comb[row * CH + 768 + e] = __float2bfloat16(out);
    }
}

// ---------------- LIF scan (both heads; 8-row load batches for ILP) ----------------
__global__ __launch_bounds__(256) void k_lif2(const float* __restrict__ lm,
                                              bf16* __restrict__ comb) {
    const int b = blockIdx.x;
    const int half = blockIdx.y;
    const int h = threadIdx.x;
    const float* p = lm + (size_t)b * Sc * 512 + half * 256 + h;
    bf16* o = comb + (size_t)b * Sc * CH + half * 256 + h;
    float mem = 0.0f;
    for (int s0 = 0; s0 < Sc; s0 += 8) {
        float xs[8];
#pragma unroll
        for (int q = 0; q < 8; ++q) xs[q] = p[(size_t)(s0 + q) * 512];
#pragma unroll
        for (int q = 0; q < 8; ++q) {
            const float reset = (mem > 1.0f) ? 1.0f : 0.0f;
            float t1 = 0.9f * mem;
            asm volatile("" : "+v"(t1));           // block FMA contraction: match np rounding
            float t2 = t1 + xs[q];
            asm volatile("" : "+v"(t2));
            mem = t2 - reset;
            o[(size_t)(s0 + q) * CH] = __float2bfloat16((mem > 1.0f) ? 1.0f : 0.0f);
        }
    }
}

// ======== head GEMM: 128x256 tile, BK=32, 4 waves, 48KB LDS, 2 blocks/CU ========
__device__ __forceinline__ void stageA32(const bf16* __restrict__ g, int rbase,
                                         bf16* lbase, int kt, int t) {
#pragma unroll
    for (int q = 0; q < 2; ++q) {
        const int f = q * 256 + t;
        const int rowt = f >> 2, chunk = f & 3;
        const int sch = chunk ^ ((rowt >> 1) & 3);
        const bf16* gp = g + (size_t)(rbase + rowt) * CH + kt * 32 + sch * 8;
        __builtin_amdgcn_global_load_lds((const __attribute__((address_space(1))) void*)gp,
                                         (__attribute__((address_space(3))) void*)(lbase + rowt * 32 + chunk * 8),
                                         16, 0, 0);
    }
}
__device__ __forceinline__ void stageB32(const bf16* __restrict__ g, int rbase, int rmax,
                                         bf16* lbase, int kt, int t) {
#pragma unroll
    for (int q = 0; q < 4; ++q) {
        const int f = q * 256 + t;
        const int rowt = f >> 2, chunk = f & 3;
        const int sch = chunk ^ ((rowt >> 1) & 3);
        int grow = rbase + rowt;
        if (grow > rmax) grow = rmax;
        const bf16* gp = g + (size_t)grow * CH + kt * 32 + sch * 8;
        __builtin_amdgcn_global_load_lds((const __attribute__((address_space(1))) void*)gp,
                                         (__attribute__((address_space(3))) void*)(lbase + rowt * 32 + chunk * 8),
                                         16, 0, 0);
    }
}

__global__ __launch_bounds__(256, 2) void k_head8(const bf16* __restrict__ Abf,
                                                  const bf16* __restrict__ Bbf,
                                                  const float* __restrict__ bias,
                                                  float* __restrict__ C) {
    __shared__ bf16 LA[2][128 * 32];
    __shared__ bf16 LB[2][256 * 32];
    const int t = threadIdx.x;
    const int w = t >> 6, lane = t & 63;
    const int wn = w;
    const int tm = blockIdx.x * 128, tn = blockIdx.y * 256;
    const int lr = lane & 15, lkc = lane >> 4;

    f32x4v acc[8][4];
    const f32x4v zero = {0.f, 0.f, 0.f, 0.f};
#pragma unroll
    for (int m = 0; m < 8; ++m)
#pragma unroll
        for (int n = 0; n < 4; ++n) acc[m][n] = zero;

    stageA32(Abf, tm, LA[0], 0, t);
    stageB32(Bbf, tn, Vc - 1, LB[0], 0, t);
    stageA32(Abf, tm, LA[1], 1, t);
    asm volatile("s_waitcnt vmcnt(2)" ::: "memory");
    __builtin_amdgcn_s_barrier();
    __builtin_amdgcn_sched_barrier(0);

    for (int kt = 0; kt < NT2; ++kt) {
        bf16* la = LA[kt & 1];
        bf16* lb = LB[kt & 1];
        bf16* lbN = LB[(kt + 1) & 1];
        short8v a[8], b[4];
#pragma unroll
        for (int m = 0; m < 8; ++m) {
            const int row = m * 16 + lr;
            const int sc = lkc ^ ((row >> 1) & 3);
            a[m] = *(const short8v*)(la + row * 32 + sc * 8);
        }
#pragma unroll
        for (int n = 0; n < 4; ++n) {
            const int row = wn * 64 + n * 16 + lr;
            const int sc = lkc ^ ((row >> 1) & 3);
            b[n] = *(const short8v*)(lb + row * 32 + sc * 8);
        }
        if (kt + 1 < NT2) stageB32(Bbf, tn, Vc - 1, lbN, kt + 1, t);
        __builtin_amdgcn_s_barrier();
        __builtin_amdgcn_sched_barrier(0);
        __builtin_amdgcn_s_setprio(1);
#pragma unroll
        for (int m = 0; m < 8; ++m)
#pragma unroll
            for (int n = 0; n < 2; ++n)
                acc[m][n] = __builtin_amdgcn_mfma_f32_16x16x32_bf16(a[m], b[n], acc[m][n], 0, 0, 0);
        __builtin_amdgcn_s_setprio(0);
        __builtin_amdgcn_s_barrier();
        __builtin_amdgcn_sched_barrier(0);
        if (kt + 2 < NT2) stageA32(Abf, tm, la, kt + 2, t);
        __builtin_amdgcn_s_setprio(1);
#pragma unroll
        for (int m = 0; m < 8; ++m)
#pragma unroll
            for (int n = 2; n < 4; ++n)
                acc[m][n] = __builtin_amdgcn_mfma_f32_16x16x32_bf16(a[m], b[n], acc[m][n], 0, 0, 0);
        __builtin_amdgcn_s_setprio(0);
        if (kt + 2 < NT2) asm volatile("s_waitcnt vmcnt(2)" ::: "memory");
        else              asm volatile("s_waitcnt vmcnt(0)" ::: "memory");
        __builtin_amdgcn_s_barrier();
        __builtin_amdgcn_sched_barrier(0);
    }
    const int lq = (lane >> 4) * 4;
#pragma unroll
    for (int n = 0; n < 4; ++n) {
        const int col = tn + wn * 64 + n * 16 + lr;
        if (col >= Vc) continue;
        const float bv = bias[col];
#pragma unroll
        for (int m = 0; m < 8; ++m) {
            const int rbase = tm + m * 16 + lq;
#pragma unroll
            for (int j = 0; j < 4; ++j)
                C[(size_t)(rbase + j) * Vc + col] = acc[m][n][j] + bv;
        }
    }
}

// ---------------- plan mean partials ----------------
__global__ __launch_bounds__(256) void k_pmean(const float* __restrict__ plan, float* __restrict__ pm2) {
    const int b = blockIdx.x, c = blockIdx.y;
    const int h = threadIdx.x;
    const float* p = plan + ((size_t)(b * Sc + c * 64)) * Hc + h;
    float s = 0.0f;
    for (int i = 0; i < 64; ++i) s += p[(size_t)i * Hc];
    pm2[((size_t)b * 8 + c) * Hc + h] = s;
}

// ---------------- read softmax + memory read ----------------
__global__ __launch_bounds__(256) void k_memread(const float* __restrict__ pm2,
                                                 const float* __restrict__ rw,
                                                 const float* __restrict__ rb,
                                                 const float* __restrict__ memm,
                                                 float* __restrict__ out) {
    const int b = blockIdx.x;
    const int t = threadIdx.x;
    __shared__ float pms[256];
    __shared__ float lg[64];
    __shared__ float sm[64];
    float v = 0.0f;
    for (int c = 0; c < 8; ++c) v += pm2[((size_t)b * 8 + c) * Hc + t];
    pms[t] = v * (1.0f / 512.0f);
    __syncthreads();
    if (t < 64) {
        float s = rb[t];
        const float* wrow = rw + (size_t)t * Hc;
        for (int i = 0; i < Hc; ++i) s = fmaf(wrow[i], pms[i], s);
        lg[t] = s;
    }
    __syncthreads();
    if (t == 0) {
        float mx = lg[0];
        for (int i = 1; i < 64; ++i) mx = fmaxf(mx, lg[i]);
        float ssum = 0.0f;
        for (int i = 0; i < 64; ++i) { const float e = expf(lg[i] - mx); sm[i] = e; ssum += e; }
        for (int i = 0; i < 64; ++i) sm[i] /= ssum;
    }
    __syncthreads();
    float s = 0.0f;
    for (int m = 0; m < 64; ++m) s = fmaf(sm[m], memm[(size_t)m * Hc + t], s);
    out[(size_t)b * Hc + t] = s;
}

extern "C" void kernel_launch(void* const* d_in, const int* in_sizes, int n_in,
                              void* d_out, int out_size, void* d_ws, size_t ws_size,
                              hipStream_t stream) {
    const int*   ids    = (const int*)  d_in[0];
    const float* embed  = (const float*)d_in[1];
    const float* pos    = (const float*)d_in[2];
    const float* qkv_w  = (const float*)d_in[3];
    const float* qkv_b  = (const float*)d_in[4];
    const float* out_w  = (const float*)d_in[5];
    const float* out_b  = (const float*)d_in[6];
    const float* ln1_g  = (const float*)d_in[7];
    const float* ln1_b  = (const float*)d_in[8];
    const float* ff1_w  = (const float*)d_in[9];
    const float* ff1_b  = (const float*)d_in[10];
    const float* ff2_w  = (const float*)d_in[11];
    const float* ff2_b  = (const float*)d_in[12];
    const float* ln2_g  = (const float*)d_in[13];
    const float* ln2_b  = (const float*)d_in[14];
    const float* log_w  = (const float*)d_in[15];
    const float* log_b  = (const float*)d_in[16];
    const float* mat_w  = (const float*)d_in[17];
    const float* mat_b  = (const float*)d_in[18];
    const float* conv_w = (const float*)d_in[19];
    const float* conv_b = (const float*)d_in[20];
    const float* read_w = (const float*)d_in[21];
    const float* read_b = (const float*)d_in[22];
    const float* memory = (const float*)d_in[23];
    const float* head_w = (const float*)d_in[24];
    const float* head_b = (const float*)d_in[25];

    char* wsb = (char*)d_ws;
    const size_t MB = 1ull << 20;
    float* X    = (float*)(wsb + 0);           // 8 MB [8192,256]
    bf16*  XH   = (bf16*)(wsb + 8 * MB);
    bf16*  XM   = (bf16*)(wsb + 12 * MB);
    bf16*  XL   = (bf16*)(wsb + 16 * MB);
    float* RES  = (float*)(wsb + 20 * MB);     // 8 MB
    bf16*  QPH  = (bf16*)(wsb + 28 * MB);      // 12 MB each [8192,768] planes
    bf16*  QPM  = (bf16*)(wsb + 40 * MB);
    bf16*  QPL  = (bf16*)(wsb + 52 * MB);
    bf16*  OH   = (bf16*)(wsb + 64 * MB);      // 4 MB each
    bf16*  OM   = (bf16*)(wsb + 68 * MB);
    bf16*  OL   = (bf16*)(wsb + 72 * MB);
    // ---- alias region 76..128 MB ----
    bf16*  VTH  = (bf16*)(wsb + 76 * MB);      // 4 MB each (attention phase)
    bf16*  VTM  = (bf16*)(wsb + 80 * MB);
    bf16*  VTL  = (bf16*)(wsb + 84 * MB);
    bf16*  H1H  = (bf16*)(wsb + 88 * MB);      // 8 MB each (ff phase; disjoint from VT)
    bf16*  H1M  = (bf16*)(wsb + 96 * MB);
    bf16*  H1L  = (bf16*)(wsb + 104 * MB);
    float* LOGMAT = (float*)(wsb + 76 * MB);   // 16 MB [8192,512] (post-loop)
    // ---------------------------------
    bf16*  COMB = (bf16*)(wsb + 128 * MB);     // 16 MB [8192,1024]
    bf16*  HWB  = (bf16*)(wsb + 144 * MB);     // 16 MB [8000,1024]
    bf16*  WP   = (bf16*)(wsb + 160 * MB);     // weight planes
    float* PM2  = (float*)(wsb + 64 * MB);     // [16,8,256] partials (reuse OH post-loop)

    float* logits = (float*)d_out;
    float* mread  = logits + (size_t)ROWS * Vc;

    // weight plane sub-offsets (elements)
    bf16* qkvwh = WP;             bf16* qkvwm = qkvwh + 393216; bf16* qkvwl = qkvwm + 393216;
    bf16* outwh = qkvwl + 393216; bf16* outwm = outwh + 131072; bf16* outwl = outwm + 131072;
    bf16* ff1wh = outwl + 131072; bf16* ff1wm = ff1wh + 262144; bf16* ff1wl = ff1wm + 262144;
    bf16* ff2wh = ff1wl + 262144; bf16* ff2wm = ff2wh + 262144; bf16* ff2wl = ff2wm + 262144;
    bf16* lmwh  = ff2wl + 262144; bf16* lmwm  = lmwh + 131072;  bf16* lmwl  = lmwm + 131072;
    bf16* w2h   = lmwl + 131072;  bf16* w2m   = w2h + 196608;   bf16* w2l   = w2m + 196608;
    float* LMB  = (float*)(w2l + 196608);      // [512] concat bias (after weight planes)
    bf16*  ZB   = (bf16*)((char*)LMB + 2048);  // 128B zero stub (16B-aligned), for conv halo OOB

    hipFuncSetAttribute((const void*)k_attn, hipFuncAttributeMaxDynamicSharedMemorySize, 155648);

    // consolidated weight prep (one launch)
    k_prep<<<dim3(9921), 256, 0, stream>>>(
        qkv_w, out_w, ff1_w, ff2_w, log_w, mat_w, conv_w, head_w, log_b, mat_b,
        qkvwh, qkvwm, qkvwl, outwh, outwm, outwl, ff1wh, ff1wm, ff1wl,
        ff2wh, ff2wm, ff2wl, lmwh, lmwm, lmwl, w2h, w2m, w2l, HWB, LMB, ZB);

    k_embed<<<dim3(ROWS / 4), 256, 0, stream>>>(ids, embed, pos, X, XH, XM, XL);
    for (int l = 0; l < 2; ++l) {
        // qkv -> QP planes [8192,768]
        k_bg3<0, 1, 128><<<dim3(64, 6, 1), 256, 0, stream>>>(
            XH, XM, XL,
            qkvwh + (size_t)l * 196608, qkvwm + (size_t)l * 196608, qkvwl + (size_t)l * 196608,
            qkv_b + l * 768, nullptr, QPH, QPM, QPL,
            256, 256, 256, 768, 0, 0, 0, 0, 0, 0, nullptr);
        k_vt<<<dim3(8, 64), 256, 0, stream>>>(QPH, QPM, QPL, VTH, VTM, VTL);
        // fused scores + softmax + PV -> O planes (pipelined LDS staging)
        k_attn<<<dim3(8, 64), 512, 155648, stream>>>(QPH, QPM, QPL, VTH, VTM, VTL, OH, OM, OL);
        // out proj -> RES fp32
        k_bg3<0, 0, 64><<<dim3(64, 4, 1), 256, 0, stream>>>(
            OH, OM, OL,
            outwh + (size_t)l * 65536, outwm + (size_t)l * 65536, outwl + (size_t)l * 65536,
            out_b + l * 256, RES, nullptr, nullptr, nullptr,
            256, 256, 256, 256, 0, 0, 0, 0, 0, 0, nullptr);
        k_add_ln<<<dim3(ROWS / 4), 256, 0, stream>>>(X, RES, ln1_g + l * 256, ln1_b + l * 256,
                                                     XH, XM, XL, nullptr);
        // ff1 + gelu -> H1 planes
        k_bg3<1, 1, 128><<<dim3(64, 4, 1), 256, 0, stream>>>(
            XH, XM, XL,
            ff1wh + (size_t)l * 131072, ff1wm + (size_t)l * 131072, ff1wl + (size_t)l * 131072,
            ff1_b + l * 512, nullptr, H1H, H1M, H1L,
            256, 256, 256, 512, 0, 0, 0, 0, 0, 0, nullptr);
        // ff2 -> RES fp32
        k_bg3<0, 0, 64><<<dim3(64, 4, 1), 256, 0, stream>>>(
            H1H, H1M, H1L,
            ff2wh + (size_t)l * 131072, ff2wm + (size_t)l * 131072, ff2wl + (size_t)l * 131072,
            ff2_b + l * 256, RES, nullptr, nullptr, nullptr,
            512, 512, 512, 256, 0, 0, 0, 0, 0, 0, nullptr);
        // final LN also packs plan into COMB (cols 768..1023)
        k_add_ln<<<dim3(ROWS / 4), 256, 0, stream>>>(X, RES, ln2_g + l * 256, ln2_b + l * 256,
                                                     XH, XM, XL, (l == 1) ? COMB : nullptr);
    }
    // plan = X; fused log+mat projection -> LOGMAT [8192,512]
    k_bg3<0, 0, 128><<<dim3(64, 4, 1), 256, 0, stream>>>(
        XH, XM, XL, lmwh, lmwm, lmwl, LMB, LOGMAT, nullptr, nullptr, nullptr,
        256, 256, 256, 512, 0, 0, 0, 0, 0, 0, nullptr);
    k_lif2<<<dim3(Bc, 2), 256, 0, stream>>>(LOGMAT, COMB);
    // conv as GEMM with fused halo (A = X planes directly) -> bf16 into COMB cols 512..767
    k_bg3<0, 3, 64, 1><<<dim3(64, 4, 1), 256, 0, stream>>>(
        XH, XM, XL, w2h, w2m, w2l, conv_b, (float*)(COMB + 512), nullptr, nullptr, nullptr,
        768, 256, 768, CH, 0, 0, 0, 0, 0, 0, ZB);
    k_head8<<<dim3(64, 32), 256, 0, stream>>>(COMB, HWB, head_b, logits);
    k_pmean<<<dim3(Bc, 8), 256, 0, stream>>>(X, PM2);
    k_memread<<<dim3(Bc), 256, 0, stream>>>(PM2, read_w, read_b, memory, mread);
}